// Round 1
// baseline (841.661 us; speedup 1.0000x reference)
//
#include <hip/hip_runtime.h>
#include <math.h>

#define NB 2
#define SEQ 2048
#define HD 1024
#define NH 8
#define DH 128
#define HALF 64

// ---------------- xpos tables: sin_q, cos_q, sin_k, cos_k  (S x 64 each) ---
__global__ __launch_bounds__(256) void k_tables(float* __restrict__ tabs) {
  int idx = blockIdx.x * 256 + threadIdx.x;
  if (idx >= SEQ * HALF) return;
  int s = idx >> 6, i = idx & 63;
  float dd = (float)DH;
  float scale = (2.0f * (float)i + 0.4f * dd) / (1.4f * dd);
  float sc = expf(logf(scale) * ((float)s / 512.0f));
  float inv_freq = expf(-logf(10000.0f) * ((float)i / (float)HALF));
  float ang = (float)s * inv_freq;
  float sn, cs;
  sincosf(ang, &sn, &cs);
  float rsc = 1.0f / sc;
  tabs[idx]               = sn * sc;
  tabs[SEQ*HALF + idx]    = cs * sc;
  tabs[2*SEQ*HALF + idx]  = sn * rsc;
  tabs[3*SEQ*HALF + idx]  = cs * rsc;
}

// ---------------- QKV projection + fused xpos ------------------------------
// grid (S/64, NH, NB), block 256. Per block: X tile 64x128 once;
// 6 passes (3 weights x 2 col-halves) of W tile 128x64.
__global__ __launch_bounds__(256) void k_qkv(
    const float* __restrict__ X, const float* __restrict__ Wq,
    const float* __restrict__ Wk, const float* __restrict__ Wv,
    const float* __restrict__ tabs,
    float* __restrict__ Qo, float* __restrict__ Ko, float* __restrict__ Vo) {
  __shared__ float Xs[64][132];   // +4 pad: bank-spread, keeps 16B align
  __shared__ float Ws[128][64];
  int t = threadIdx.x;
  int s0 = blockIdx.x * 64;
  int hh = blockIdx.y;
  int b  = blockIdx.z;

  for (int idx = t; idx < 64*32; idx += 256) {
    int r = idx >> 5, c4 = idx & 31;
    float4 v = *(const float4*)(X + (size_t)(b*SEQ + s0 + r) * HD + hh*DH + c4*4);
    *(float4*)&Xs[r][c4*4] = v;
  }

  const float* Wp[3] = {Wq, Wk, Wv};
  float* Op[3] = {Qo, Ko, Vo};
  int r0 = (t >> 4) * 4;
  int c0 = (t & 15) * 4;

  for (int which = 0; which < 3; ++which) {
    const float* W = Wp[which] + (size_t)hh * (DH*DH);
    for (int hf = 0; hf < 2; ++hf) {
      __syncthreads();              // prev pass done reading Ws (also Xs ready)
      for (int idx = t; idx < 128*16; idx += 256) {
        int r = idx >> 4, c4 = idx & 15;
        float4 v = *(const float4*)(W + r*DH + hf*64 + c4*4);
        *(float4*)&Ws[r][c4*4] = v;
      }
      __syncthreads();
      float acc[4][4] = {};
      #pragma unroll 4
      for (int k = 0; k < DH; k += 4) {
        float4 xa[4], wb[4];
        #pragma unroll
        for (int i = 0; i < 4; ++i) xa[i] = *(const float4*)&Xs[r0+i][k];
        #pragma unroll
        for (int kk = 0; kk < 4; ++kk) wb[kk] = *(const float4*)&Ws[k+kk][c0];
        #pragma unroll
        for (int i = 0; i < 4; ++i) {
          float xv[4] = {xa[i].x, xa[i].y, xa[i].z, xa[i].w};
          #pragma unroll
          for (int kk = 0; kk < 4; ++kk) {
            acc[i][0] = fmaf(xv[kk], wb[kk].x, acc[i][0]);
            acc[i][1] = fmaf(xv[kk], wb[kk].y, acc[i][1]);
            acc[i][2] = fmaf(xv[kk], wb[kk].z, acc[i][2]);
            acc[i][3] = fmaf(xv[kk], wb[kk].w, acc[i][3]);
          }
        }
      }
      float* O = Op[which];
      #pragma unroll
      for (int i = 0; i < 4; ++i) {
        int s = s0 + r0 + i;
        int cbase = hf*64 + c0;
        float o0 = acc[i][0], o1 = acc[i][1], o2 = acc[i][2], o3 = acc[i][3];
        if (which < 2) {
          const float* st = tabs + (which ? 2*SEQ*HALF : 0);
          const float* ct = st + SEQ*HALF;
          int p0 = cbase >> 1, p1 = p0 + 1;
          float s0v = st[s*HALF + p0], c0v = ct[s*HALF + p0];
          float s1v = st[s*HALF + p1], c1v = ct[s*HALF + p1];
          float e0 = o0*c0v - o1*s0v;
          float e1 = o1*c0v + o0*s0v;
          float e2 = o2*c1v - o3*s1v;
          float e3 = o3*c1v + o2*s1v;
          o0=e0; o1=e1; o2=e2; o3=e3;
        }
        float4 vv = {o0,o1,o2,o3};
        *(float4*)(O + (size_t)((b*NH + hh)*SEQ + s) * DH + cbase) = vv;
      }
    }
  }
}

// ---------------- retention: Y = (QK^T * gamma^(s-t) * causal) V -----------
// grid (32, NH, NB) with work-balance swizzle, block 256.
// 64-query x 32-key tiles; per-thread 4x8 output accumulator.
__global__ __launch_bounds__(256) void k_ret(
    const float* __restrict__ Qi, const float* __restrict__ Ki,
    const float* __restrict__ Vi, float* __restrict__ Yo) {
  __shared__ float Qs[64][132];
  __shared__ float Ks[32][132];
  __shared__ float Vs[32][132];
  __shared__ float Ss[64][36];
  int t = threadIdx.x;
  int bx = blockIdx.x;
  int qt = (bx & 1) ? (31 - (bx >> 1)) : (bx >> 1);   // pair heavy+light tiles
  int hh = blockIdx.y, b = blockIdx.z;
  int s0 = qt * 64;
  size_t base = (size_t)((b*NH + hh) * SEQ) * DH;

  double ga = log(1.0/32.0), gbb = log(1.0/512.0);
  float gamma = (float)(1.0 - exp(ga + (double)hh * (gbb - ga) / 7.0));
  float l2g = log2f(gamma);

  for (int idx = t; idx < 64*32; idx += 256) {
    int r = idx >> 5, c4 = idx & 31;
    *(float4*)&Qs[r][c4*4] = *(const float4*)(Qi + base + (size_t)(s0+r)*DH + c4*4);
  }

  int r0 = (t >> 4) * 4;
  int cA = (t & 15) * 4;
  int ck = (t & 15) * 2;
  float acc[4][8] = {};

  int ktmax = qt*2 + 1;
  for (int kt = 0; kt <= ktmax; ++kt) {
    int t0 = kt * 32;
    __syncthreads();   // prev PV done with Ks/Vs/Ss (and Qs ready on iter 0)
    for (int idx = t; idx < 32*32; idx += 256) {
      int r = idx >> 5, c4 = idx & 31;
      *(float4*)&Ks[r][c4*4] = *(const float4*)(Ki + base + (size_t)(t0+r)*DH + c4*4);
      *(float4*)&Vs[r][c4*4] = *(const float4*)(Vi + base + (size_t)(t0+r)*DH + c4*4);
    }
    __syncthreads();
    // S = Q K^T for rows r0..r0+3, cols ck..ck+1
    float sacc[4][2] = {};
    #pragma unroll 2
    for (int k = 0; k < DH; k += 4) {
      float4 q4[4], k4[2];
      #pragma unroll
      for (int i = 0; i < 4; ++i) q4[i] = *(const float4*)&Qs[r0+i][k];
      #pragma unroll
      for (int j = 0; j < 2; ++j) k4[j] = *(const float4*)&Ks[ck+j][k];
      #pragma unroll
      for (int i = 0; i < 4; ++i) {
        #pragma unroll
        for (int j = 0; j < 2; ++j) {
          sacc[i][j] = fmaf(q4[i].x, k4[j].x, sacc[i][j]);
          sacc[i][j] = fmaf(q4[i].y, k4[j].y, sacc[i][j]);
          sacc[i][j] = fmaf(q4[i].z, k4[j].z, sacc[i][j]);
          sacc[i][j] = fmaf(q4[i].w, k4[j].w, sacc[i][j]);
        }
      }
    }
    #pragma unroll
    for (int i = 0; i < 4; ++i) {
      int sg = s0 + r0 + i;
      #pragma unroll
      for (int j = 0; j < 2; ++j) {
        int tg = t0 + ck + j;
        int diff = sg - tg;
        float w = (diff >= 0) ? exp2f(l2g * (float)diff) : 0.0f;
        Ss[r0+i][ck+j] = sacc[i][j] * w;
      }
    }
    __syncthreads();
    // Y += S V
    #pragma unroll 2
    for (int k = 0; k < 32; k += 4) {
      float4 s4[4];
      #pragma unroll
      for (int i = 0; i < 4; ++i) s4[i] = *(const float4*)&Ss[r0+i][k];
      #pragma unroll
      for (int kk = 0; kk < 4; ++kk) {
        float4 va = *(const float4*)&Vs[k+kk][cA];
        float4 vb = *(const float4*)&Vs[k+kk][64+cA];
        #pragma unroll
        for (int i = 0; i < 4; ++i) {
          float sk = (kk==0) ? s4[i].x : (kk==1) ? s4[i].y : (kk==2) ? s4[i].z : s4[i].w;
          acc[i][0] = fmaf(sk, va.x, acc[i][0]);
          acc[i][1] = fmaf(sk, va.y, acc[i][1]);
          acc[i][2] = fmaf(sk, va.z, acc[i][2]);
          acc[i][3] = fmaf(sk, va.w, acc[i][3]);
          acc[i][4] = fmaf(sk, vb.x, acc[i][4]);
          acc[i][5] = fmaf(sk, vb.y, acc[i][5]);
          acc[i][6] = fmaf(sk, vb.z, acc[i][6]);
          acc[i][7] = fmaf(sk, vb.w, acc[i][7]);
        }
      }
    }
  }
  #pragma unroll
  for (int i = 0; i < 4; ++i) {
    float4 a = {acc[i][0],acc[i][1],acc[i][2],acc[i][3]};
    float4 bq = {acc[i][4],acc[i][5],acc[i][6],acc[i][7]};
    *(float4*)(Yo + base + (size_t)(s0+r0+i)*DH + cA) = a;
    *(float4*)(Yo + base + (size_t)(s0+r0+i)*DH + 64 + cA) = bq;
  }
}

// ---------------- groupnorm over (B*S*h, 128) + transpose to (B,S,H) -------
__global__ __launch_bounds__(256) void k_gnorm(
    const float* __restrict__ Y, const float* __restrict__ gw,
    const float* __restrict__ gb, float* __restrict__ Yn) {
  int wave = threadIdx.x >> 6, lane = threadIdx.x & 63;
  int g = blockIdx.x * 4 + wave;       // (b*NH+hh)*SEQ + s
  int b = g >> 14;
  int hh = (g >> 11) & 7;
  int s = g & 2047;
  const float* yp = Y + (size_t)g * DH;
  float v0 = yp[lane], v1 = yp[64 + lane];
  float s1 = v0 + v1, s2 = v0*v0 + v1*v1;
  #pragma unroll
  for (int off = 32; off; off >>= 1) {
    s1 += __shfl_xor(s1, off);
    s2 += __shfl_xor(s2, off);
  }
  float mean = s1 * (1.0f/128.0f);
  float var = s2 * (1.0f/128.0f) - mean*mean;
  float inv = rsqrtf(var + 1e-5f);
  int c0 = hh*DH + lane;
  float* op = Yn + (size_t)(b*SEQ + s) * HD;
  op[c0]      = (v0 - mean) * inv * gw[c0]    + gb[c0];
  op[c0 + 64] = (v1 - mean) * inv * gw[c0+64] + gb[c0+64];
}

// ---------------- generic 64x64 fp32 GEMM, M=4096 N=K=1024 -----------------
// mode 1: C = swish(A@Bm) * E   (gate path);  mode 0: C = A@Bm (output)
__global__ __launch_bounds__(256) void k_gemm(
    const float* __restrict__ A, const float* __restrict__ Bm,
    const float* __restrict__ E, float* __restrict__ C, int mode) {
  __shared__ float As[64][36];
  __shared__ float Bs[32][68];
  int t = threadIdx.x;
  int n0 = blockIdx.x * 64, m0 = blockIdx.y * 64;
  int r0 = (t >> 4) * 4, c0 = (t & 15) * 4;
  float acc[4][4] = {};
  for (int k0 = 0; k0 < HD; k0 += 32) {
    __syncthreads();
    for (int idx = t; idx < 64*8; idx += 256) {
      int r = idx >> 3, c4 = idx & 7;
      *(float4*)&As[r][c4*4] = *(const float4*)(A + (size_t)(m0+r)*HD + k0 + c4*4);
    }
    for (int idx = t; idx < 32*16; idx += 256) {
      int r = idx >> 4, c4 = idx & 15;
      *(float4*)&Bs[r][c4*4] = *(const float4*)(Bm + (size_t)(k0+r)*HD + n0 + c4*4);
    }
    __syncthreads();
    #pragma unroll 2
    for (int k = 0; k < 32; k += 4) {
      float4 a4[4];
      #pragma unroll
      for (int i = 0; i < 4; ++i) a4[i] = *(const float4*)&As[r0+i][k];
      #pragma unroll
      for (int kk = 0; kk < 4; ++kk) {
        float4 b4 = *(const float4*)&Bs[k+kk][c0];
        #pragma unroll
        for (int i = 0; i < 4; ++i) {
          float av = (kk==0)?a4[i].x:(kk==1)?a4[i].y:(kk==2)?a4[i].z:a4[i].w;
          acc[i][0] = fmaf(av, b4.x, acc[i][0]);
          acc[i][1] = fmaf(av, b4.y, acc[i][1]);
          acc[i][2] = fmaf(av, b4.z, acc[i][2]);
          acc[i][3] = fmaf(av, b4.w, acc[i][3]);
        }
      }
    }
  }
  #pragma unroll
  for (int i = 0; i < 4; ++i) {
    size_t row = (size_t)(m0 + r0 + i) * HD + n0 + c0;
    float4 o;
    #pragma unroll
    for (int j = 0; j < 4; ++j) {
      float g = acc[i][j];
      float v;
      if (mode == 1) {
        float sg = 1.0f / (1.0f + expf(-g));
        v = g * sg * E[row + j];
      } else {
        v = g;
      }
      ((float*)&o)[j] = v;
    }
    *(float4*)(C + row) = o;
  }
}

extern "C" void kernel_launch(void* const* d_in, const int* in_sizes, int n_in,
                              void* d_out, int out_size, void* d_ws, size_t ws_size,
                              hipStream_t stream) {
  const float* X  = (const float*)d_in[0];
  const float* Wq = (const float*)d_in[1];
  const float* Wk = (const float*)d_in[2];
  const float* Wv = (const float*)d_in[3];
  const float* Wg = (const float*)d_in[4];
  const float* Wo = (const float*)d_in[5];
  const float* gw = (const float*)d_in[6];
  const float* gb = (const float*)d_in[7];
  float* out = (float*)d_out;
  float* ws = (float*)d_ws;

  // workspace layout (floats): tabs | Q | K | V | Y   (~66 MB total)
  float* tabs = ws;                    // 4 * 2048 * 64 = 524288
  float* Q = ws + 524288;              // 4194304 each
  float* K = Q + 4194304;
  float* V = K + 4194304;
  float* Y = V + 4194304;
  float* Yn = Q;                       // reuse: Q dead after k_ret
  float* Ab = K;                       // reuse: K dead after k_ret

  k_tables<<<dim3(512), dim3(256), 0, stream>>>(tabs);
  k_qkv<<<dim3(32, 8, 2), dim3(256), 0, stream>>>(X, Wq, Wk, Wv, tabs, Q, K, V);
  k_ret<<<dim3(32, 8, 2), dim3(256), 0, stream>>>(Q, K, V, Y);
  k_gnorm<<<dim3(8192), dim3(256), 0, stream>>>(Y, gw, gb, Yn);
  k_gemm<<<dim3(16, 64), dim3(256), 0, stream>>>(X, Wg, Yn, Ab, 1);
  k_gemm<<<dim3(16, 64), dim3(256), 0, stream>>>(Ab, Wo, nullptr, out, 0);
}

// Round 2
// 479.121 us; speedup vs baseline: 1.7567x; 1.7567x over previous
//
#include <hip/hip_runtime.h>
#include <math.h>

#define NB 2
#define SEQ 2048
#define HD 1024
#define NH 8
#define DH 128
#define HALF 64

typedef __bf16 bf16_t;
typedef __attribute__((ext_vector_type(8))) __bf16 bf16x8;
typedef __attribute__((ext_vector_type(4))) __bf16 bf16x4;
typedef __attribute__((ext_vector_type(4))) float f32x4;

// ---------------- xpos tables: sin_q, cos_q, sin_k, cos_k  (S x 64 each) ---
__global__ __launch_bounds__(256) void k_tables(float* __restrict__ tabs) {
  int idx = blockIdx.x * 256 + threadIdx.x;
  if (idx >= SEQ * HALF) return;
  int s = idx >> 6, i = idx & 63;
  float dd = (float)DH;
  float scale = (2.0f * (float)i + 0.4f * dd) / (1.4f * dd);
  float sc = expf(logf(scale) * ((float)s / 512.0f));
  float inv_freq = expf(-logf(10000.0f) * ((float)i / (float)HALF));
  float ang = (float)s * inv_freq;
  float sn, cs;
  sincosf(ang, &sn, &cs);
  float rsc = 1.0f / sc;
  tabs[idx]               = sn * sc;
  tabs[SEQ*HALF + idx]    = cs * sc;
  tabs[2*SEQ*HALF + idx]  = sn * rsc;
  tabs[3*SEQ*HALF + idx]  = cs * rsc;
}

// ---------------- QKV projection + fused xpos + bf16 hi/lo split -----------
// Outputs: Qh/Ql, Kh/Kl row-major [bh][s][d]; Vh/Vl transposed [bh][d][s].
__global__ __launch_bounds__(256) void k_qkv(
    const float* __restrict__ X, const float* __restrict__ Wq,
    const float* __restrict__ Wk, const float* __restrict__ Wv,
    const float* __restrict__ tabs,
    bf16_t* __restrict__ Qh, bf16_t* __restrict__ Ql,
    bf16_t* __restrict__ Kh, bf16_t* __restrict__ Kl,
    bf16_t* __restrict__ Vh, bf16_t* __restrict__ Vl) {
  __shared__ float Xs[64][132];
  __shared__ float Ws[128][64];
  int t = threadIdx.x;
  int s0 = blockIdx.x * 64;
  int hh = blockIdx.y;
  int b  = blockIdx.z;

  for (int idx = t; idx < 64*32; idx += 256) {
    int r = idx >> 5, c4 = idx & 31;
    float4 v = *(const float4*)(X + (size_t)(b*SEQ + s0 + r) * HD + hh*DH + c4*4);
    *(float4*)&Xs[r][c4*4] = v;
  }

  const float* Wp[3] = {Wq, Wk, Wv};
  int r0 = (t >> 4) * 4;
  int c0 = (t & 15) * 4;

  for (int which = 0; which < 3; ++which) {
    const float* W = Wp[which] + (size_t)hh * (DH*DH);
    for (int hf = 0; hf < 2; ++hf) {
      __syncthreads();
      for (int idx = t; idx < 128*16; idx += 256) {
        int r = idx >> 4, c4 = idx & 15;
        float4 v = *(const float4*)(W + r*DH + hf*64 + c4*4);
        *(float4*)&Ws[r][c4*4] = v;
      }
      __syncthreads();
      float acc[4][4] = {};
      #pragma unroll 4
      for (int k = 0; k < DH; k += 4) {
        float4 xa[4], wb[4];
        #pragma unroll
        for (int i = 0; i < 4; ++i) xa[i] = *(const float4*)&Xs[r0+i][k];
        #pragma unroll
        for (int kk = 0; kk < 4; ++kk) wb[kk] = *(const float4*)&Ws[k+kk][c0];
        #pragma unroll
        for (int i = 0; i < 4; ++i) {
          float xv[4] = {xa[i].x, xa[i].y, xa[i].z, xa[i].w};
          #pragma unroll
          for (int kk = 0; kk < 4; ++kk) {
            acc[i][0] = fmaf(xv[kk], wb[kk].x, acc[i][0]);
            acc[i][1] = fmaf(xv[kk], wb[kk].y, acc[i][1]);
            acc[i][2] = fmaf(xv[kk], wb[kk].z, acc[i][2]);
            acc[i][3] = fmaf(xv[kk], wb[kk].w, acc[i][3]);
          }
        }
      }
      int cbase = hf*64 + c0;
      float o[4][4];
      #pragma unroll
      for (int i = 0; i < 4; ++i) {
        float o0 = acc[i][0], o1 = acc[i][1], o2 = acc[i][2], o3 = acc[i][3];
        if (which < 2) {
          int s = s0 + r0 + i;
          const float* st = tabs + (which ? 2*SEQ*HALF : 0);
          const float* ct = st + SEQ*HALF;
          int p0 = cbase >> 1, p1 = p0 + 1;
          float s0v = st[s*HALF + p0], c0v = ct[s*HALF + p0];
          float s1v = st[s*HALF + p1], c1v = ct[s*HALF + p1];
          float e0 = o0*c0v - o1*s0v;
          float e1 = o1*c0v + o0*s0v;
          float e2 = o2*c1v - o3*s1v;
          float e3 = o3*c1v + o2*s1v;
          o0=e0; o1=e1; o2=e2; o3=e3;
        }
        o[i][0]=o0; o[i][1]=o1; o[i][2]=o2; o[i][3]=o3;
      }
      size_t bh = (size_t)(b*NH + hh);
      if (which < 2) {
        bf16_t* Hp = which ? Kh : Qh;
        bf16_t* Lp = which ? Kl : Ql;
        #pragma unroll
        for (int i = 0; i < 4; ++i) {
          int s = s0 + r0 + i;
          bf16x4 hv, lv;
          #pragma unroll
          for (int j = 0; j < 4; ++j) {
            bf16_t hb = (bf16_t)o[i][j];
            hv[j] = hb;
            lv[j] = (bf16_t)(o[i][j] - (float)hb);
          }
          size_t off = (bh*SEQ + s) * DH + cbase;
          *(bf16x4*)(Hp + off) = hv;
          *(bf16x4*)(Lp + off) = lv;
        }
      } else {
        #pragma unroll
        for (int j = 0; j < 4; ++j) {
          bf16x4 hv, lv;
          #pragma unroll
          for (int i = 0; i < 4; ++i) {
            bf16_t hb = (bf16_t)o[i][j];
            hv[i] = hb;
            lv[i] = (bf16_t)(o[i][j] - (float)hb);
          }
          size_t off = bh * (size_t)(DH*SEQ) + (size_t)(cbase + j)*SEQ + (s0 + r0);
          *(bf16x4*)(Vh + off) = hv;
          *(bf16x4*)(Vl + off) = lv;
        }
      }
    }
  }
}

// ---------------- retention via MFMA bf16x3 --------------------------------
// grid (32, NH, NB), block 256 (4 waves). Per block: 64 q-rows, KV tiles of 64.
// Each wave owns 16 q-rows. QK^T and PV via mfma_f32_16x16x32_bf16, hi/lo
// split (3 mfma per logical product). K/V staged in LDS with 16B-block XOR
// swizzle; P round-trips per-wave through swizzled LDS.
__global__ __launch_bounds__(256, 2) void k_ret(
    const bf16_t* __restrict__ Qhig, const bf16_t* __restrict__ Qlog,
    const bf16_t* __restrict__ Khig, const bf16_t* __restrict__ Klog,
    const bf16_t* __restrict__ Vhig, const bf16_t* __restrict__ Vlog,
    float* __restrict__ Yo) {
  __shared__ bf16_t Kh[64][128], Kl[64][128];
  __shared__ bf16_t Vh[128][64], Vl[128][64];
  __shared__ bf16_t Ph[64][64], Pl[64][64];
  int t = threadIdx.x;
  int lane = t & 63, w = t >> 6;
  int lr = lane & 15, lg = lane >> 4;
  int bx = blockIdx.x, hh = blockIdx.y, b = blockIdx.z;
  int qsw = (bx & 1) ? (31 - (bx >> 1)) : (bx >> 1);
  int qt = b ? (31 - qsw) : qsw;          // co-resident pairs sum to const work
  int s0 = qt * 64;
  size_t base = (size_t)((b*NH + hh) * SEQ) * DH;

  double ga = log(1.0/32.0), gbb = log(1.0/512.0);
  float gamma = (float)(1.0 - exp(ga + (double)hh * (gbb - ga) / 7.0));
  float l2g = log2f(gamma);
  float colf = exp2f(-l2g * (float)lr);          // gamma^(-lr)
  float g16v[4];
  #pragma unroll
  for (int ts = 0; ts < 4; ++ts) g16v[ts] = exp2f(-l2g * (float)(16*ts));

  // Q fragments (A operand): row = s0+16w+lr, k-chunk = 8*lg + 32*ks
  bf16x8 qh[4], ql[4];
  {
    const bf16_t* qph = Qhig + base + (size_t)(s0 + 16*w + lr) * DH + lg * 8;
    const bf16_t* qpl = Qlog + base + (size_t)(s0 + 16*w + lr) * DH + lg * 8;
    #pragma unroll
    for (int ks = 0; ks < 4; ++ks) {
      qh[ks] = *(const bf16x8*)(qph + 32*ks);
      ql[ks] = *(const bf16x8*)(qpl + 32*ks);
    }
  }
  f32x4 yacc[8];
  #pragma unroll
  for (int i = 0; i < 8; ++i) yacc[i] = (f32x4){0.f,0.f,0.f,0.f};

  for (int kt = 0; kt <= qt; ++kt) {
    int t0 = kt * 64;
    __syncthreads();   // prev iteration done with Kh/Kl/Vh/Vl
    // stage K tiles: 64 rows x 128 cols bf16, swizzle k-chunk with row&7
    for (int idx = t; idx < 1024; idx += 256) {
      int r = idx >> 4, kb = idx & 15;
      int kbs = kb ^ (r & 7);
      *(bf16x8*)&Kh[r][kbs*8] = *(const bf16x8*)(Khig + base + (size_t)(t0 + r)*DH + kb*8);
      *(bf16x8*)&Kl[r][kbs*8] = *(const bf16x8*)(Klog + base + (size_t)(t0 + r)*DH + kb*8);
    }
    // stage V^T tiles: 128 rows (d) x 64 cols (t) bf16, swizzle t-chunk with d&7
    for (int idx = t; idx < 1024; idx += 256) {
      int d = idx >> 3, cb = idx & 7;
      int cbs = cb ^ (d & 7);
      *(bf16x8*)&Vh[d][cbs*8] = *(const bf16x8*)(Vhig + base + (size_t)d*SEQ + t0 + cb*8);
      *(bf16x8*)&Vl[d][cbs*8] = *(const bf16x8*)(Vlog + base + (size_t)d*SEQ + t0 + cb*8);
    }
    __syncthreads();

    float rowf[4];
    #pragma unroll
    for (int reg = 0; reg < 4; ++reg)
      rowf[reg] = exp2f(l2g * (float)(s0 + 16*w + 4*lg + reg - t0));   // gamma^(q-t0) >= 0 exp

    // ---- S = Q K^T (per wave: 16 q-rows x 64 t) + decay + split to P ----
    #pragma unroll
    for (int ts = 0; ts < 4; ++ts) {
      f32x4 sacc = (f32x4){0.f,0.f,0.f,0.f};
      int trow = 16*ts + lr;
      #pragma unroll
      for (int ks = 0; ks < 4; ++ks) {
        int kbs = (4*ks + lg) ^ (trow & 7);
        bf16x8 kh = *(const bf16x8*)&Kh[trow][kbs*8];
        bf16x8 kl = *(const bf16x8*)&Kl[trow][kbs*8];
        sacc = __builtin_amdgcn_mfma_f32_16x16x32_bf16(qh[ks], kh, sacc, 0, 0, 0);
        sacc = __builtin_amdgcn_mfma_f32_16x16x32_bf16(qh[ks], kl, sacc, 0, 0, 0);
        sacc = __builtin_amdgcn_mfma_f32_16x16x32_bf16(ql[ks], kh, sacc, 0, 0, 0);
      }
      float cf = colf * g16v[ts];
      #pragma unroll
      for (int reg = 0; reg < 4; ++reg) {
        int qloc = 4*lg + reg;
        int diff = (s0 + 16*w + qloc) - (t0 + trow);
        float p = (diff >= 0) ? sacc[reg] * (rowf[reg] * cf) : 0.0f;
        bf16_t ph = (bf16_t)p;
        bf16_t pl = (bf16_t)(p - (float)ph);
        int cb = (trow >> 3) ^ (qloc & 7);
        Ph[16*w + qloc][cb*8 + (trow & 7)] = ph;
        Pl[16*w + qloc][cb*8 + (trow & 7)] = pl;
      }
    }
    // ---- Y += P V  (per wave: 16 q-rows x 128 d) ----
    #pragma unroll
    for (int ks = 0; ks < 2; ++ks) {
      int prow = 16*w + lr;
      int pcb = (4*ks + lg) ^ (lr & 7);
      bf16x8 pah = *(const bf16x8*)&Ph[prow][pcb*8];
      bf16x8 pal = *(const bf16x8*)&Pl[prow][pcb*8];
      #pragma unroll
      for (int sub = 0; sub < 8; ++sub) {
        int drow = 16*sub + lr;
        int vcb = (4*ks + lg) ^ (drow & 7);
        bf16x8 vh = *(const bf16x8*)&Vh[drow][vcb*8];
        bf16x8 vl = *(const bf16x8*)&Vl[drow][vcb*8];
        yacc[sub] = __builtin_amdgcn_mfma_f32_16x16x32_bf16(pah, vh, yacc[sub], 0, 0, 0);
        yacc[sub] = __builtin_amdgcn_mfma_f32_16x16x32_bf16(pah, vl, yacc[sub], 0, 0, 0);
        yacc[sub] = __builtin_amdgcn_mfma_f32_16x16x32_bf16(pal, vh, yacc[sub], 0, 0, 0);
      }
    }
  }
  // epilogue: C/D layout col = lr, row = 4*lg + reg
  #pragma unroll
  for (int sub = 0; sub < 8; ++sub) {
    #pragma unroll
    for (int reg = 0; reg < 4; ++reg) {
      int row = s0 + 16*w + 4*lg + reg;
      Yo[base + (size_t)row*DH + 16*sub + lr] = yacc[sub][reg];
    }
  }
}

// ---------------- groupnorm over (B*S*h, 128) + transpose to (B,S,H) -------
__global__ __launch_bounds__(256) void k_gnorm(
    const float* __restrict__ Y, const float* __restrict__ gw,
    const float* __restrict__ gb, float* __restrict__ Yn) {
  int wave = threadIdx.x >> 6, lane = threadIdx.x & 63;
  int g = blockIdx.x * 4 + wave;       // (b*NH+hh)*SEQ + s
  int b = g >> 14;
  int hh = (g >> 11) & 7;
  int s = g & 2047;
  const float* yp = Y + (size_t)g * DH;
  float v0 = yp[lane], v1 = yp[64 + lane];
  float s1 = v0 + v1, s2 = v0*v0 + v1*v1;
  #pragma unroll
  for (int off = 32; off; off >>= 1) {
    s1 += __shfl_xor(s1, off);
    s2 += __shfl_xor(s2, off);
  }
  float mean = s1 * (1.0f/128.0f);
  float var = s2 * (1.0f/128.0f) - mean*mean;
  float inv = rsqrtf(var + 1e-5f);
  int c0 = hh*DH + lane;
  float* op = Yn + (size_t)(b*SEQ + s) * HD;
  op[c0]      = (v0 - mean) * inv * gw[c0]    + gb[c0];
  op[c0 + 64] = (v1 - mean) * inv * gw[c0+64] + gb[c0+64];
}

// ---------------- generic 64x64 fp32 GEMM, M=4096 N=K=1024 -----------------
__global__ __launch_bounds__(256) void k_gemm(
    const float* __restrict__ A, const float* __restrict__ Bm,
    const float* __restrict__ E, float* __restrict__ C, int mode) {
  __shared__ float As[64][36];
  __shared__ float Bs[32][68];
  int t = threadIdx.x;
  int n0 = blockIdx.x * 64, m0 = blockIdx.y * 64;
  int r0 = (t >> 4) * 4, c0 = (t & 15) * 4;
  float acc[4][4] = {};
  for (int k0 = 0; k0 < HD; k0 += 32) {
    __syncthreads();
    for (int idx = t; idx < 64*8; idx += 256) {
      int r = idx >> 3, c4 = idx & 7;
      *(float4*)&As[r][c4*4] = *(const float4*)(A + (size_t)(m0+r)*HD + k0 + c4*4);
    }
    for (int idx = t; idx < 32*16; idx += 256) {
      int r = idx >> 4, c4 = idx & 15;
      *(float4*)&Bs[r][c4*4] = *(const float4*)(Bm + (size_t)(k0+r)*HD + n0 + c4*4);
    }
    __syncthreads();
    #pragma unroll 2
    for (int k = 0; k < 32; k += 4) {
      float4 a4[4];
      #pragma unroll
      for (int i = 0; i < 4; ++i) a4[i] = *(const float4*)&As[r0+i][k];
      #pragma unroll
      for (int kk = 0; kk < 4; ++kk) {
        float4 b4 = *(const float4*)&Bs[k+kk][c0];
        #pragma unroll
        for (int i = 0; i < 4; ++i) {
          float av = (kk==0)?a4[i].x:(kk==1)?a4[i].y:(kk==2)?a4[i].z:a4[i].w;
          acc[i][0] = fmaf(av, b4.x, acc[i][0]);
          acc[i][1] = fmaf(av, b4.y, acc[i][1]);
          acc[i][2] = fmaf(av, b4.z, acc[i][2]);
          acc[i][3] = fmaf(av, b4.w, acc[i][3]);
        }
      }
    }
  }
  #pragma unroll
  for (int i = 0; i < 4; ++i) {
    size_t row = (size_t)(m0 + r0 + i) * HD + n0 + c0;
    float4 o;
    #pragma unroll
    for (int j = 0; j < 4; ++j) {
      float g = acc[i][j];
      float v;
      if (mode == 1) {
        float sg = 1.0f / (1.0f + expf(-g));
        v = g * sg * E[row + j];
      } else {
        v = g;
      }
      ((float*)&o)[j] = v;
    }
    *(float4*)(C + row) = o;
  }
}

extern "C" void kernel_launch(void* const* d_in, const int* in_sizes, int n_in,
                              void* d_out, int out_size, void* d_ws, size_t ws_size,
                              hipStream_t stream) {
  const float* X  = (const float*)d_in[0];
  const float* Wq = (const float*)d_in[1];
  const float* Wk = (const float*)d_in[2];
  const float* Wv = (const float*)d_in[3];
  const float* Wg = (const float*)d_in[4];
  const float* Wo = (const float*)d_in[5];
  const float* gw = (const float*)d_in[6];
  const float* gb = (const float*)d_in[7];
  float* out = (float*)d_out;
  float* ws = (float*)d_ws;

  // workspace: tabs(2MB) | Qh Ql Kh Kl Vh Vl (6x8MB bf16) | Y(16MB)  = 66MB
  float* tabs = ws;
  bf16_t* Qh = (bf16_t*)(ws + 524288);
  bf16_t* Ql = Qh + 4194304;
  bf16_t* Kh = Ql + 4194304;
  bf16_t* Kl = Kh + 4194304;
  bf16_t* Vh = Kl + 4194304;
  bf16_t* Vl = Vh + 4194304;
  float* Y  = (float*)(Vl + 4194304);
  float* Yn = (float*)Qh;              // reuse: Q dead after k_ret
  float* Ab = (float*)Kh;              // reuse: K dead after k_ret

  k_tables<<<dim3(512), dim3(256), 0, stream>>>(tabs);
  k_qkv<<<dim3(32, 8, 2), dim3(256), 0, stream>>>(X, Wq, Wk, Wv, tabs, Qh, Ql, Kh, Kl, Vh, Vl);
  k_ret<<<dim3(32, 8, 2), dim3(256), 0, stream>>>(Qh, Ql, Kh, Kl, Vh, Vl, Y);
  k_gnorm<<<dim3(8192), dim3(256), 0, stream>>>(Y, gw, gb, Yn);
  k_gemm<<<dim3(16, 64), dim3(256), 0, stream>>>(X, Wg, Yn, Ab, 1);
  k_gemm<<<dim3(16, 64), dim3(256), 0, stream>>>(Ab, Wo, nullptr, out, 0);
}

// Round 3
// 309.187 us; speedup vs baseline: 2.7222x; 1.5496x over previous
//
#include <hip/hip_runtime.h>
#include <math.h>

#define NB 2
#define SEQ 2048
#define HD 1024
#define NH 8
#define DH 128
#define HALF 64

typedef __bf16 bf16_t;
typedef __attribute__((ext_vector_type(8))) __bf16 bf16x8;
typedef __attribute__((ext_vector_type(4))) __bf16 bf16x4;
typedef __attribute__((ext_vector_type(4))) float f32x4;

// ---------------- xpos tables: sin_q, cos_q, sin_k, cos_k  (S x 64 each) ---
__global__ __launch_bounds__(256) void k_tables(float* __restrict__ tabs) {
  int idx = blockIdx.x * 256 + threadIdx.x;
  if (idx >= SEQ * HALF) return;
  int s = idx >> 6, i = idx & 63;
  float dd = (float)DH;
  float scale = (2.0f * (float)i + 0.4f * dd) / (1.4f * dd);
  float sc = expf(logf(scale) * ((float)s / 512.0f));
  float inv_freq = expf(-logf(10000.0f) * ((float)i / (float)HALF));
  float ang = (float)s * inv_freq;
  float sn, cs;
  sincosf(ang, &sn, &cs);
  float rsc = 1.0f / sc;
  tabs[idx]               = sn * sc;
  tabs[SEQ*HALF + idx]    = cs * sc;
  tabs[2*SEQ*HALF + idx]  = sn * rsc;
  tabs[3*SEQ*HALF + idx]  = cs * rsc;
}

// ---------------- transpose + hi/lo bf16 split of a weight matrix ----------
// in: fp32 [M][N] row-major (z-th matrix); out: bf16 [N][M] hi/lo.
__global__ __launch_bounds__(256) void k_wsplit(
    const float* __restrict__ in, bf16_t* __restrict__ oh,
    bf16_t* __restrict__ ol, int M, int N) {
  __shared__ float tile[64][65];
  int z = blockIdx.z;
  in += (size_t)z * M * N; oh += (size_t)z * M * N; ol += (size_t)z * M * N;
  int r0 = blockIdx.y * 64, c0 = blockIdx.x * 64;
  int t = threadIdx.x;
  for (int idx = t; idx < 1024; idx += 256) {
    int r = idx >> 4, c4 = (idx & 15) * 4;
    float4 v = *(const float4*)(in + (size_t)(r0 + r) * N + c0 + c4);
    *(float4*)&tile[r][c4] = v;
  }
  __syncthreads();
  for (int idx = t; idx < 1024; idx += 256) {
    int c = idx >> 4, r4 = (idx & 15) * 4;
    bf16x4 h, l;
    #pragma unroll
    for (int j = 0; j < 4; ++j) {
      float f = tile[r4 + j][c];
      bf16_t hb = (bf16_t)f;
      h[j] = hb;
      l[j] = (bf16_t)(f - (float)hb);
    }
    size_t off = (size_t)(c0 + c) * M + r0 + r4;
    *(bf16x4*)(oh + off) = h;
    *(bf16x4*)(ol + off) = l;
  }
}

// ---------------- QKV projection via MFMA bf16x3 + fused xpos --------------
// grid (S/64, NH, NB), 4 waves. X-frags split in registers; W^T hi/lo staged
// in swizzled LDS. Q/K: xpos in f32 epilogue (partner col via shfl_xor 1).
// V stored transposed [bh][d][s].
__global__ __launch_bounds__(256, 2) void k_qkv(
    const float* __restrict__ X, const float* __restrict__ tabs,
    const bf16_t* __restrict__ Wqth, const bf16_t* __restrict__ Wqtl,
    const bf16_t* __restrict__ Wkth, const bf16_t* __restrict__ Wktl,
    const bf16_t* __restrict__ Wvth, const bf16_t* __restrict__ Wvtl,
    bf16_t* __restrict__ Qh, bf16_t* __restrict__ Ql,
    bf16_t* __restrict__ Kh, bf16_t* __restrict__ Kl,
    bf16_t* __restrict__ Vh, bf16_t* __restrict__ Vl) {
  __shared__ bf16_t Wsh[128][128], Wsl[128][128];
  int t = threadIdx.x;
  int lane = t & 63, w = t >> 6;
  int lr = lane & 15, lg = lane >> 4;
  int s0 = blockIdx.x * 64;
  int hh = blockIdx.y;
  int b  = blockIdx.z;
  size_t bh = (size_t)(b*NH + hh);

  // X fragments: row s0+16w+lr, k-chunks 8*lg + 32*ks
  bf16x8 xh[4], xl[4];
  {
    const float* xp = X + ((size_t)(b*SEQ + s0 + 16*w + lr)) * HD + hh*DH + 8*lg;
    #pragma unroll
    for (int ks = 0; ks < 4; ++ks) {
      float4 u = *(const float4*)(xp + 32*ks);
      float4 v = *(const float4*)(xp + 32*ks + 4);
      float fv[8] = {u.x,u.y,u.z,u.w,v.x,v.y,v.z,v.w};
      #pragma unroll
      for (int j = 0; j < 8; ++j) {
        bf16_t hb = (bf16_t)fv[j];
        xh[ks][j] = hb;
        xl[ks][j] = (bf16_t)(fv[j] - (float)hb);
      }
    }
  }

  const bf16_t* Wh[3] = {Wqth, Wkth, Wvth};
  const bf16_t* Wl[3] = {Wqtl, Wktl, Wvtl};

  for (int which = 0; which < 3; ++which) {
    const bf16_t* wh = Wh[which] + bh % NH * (size_t)(DH*DH);
    const bf16_t* wl = Wl[which] + bh % NH * (size_t)(DH*DH);
    __syncthreads();
    for (int idx = t; idx < 2048; idx += 256) {
      int e = idx >> 4, kb = idx & 15;
      int kbs = kb ^ (e & 7);
      *(bf16x8*)&Wsh[e][kbs*8] = *(const bf16x8*)(wh + (size_t)e*DH + kb*8);
      *(bf16x8*)&Wsl[e][kbs*8] = *(const bf16x8*)(wl + (size_t)e*DH + kb*8);
    }
    __syncthreads();
    f32x4 yacc[8];
    #pragma unroll
    for (int i = 0; i < 8; ++i) yacc[i] = (f32x4){0.f,0.f,0.f,0.f};
    #pragma unroll
    for (int sub = 0; sub < 8; ++sub) {
      int e = 16*sub + lr;
      #pragma unroll
      for (int ks = 0; ks < 4; ++ks) {
        int ch = (lg + 4*ks) ^ (lr & 7);
        bf16x8 bhv = *(const bf16x8*)&Wsh[e][ch*8];
        bf16x8 blv = *(const bf16x8*)&Wsl[e][ch*8];
        yacc[sub] = __builtin_amdgcn_mfma_f32_16x16x32_bf16(xh[ks], bhv, yacc[sub], 0, 0, 0);
        yacc[sub] = __builtin_amdgcn_mfma_f32_16x16x32_bf16(xh[ks], blv, yacc[sub], 0, 0, 0);
        yacc[sub] = __builtin_amdgcn_mfma_f32_16x16x32_bf16(xl[ks], bhv, yacc[sub], 0, 0, 0);
      }
    }
    // epilogue: C row (s-local) = 16w+4lg+reg, col e = 16sub+lr
    if (which < 2) {
      const float* st = tabs + (which ? 2*SEQ*HALF : 0);
      const float* ct = st + SEQ*HALF;
      bf16_t* Hp = which ? Kh : Qh;
      bf16_t* Lp = which ? Kl : Ql;
      #pragma unroll
      for (int sub = 0; sub < 8; ++sub) {
        int e = 16*sub + lr;
        int i = e >> 1;
        #pragma unroll
        for (int reg = 0; reg < 4; ++reg) {
          float v = yacc[sub][reg];
          float p = __shfl_xor(v, 1);
          int srow = s0 + 16*w + 4*lg + reg;
          float sv = st[srow*HALF + i], cv = ct[srow*HALF + i];
          float o = v * cv + ((e & 1) ? p : -p) * sv;
          bf16_t oh = (bf16_t)o;
          size_t off = (bh*SEQ + srow) * DH + e;
          Hp[off] = oh;
          Lp[off] = (bf16_t)(o - (float)oh);
        }
      }
    } else {
      #pragma unroll
      for (int sub = 0; sub < 8; ++sub) {
        int e = 16*sub + lr;
        bf16x4 hv, lv;
        #pragma unroll
        for (int reg = 0; reg < 4; ++reg) {
          float f = yacc[sub][reg];
          bf16_t hb = (bf16_t)f;
          hv[reg] = hb;
          lv[reg] = (bf16_t)(f - (float)hb);
        }
        size_t off = bh * (size_t)(DH*SEQ) + (size_t)e*SEQ + (s0 + 16*w + 4*lg);
        *(bf16x4*)(Vh + off) = hv;
        *(bf16x4*)(Vl + off) = lv;
      }
    }
  }
}

// ---------------- retention via MFMA bf16x3 (unchanged from round 2) -------
__global__ __launch_bounds__(256, 2) void k_ret(
    const bf16_t* __restrict__ Qhig, const bf16_t* __restrict__ Qlog,
    const bf16_t* __restrict__ Khig, const bf16_t* __restrict__ Klog,
    const bf16_t* __restrict__ Vhig, const bf16_t* __restrict__ Vlog,
    float* __restrict__ Yo) {
  __shared__ bf16_t Kh[64][128], Kl[64][128];
  __shared__ bf16_t Vh[128][64], Vl[128][64];
  __shared__ bf16_t Ph[64][64], Pl[64][64];
  int t = threadIdx.x;
  int lane = t & 63, w = t >> 6;
  int lr = lane & 15, lg = lane >> 4;
  int bx = blockIdx.x, hh = blockIdx.y, b = blockIdx.z;
  int qsw = (bx & 1) ? (31 - (bx >> 1)) : (bx >> 1);
  int qt = b ? (31 - qsw) : qsw;
  int s0 = qt * 64;
  size_t base = (size_t)((b*NH + hh) * SEQ) * DH;

  double ga = log(1.0/32.0), gbb = log(1.0/512.0);
  float gamma = (float)(1.0 - exp(ga + (double)hh * (gbb - ga) / 7.0));
  float l2g = log2f(gamma);
  float colf = exp2f(-l2g * (float)lr);
  float g16v[4];
  #pragma unroll
  for (int ts = 0; ts < 4; ++ts) g16v[ts] = exp2f(-l2g * (float)(16*ts));

  bf16x8 qh[4], ql[4];
  {
    const bf16_t* qph = Qhig + base + (size_t)(s0 + 16*w + lr) * DH + lg * 8;
    const bf16_t* qpl = Qlog + base + (size_t)(s0 + 16*w + lr) * DH + lg * 8;
    #pragma unroll
    for (int ks = 0; ks < 4; ++ks) {
      qh[ks] = *(const bf16x8*)(qph + 32*ks);
      ql[ks] = *(const bf16x8*)(qpl + 32*ks);
    }
  }
  f32x4 yacc[8];
  #pragma unroll
  for (int i = 0; i < 8; ++i) yacc[i] = (f32x4){0.f,0.f,0.f,0.f};

  for (int kt = 0; kt <= qt; ++kt) {
    int t0 = kt * 64;
    __syncthreads();
    for (int idx = t; idx < 1024; idx += 256) {
      int r = idx >> 4, kb = idx & 15;
      int kbs = kb ^ (r & 7);
      *(bf16x8*)&Kh[r][kbs*8] = *(const bf16x8*)(Khig + base + (size_t)(t0 + r)*DH + kb*8);
      *(bf16x8*)&Kl[r][kbs*8] = *(const bf16x8*)(Klog + base + (size_t)(t0 + r)*DH + kb*8);
    }
    for (int idx = t; idx < 1024; idx += 256) {
      int d = idx >> 3, cb = idx & 7;
      int cbs = cb ^ (d & 7);
      *(bf16x8*)&Vh[d][cbs*8] = *(const bf16x8*)(Vhig + base + (size_t)d*SEQ + t0 + cb*8);
      *(bf16x8*)&Vl[d][cbs*8] = *(const bf16x8*)(Vlog + base + (size_t)d*SEQ + t0 + cb*8);
    }
    __syncthreads();

    float rowf[4];
    #pragma unroll
    for (int reg = 0; reg < 4; ++reg)
      rowf[reg] = exp2f(l2g * (float)(s0 + 16*w + 4*lg + reg - t0));

    #pragma unroll
    for (int ts = 0; ts < 4; ++ts) {
      f32x4 sacc = (f32x4){0.f,0.f,0.f,0.f};
      int trow = 16*ts + lr;
      #pragma unroll
      for (int ks = 0; ks < 4; ++ks) {
        int kbs = (4*ks + lg) ^ (trow & 7);
        bf16x8 kh = *(const bf16x8*)&Kh[trow][kbs*8];
        bf16x8 kl = *(const bf16x8*)&Kl[trow][kbs*8];
        sacc = __builtin_amdgcn_mfma_f32_16x16x32_bf16(qh[ks], kh, sacc, 0, 0, 0);
        sacc = __builtin_amdgcn_mfma_f32_16x16x32_bf16(qh[ks], kl, sacc, 0, 0, 0);
        sacc = __builtin_amdgcn_mfma_f32_16x16x32_bf16(ql[ks], kh, sacc, 0, 0, 0);
      }
      float cf = colf * g16v[ts];
      #pragma unroll
      for (int reg = 0; reg < 4; ++reg) {
        int qloc = 4*lg + reg;
        int diff = (s0 + 16*w + qloc) - (t0 + trow);
        float p = (diff >= 0) ? sacc[reg] * (rowf[reg] * cf) : 0.0f;
        bf16_t ph = (bf16_t)p;
        bf16_t pl = (bf16_t)(p - (float)ph);
        int cb = (trow >> 3) ^ (qloc & 7);
        Ph[16*w + qloc][cb*8 + (trow & 7)] = ph;
        Pl[16*w + qloc][cb*8 + (trow & 7)] = pl;
      }
    }
    #pragma unroll
    for (int ks = 0; ks < 2; ++ks) {
      int prow = 16*w + lr;
      int pcb = (4*ks + lg) ^ (lr & 7);
      bf16x8 pah = *(const bf16x8*)&Ph[prow][pcb*8];
      bf16x8 pal = *(const bf16x8*)&Pl[prow][pcb*8];
      #pragma unroll
      for (int sub = 0; sub < 8; ++sub) {
        int drow = 16*sub + lr;
        int vcb = (4*ks + lg) ^ (drow & 7);
        bf16x8 vh = *(const bf16x8*)&Vh[drow][vcb*8];
        bf16x8 vl = *(const bf16x8*)&Vl[drow][vcb*8];
        yacc[sub] = __builtin_amdgcn_mfma_f32_16x16x32_bf16(pah, vh, yacc[sub], 0, 0, 0);
        yacc[sub] = __builtin_amdgcn_mfma_f32_16x16x32_bf16(pah, vl, yacc[sub], 0, 0, 0);
        yacc[sub] = __builtin_amdgcn_mfma_f32_16x16x32_bf16(pal, vh, yacc[sub], 0, 0, 0);
      }
    }
  }
  #pragma unroll
  for (int sub = 0; sub < 8; ++sub) {
    #pragma unroll
    for (int reg = 0; reg < 4; ++reg) {
      int row = s0 + 16*w + 4*lg + reg;
      Yo[base + (size_t)row*DH + 16*sub + lr] = yacc[sub][reg];
    }
  }
}

// ---------------- groupnorm over (B*S*h, 128) + transpose to (B,S,H) -------
__global__ __launch_bounds__(256) void k_gnorm(
    const float* __restrict__ Y, const float* __restrict__ gw,
    const float* __restrict__ gb, float* __restrict__ Yn) {
  int wave = threadIdx.x >> 6, lane = threadIdx.x & 63;
  int g = blockIdx.x * 4 + wave;
  int b = g >> 14;
  int hh = (g >> 11) & 7;
  int s = g & 2047;
  const float* yp = Y + (size_t)g * DH;
  float v0 = yp[lane], v1 = yp[64 + lane];
  float s1 = v0 + v1, s2 = v0*v0 + v1*v1;
  #pragma unroll
  for (int off = 32; off; off >>= 1) {
    s1 += __shfl_xor(s1, off);
    s2 += __shfl_xor(s2, off);
  }
  float mean = s1 * (1.0f/128.0f);
  float var = s2 * (1.0f/128.0f) - mean*mean;
  float inv = rsqrtf(var + 1e-5f);
  int c0 = hh*DH + lane;
  float* op = Yn + (size_t)(b*SEQ + s) * HD;
  op[c0]      = (v0 - mean) * inv * gw[c0]    + gb[c0];
  op[c0 + 64] = (v1 - mean) * inv * gw[c0+64] + gb[c0+64];
}

// ---------------- MFMA bf16x3 GEMM, M=4096 N=1024 K=1024 -------------------
// tile 64(M)x128(N), BK=64, 4 waves. mode 1: A=X fp32 (split in staging),
// epilogue swish(G)*E -> split-store Oh/Ol. mode 0: A=Ah/Al bf16, out f32.
__global__ __launch_bounds__(256, 2) void k_gemm(
    const float* __restrict__ Af, const bf16_t* __restrict__ Ahg,
    const bf16_t* __restrict__ Alg,
    const bf16_t* __restrict__ Bh, const bf16_t* __restrict__ Bl,
    const float* __restrict__ E,
    bf16_t* __restrict__ Oh, bf16_t* __restrict__ Ol,
    float* __restrict__ Of, int mode) {
  __shared__ bf16_t Ash[64][64], Asl[64][64];
  __shared__ bf16_t Bsh[128][64], Bsl[128][64];
  int t = threadIdx.x;
  int lane = t & 63, w = t >> 6;
  int lr = lane & 15, lg = lane >> 4;
  int n0 = blockIdx.x * 128, m0 = blockIdx.y * 64;

  f32x4 yacc[8];
  #pragma unroll
  for (int i = 0; i < 8; ++i) yacc[i] = (f32x4){0.f,0.f,0.f,0.f};

  for (int k0 = 0; k0 < HD; k0 += 64) {
    __syncthreads();
    if (mode == 1) {
      for (int idx = t; idx < 512; idx += 256) {
        int m = idx >> 3, kb = idx & 7;
        const float* src = Af + (size_t)(m0 + m) * HD + k0 + kb*8;
        float4 u = *(const float4*)src;
        float4 v = *(const float4*)(src + 4);
        float fv[8] = {u.x,u.y,u.z,u.w,v.x,v.y,v.z,v.w};
        bf16x8 h, l;
        #pragma unroll
        for (int j = 0; j < 8; ++j) {
          bf16_t hb = (bf16_t)fv[j];
          h[j] = hb;
          l[j] = (bf16_t)(fv[j] - (float)hb);
        }
        int kbs = kb ^ (m & 7);
        *(bf16x8*)&Ash[m][kbs*8] = h;
        *(bf16x8*)&Asl[m][kbs*8] = l;
      }
    } else {
      for (int idx = t; idx < 512; idx += 256) {
        int m = idx >> 3, kb = idx & 7;
        int kbs = kb ^ (m & 7);
        *(bf16x8*)&Ash[m][kbs*8] = *(const bf16x8*)(Ahg + (size_t)(m0+m)*HD + k0 + kb*8);
        *(bf16x8*)&Asl[m][kbs*8] = *(const bf16x8*)(Alg + (size_t)(m0+m)*HD + k0 + kb*8);
      }
    }
    for (int idx = t; idx < 1024; idx += 256) {
      int n = idx >> 3, kb = idx & 7;
      int kbs = kb ^ (n & 7);
      *(bf16x8*)&Bsh[n][kbs*8] = *(const bf16x8*)(Bh + (size_t)(n0+n)*HD + k0 + kb*8);
      *(bf16x8*)&Bsl[n][kbs*8] = *(const bf16x8*)(Bl + (size_t)(n0+n)*HD + k0 + kb*8);
    }
    __syncthreads();
    bf16x8 ah[2], al[2];
    #pragma unroll
    for (int ks = 0; ks < 2; ++ks) {
      int ch = (lg + 4*ks) ^ (lr & 7);
      ah[ks] = *(const bf16x8*)&Ash[16*w + lr][ch*8];
      al[ks] = *(const bf16x8*)&Asl[16*w + lr][ch*8];
    }
    #pragma unroll
    for (int sub = 0; sub < 8; ++sub) {
      int n = 16*sub + lr;
      #pragma unroll
      for (int ks = 0; ks < 2; ++ks) {
        int ch = (lg + 4*ks) ^ (lr & 7);
        bf16x8 bhv = *(const bf16x8*)&Bsh[n][ch*8];
        bf16x8 blv = *(const bf16x8*)&Bsl[n][ch*8];
        yacc[sub] = __builtin_amdgcn_mfma_f32_16x16x32_bf16(ah[ks], bhv, yacc[sub], 0, 0, 0);
        yacc[sub] = __builtin_amdgcn_mfma_f32_16x16x32_bf16(ah[ks], blv, yacc[sub], 0, 0, 0);
        yacc[sub] = __builtin_amdgcn_mfma_f32_16x16x32_bf16(al[ks], bhv, yacc[sub], 0, 0, 0);
      }
    }
  }
  // epilogue: row m0+16w+4lg+reg, col n0+16sub+lr
  #pragma unroll
  for (int sub = 0; sub < 8; ++sub) {
    #pragma unroll
    for (int reg = 0; reg < 4; ++reg) {
      int m = m0 + 16*w + 4*lg + reg;
      int n = n0 + 16*sub + lr;
      float g = yacc[sub][reg];
      if (mode == 1) {
        float sg = 1.0f / (1.0f + expf(-g));
        float a = g * sg * E[(size_t)m * HD + n];
        bf16_t hb = (bf16_t)a;
        Oh[(size_t)m * HD + n] = hb;
        Ol[(size_t)m * HD + n] = (bf16_t)(a - (float)hb);
      } else {
        Of[(size_t)m * HD + n] = g;
      }
    }
  }
}

extern "C" void kernel_launch(void* const* d_in, const int* in_sizes, int n_in,
                              void* d_out, int out_size, void* d_ws, size_t ws_size,
                              hipStream_t stream) {
  const float* X  = (const float*)d_in[0];
  const float* Wq = (const float*)d_in[1];
  const float* Wk = (const float*)d_in[2];
  const float* Wv = (const float*)d_in[3];
  const float* Wg = (const float*)d_in[4];
  const float* Wo = (const float*)d_in[5];
  const float* gw = (const float*)d_in[6];
  const float* gb = (const float*)d_in[7];
  float* out = (float*)d_out;
  float* ws = (float*)d_ws;

  // workspace: tabs 2MB | QKV hi/lo 48MB | Y 16MB | Wqkv^T hi/lo 1.5MB |
  //            Wg^T/Wo^T hi/lo 8MB  (~75.5MB). Yn aliases Qh/Ql; A2 aliases Y.
  float* tabs = ws;
  bf16_t* Qh = (bf16_t*)(ws + 524288);
  bf16_t* Ql = Qh + 4194304;
  bf16_t* Kh = Ql + 4194304;
  bf16_t* Kl = Kh + 4194304;
  bf16_t* Vh = Kl + 4194304;
  bf16_t* Vl = Vh + 4194304;
  float*  Y  = (float*)(Vl + 4194304);
  bf16_t* Wqth = (bf16_t*)(Y + 4194304);
  bf16_t* Wqtl = Wqth + 131072;
  bf16_t* Wkth = Wqtl + 131072;
  bf16_t* Wktl = Wkth + 131072;
  bf16_t* Wvth = Wktl + 131072;
  bf16_t* Wvtl = Wvth + 131072;
  bf16_t* Wgth = Wvtl + 131072;
  bf16_t* Wgtl = Wgth + 1048576;
  bf16_t* Woth = Wgtl + 1048576;
  bf16_t* Wotl = Woth + 1048576;
  float*  Yn = (float*)Qh;         // 16MB alias (Q dead after k_ret)
  bf16_t* A2h = (bf16_t*)Y;        // 16MB alias (Y dead after k_gnorm)
  bf16_t* A2l = A2h + 4194304;

  k_tables<<<dim3(512), dim3(256), 0, stream>>>(tabs);
  k_wsplit<<<dim3(2, 2, 8), dim3(256), 0, stream>>>(Wq, Wqth, Wqtl, DH, DH);
  k_wsplit<<<dim3(2, 2, 8), dim3(256), 0, stream>>>(Wk, Wkth, Wktl, DH, DH);
  k_wsplit<<<dim3(2, 2, 8), dim3(256), 0, stream>>>(Wv, Wvth, Wvtl, DH, DH);
  k_wsplit<<<dim3(16, 16, 1), dim3(256), 0, stream>>>(Wg, Wgth, Wgtl, HD, HD);
  k_wsplit<<<dim3(16, 16, 1), dim3(256), 0, stream>>>(Wo, Woth, Wotl, HD, HD);
  k_qkv<<<dim3(32, 8, 2), dim3(256), 0, stream>>>(X, tabs, Wqth, Wqtl, Wkth, Wktl,
                                                  Wvth, Wvtl, Qh, Ql, Kh, Kl, Vh, Vl);
  k_ret<<<dim3(32, 8, 2), dim3(256), 0, stream>>>(Qh, Ql, Kh, Kl, Vh, Vl, Y);
  k_gnorm<<<dim3(8192), dim3(256), 0, stream>>>(Y, gw, gb, Yn);
  k_gemm<<<dim3(8, 64), dim3(256), 0, stream>>>(X, nullptr, nullptr, Wgth, Wgtl,
                                                Yn, A2h, A2l, nullptr, 1);
  k_gemm<<<dim3(8, 64), dim3(256), 0, stream>>>(nullptr, A2h, A2l, Woth, Wotl,
                                                nullptr, nullptr, nullptr, out, 0);
}

// Round 4
// 228.183 us; speedup vs baseline: 3.6885x; 1.3550x over previous
//
#include <hip/hip_runtime.h>
#include <math.h>

#define NB 2
#define SEQ 2048
#define HD 1024
#define NH 8
#define DH 128
#define HALF 64

typedef __bf16 bf16_t;
typedef __attribute__((ext_vector_type(8))) __bf16 bf16x8;
typedef __attribute__((ext_vector_type(4))) __bf16 bf16x4;
typedef __attribute__((ext_vector_type(4))) float f32x4;

__device__ __forceinline__ float head_l2g(int hh) {
  double ga = log(1.0/32.0), gbb = log(1.0/512.0);
  float gamma = (float)(1.0 - exp(ga + (double)hh * (gbb - ga) / 7.0));
  return log2f(gamma);
}

// ---------------- xpos tables: sin_q, cos_q, sin_k, cos_k  (S x 64 each) ---
__global__ __launch_bounds__(256) void k_tables(float* __restrict__ tabs) {
  int idx = blockIdx.x * 256 + threadIdx.x;
  if (idx >= SEQ * HALF) return;
  int s = idx >> 6, i = idx & 63;
  float dd = (float)DH;
  float scale = (2.0f * (float)i + 0.4f * dd) / (1.4f * dd);
  float sc = expf(logf(scale) * ((float)s / 512.0f));
  float inv_freq = expf(-logf(10000.0f) * ((float)i / (float)HALF));
  float ang = (float)s * inv_freq;
  float sn, cs;
  sincosf(ang, &sn, &cs);
  float rsc = 1.0f / sc;
  tabs[idx]               = sn * sc;
  tabs[SEQ*HALF + idx]    = cs * sc;
  tabs[2*SEQ*HALF + idx]  = sn * rsc;
  tabs[3*SEQ*HALF + idx]  = cs * rsc;
}

// ---------------- transpose + hi/lo bf16 split of a weight matrix ----------
__global__ __launch_bounds__(256) void k_wsplit(
    const float* __restrict__ in, bf16_t* __restrict__ oh,
    bf16_t* __restrict__ ol, int M, int N) {
  __shared__ float tile[64][65];
  int z = blockIdx.z;
  in += (size_t)z * M * N; oh += (size_t)z * M * N; ol += (size_t)z * M * N;
  int r0 = blockIdx.y * 64, c0 = blockIdx.x * 64;
  int t = threadIdx.x;
  for (int idx = t; idx < 1024; idx += 256) {
    int r = idx >> 4, c4 = (idx & 15) * 4;
    float4 v = *(const float4*)(in + (size_t)(r0 + r) * N + c0 + c4);
    *(float4*)&tile[r][c4] = v;
  }
  __syncthreads();
  for (int idx = t; idx < 1024; idx += 256) {
    int c = idx >> 4, r4 = (idx & 15) * 4;
    bf16x4 h, l;
    #pragma unroll
    for (int j = 0; j < 4; ++j) {
      float f = tile[r4 + j][c];
      bf16_t hb = (bf16_t)f;
      h[j] = hb;
      l[j] = (bf16_t)(f - (float)hb);
    }
    size_t off = (size_t)(c0 + c) * M + r0 + r4;
    *(bf16x4*)(oh + off) = h;
    *(bf16x4*)(ol + off) = l;
  }
}

// ---------------- QKV projection via MFMA bf16x3 + fused xpos --------------
__global__ __launch_bounds__(256, 2) void k_qkv(
    const float* __restrict__ X, const float* __restrict__ tabs,
    const bf16_t* __restrict__ Wqth, const bf16_t* __restrict__ Wqtl,
    const bf16_t* __restrict__ Wkth, const bf16_t* __restrict__ Wktl,
    const bf16_t* __restrict__ Wvth, const bf16_t* __restrict__ Wvtl,
    bf16_t* __restrict__ Qh, bf16_t* __restrict__ Ql,
    bf16_t* __restrict__ Kh, bf16_t* __restrict__ Kl,
    bf16_t* __restrict__ Vh, bf16_t* __restrict__ Vl) {
  __shared__ bf16_t Wsh[128][128], Wsl[128][128];
  int t = threadIdx.x;
  int lane = t & 63, w = t >> 6;
  int lr = lane & 15, lg = lane >> 4;
  int s0 = blockIdx.x * 64;
  int hh = blockIdx.y;
  int b  = blockIdx.z;
  size_t bh = (size_t)(b*NH + hh);

  bf16x8 xh[4], xl[4];
  {
    const float* xp = X + ((size_t)(b*SEQ + s0 + 16*w + lr)) * HD + hh*DH + 8*lg;
    #pragma unroll
    for (int ks = 0; ks < 4; ++ks) {
      float4 u = *(const float4*)(xp + 32*ks);
      float4 v = *(const float4*)(xp + 32*ks + 4);
      float fv[8] = {u.x,u.y,u.z,u.w,v.x,v.y,v.z,v.w};
      #pragma unroll
      for (int j = 0; j < 8; ++j) {
        bf16_t hb = (bf16_t)fv[j];
        xh[ks][j] = hb;
        xl[ks][j] = (bf16_t)(fv[j] - (float)hb);
      }
    }
  }

  const bf16_t* Wh[3] = {Wqth, Wkth, Wvth};
  const bf16_t* Wl[3] = {Wqtl, Wktl, Wvtl};

  for (int which = 0; which < 3; ++which) {
    const bf16_t* wh = Wh[which] + (size_t)hh * (DH*DH);
    const bf16_t* wl = Wl[which] + (size_t)hh * (DH*DH);
    __syncthreads();
    for (int idx = t; idx < 2048; idx += 256) {
      int e = idx >> 4, kb = idx & 15;
      int kbs = kb ^ (e & 7);
      *(bf16x8*)&Wsh[e][kbs*8] = *(const bf16x8*)(wh + (size_t)e*DH + kb*8);
      *(bf16x8*)&Wsl[e][kbs*8] = *(const bf16x8*)(wl + (size_t)e*DH + kb*8);
    }
    __syncthreads();
    f32x4 yacc[8];
    #pragma unroll
    for (int i = 0; i < 8; ++i) yacc[i] = (f32x4){0.f,0.f,0.f,0.f};
    #pragma unroll
    for (int sub = 0; sub < 8; ++sub) {
      int e = 16*sub + lr;
      #pragma unroll
      for (int ks = 0; ks < 4; ++ks) {
        int ch = (lg + 4*ks) ^ (lr & 7);
        bf16x8 bhv = *(const bf16x8*)&Wsh[e][ch*8];
        bf16x8 blv = *(const bf16x8*)&Wsl[e][ch*8];
        yacc[sub] = __builtin_amdgcn_mfma_f32_16x16x32_bf16(xh[ks], bhv, yacc[sub], 0, 0, 0);
        yacc[sub] = __builtin_amdgcn_mfma_f32_16x16x32_bf16(xh[ks], blv, yacc[sub], 0, 0, 0);
        yacc[sub] = __builtin_amdgcn_mfma_f32_16x16x32_bf16(xl[ks], bhv, yacc[sub], 0, 0, 0);
      }
    }
    if (which < 2) {
      const float* st = tabs + (which ? 2*SEQ*HALF : 0);
      const float* ct = st + SEQ*HALF;
      bf16_t* Hp = which ? Kh : Qh;
      bf16_t* Lp = which ? Kl : Ql;
      #pragma unroll
      for (int sub = 0; sub < 8; ++sub) {
        int e = 16*sub + lr;
        int i = e >> 1;
        #pragma unroll
        for (int reg = 0; reg < 4; ++reg) {
          float v = yacc[sub][reg];
          float p = __shfl_xor(v, 1);
          int srow = s0 + 16*w + 4*lg + reg;
          float sv = st[srow*HALF + i], cv = ct[srow*HALF + i];
          float o = v * cv + ((e & 1) ? p : -p) * sv;
          bf16_t oh = (bf16_t)o;
          size_t off = (bh*SEQ + srow) * DH + e;
          Hp[off] = oh;
          Lp[off] = (bf16_t)(o - (float)oh);
        }
      }
    } else {
      #pragma unroll
      for (int sub = 0; sub < 8; ++sub) {
        int e = 16*sub + lr;
        bf16x4 hv, lv;
        #pragma unroll
        for (int reg = 0; reg < 4; ++reg) {
          float f = yacc[sub][reg];
          bf16_t hb = (bf16_t)f;
          hv[reg] = hb;
          lv[reg] = (bf16_t)(f - (float)hb);
        }
        size_t off = bh * (size_t)(DH*SEQ) + (size_t)e*SEQ + (s0 + 16*w + 4*lg);
        *(bf16x4*)(Vh + off) = hv;
        *(bf16x4*)(Vl + off) = lv;
      }
    }
  }
}

// ---------------- delta: Dt[dv][dk] = sum_tau g^(127-tau) V[tau][dv] K[tau][dk]
// grid (16 chunks, 16 bh), 256 thr, 128KB LDS, uniform work.
__global__ __launch_bounds__(256, 1) void k_delta(
    const bf16_t* __restrict__ Khg, const bf16_t* __restrict__ Klg,
    const bf16_t* __restrict__ VTh, const bf16_t* __restrict__ VTl,
    bf16_t* __restrict__ DSth, bf16_t* __restrict__ DStl) {
  __shared__ bf16_t KTh[128][128], KTl[128][128];   // [dk][tau], chunk-swz
  __shared__ bf16_t Vdh[128][128], Vdl[128][128];   // [dv][tau], chunk-swz
  int t = threadIdx.x;
  int lane = t & 63, w = t >> 6;
  int lr = lane & 15, lg = lane >> 4;
  int c = blockIdx.x, bh = blockIdx.y, hh = bh & 7;
  float l2g = head_l2g(hh);
  size_t kbase = (size_t)bh * SEQ * DH + (size_t)c * 128 * DH;
  size_t vtb   = (size_t)bh * DH * SEQ + (size_t)c * 128;

  // stage K transposed: tau-major lanes -> scalar b16 writes spread over banks
  for (int idx = t; idx < 2048; idx += 256) {
    int dc = idx >> 7, tau = idx & 127;
    bf16x8 h8 = *(const bf16x8*)(Khg + kbase + (size_t)tau*DH + dc*8);
    bf16x8 l8 = *(const bf16x8*)(Klg + kbase + (size_t)tau*DH + dc*8);
    #pragma unroll
    for (int j = 0; j < 8; ++j) {
      int d = dc*8 + j;
      int col = (((tau>>3) ^ (d & 7)) << 3) | (tau & 7);
      KTh[d][col] = h8[j];
      KTl[d][col] = l8[j];
    }
  }
  // stage decayed V^T
  for (int idx = t; idx < 2048; idx += 256) {
    int dv = idx >> 4, tc = idx & 15;
    bf16x8 h8 = *(const bf16x8*)(VTh + vtb + (size_t)dv*SEQ + tc*8);
    bf16x8 l8 = *(const bf16x8*)(VTl + vtb + (size_t)dv*SEQ + tc*8);
    bf16x8 oh, ol;
    #pragma unroll
    for (int j = 0; j < 8; ++j) {
      int tau = tc*8 + j;
      float f = ((float)h8[j] + (float)l8[j]) * exp2f(l2g * (float)(127 - tau));
      bf16_t hb = (bf16_t)f;
      oh[j] = hb;
      ol[j] = (bf16_t)(f - (float)hb);
    }
    int cs = tc ^ (dv & 7);
    *(bf16x8*)&Vdh[dv][cs*8] = oh;
    *(bf16x8*)&Vdl[dv][cs*8] = ol;
  }
  __syncthreads();

  f32x4 acc[2][8];
  #pragma unroll
  for (int i = 0; i < 2; ++i)
    #pragma unroll
    for (int s = 0; s < 8; ++s) acc[i][s] = (f32x4){0.f,0.f,0.f,0.f};

  #pragma unroll
  for (int i = 0; i < 2; ++i) {
    int dv = 32*w + 16*i + lr;
    #pragma unroll
    for (int ks = 0; ks < 4; ++ks) {
      int ca = (lg + 4*ks) ^ (dv & 7);
      bf16x8 avh = *(const bf16x8*)&Vdh[dv][ca*8];
      bf16x8 avl = *(const bf16x8*)&Vdl[dv][ca*8];
      #pragma unroll
      for (int sub = 0; sub < 8; ++sub) {
        int dk = 16*sub + lr;
        int cb = (lg + 4*ks) ^ (dk & 7);
        bf16x8 bkh = *(const bf16x8*)&KTh[dk][cb*8];
        bf16x8 bkl = *(const bf16x8*)&KTl[dk][cb*8];
        acc[i][sub] = __builtin_amdgcn_mfma_f32_16x16x32_bf16(avh, bkh, acc[i][sub], 0, 0, 0);
        acc[i][sub] = __builtin_amdgcn_mfma_f32_16x16x32_bf16(avh, bkl, acc[i][sub], 0, 0, 0);
        acc[i][sub] = __builtin_amdgcn_mfma_f32_16x16x32_bf16(avl, bkh, acc[i][sub], 0, 0, 0);
      }
    }
  }
  size_t obase = ((size_t)bh * 16 + c) * 16384;
  #pragma unroll
  for (int i = 0; i < 2; ++i) {
    #pragma unroll
    for (int sub = 0; sub < 8; ++sub) {
      #pragma unroll
      for (int reg = 0; reg < 4; ++reg) {
        int dv = 32*w + 16*i + 4*lg + reg;
        int dk = 16*sub + lr;
        float f = acc[i][sub][reg];
        bf16_t hb = (bf16_t)f;
        size_t off = obase + (size_t)dv*128 + dk;
        DSth[off] = hb;
        DStl[off] = (bf16_t)(f - (float)hb);
      }
    }
  }
}

// ---------------- in-place prefix scan over chunks: DSt[c] Δ -> S_c --------
__global__ __launch_bounds__(256) void k_scan(
    bf16_t* __restrict__ DSth, bf16_t* __restrict__ DStl) {
  int t = threadIdx.x;
  int bh = blockIdx.y, hh = bh & 7;
  float l2g = head_l2g(hh);
  float g128 = exp2f(l2g * 128.0f);
  int dv = blockIdx.x * 16 + (t >> 4);
  int dk0 = (t & 15) * 8;
  size_t base = ((size_t)bh * 16) * 16384 + (size_t)dv*128 + dk0;
  float S[8] = {};
  for (int c = 0; c < 16; ++c) {
    size_t off = base + (size_t)c * 16384;
    bf16x8 dh = *(const bf16x8*)(DSth + off);
    bf16x8 dl = *(const bf16x8*)(DStl + off);
    bf16x8 sh, sl;
    #pragma unroll
    for (int j = 0; j < 8; ++j) {
      bf16_t hb = (bf16_t)S[j];
      sh[j] = hb;
      sl[j] = (bf16_t)(S[j] - (float)hb);
    }
    *(bf16x8*)(DSth + off) = sh;
    *(bf16x8*)(DStl + off) = sl;
    #pragma unroll
    for (int j = 0; j < 8; ++j)
      S[j] = g128*S[j] + ((float)dh[j] + (float)dl[j]);
  }
}

// ---------------- retention: cross (Q·S^T) + intra, uniform chunks ---------
// grid (16 chunks, 16 bh), 512 thr (8 waves x 16 q-rows), 96KB LDS.
__global__ __launch_bounds__(512, 1) void k_ret(
    const bf16_t* __restrict__ Qhig, const bf16_t* __restrict__ Qlog,
    const bf16_t* __restrict__ Khig, const bf16_t* __restrict__ Klog,
    const bf16_t* __restrict__ VThg, const bf16_t* __restrict__ VTlg,
    const bf16_t* __restrict__ DSth, const bf16_t* __restrict__ DStl,
    float* __restrict__ Yo) {
  __shared__ bf16_t Ksh[64][128], Ksl[64][128];
  __shared__ bf16_t Vsh[128][64], Vsl[128][64];
  __shared__ bf16_t Ph[128][64], Pl[128][64];
  int t = threadIdx.x;
  int lane = t & 63, w = t >> 6;          // 8 waves
  int lr = lane & 15, lg = lane >> 4;
  int c = blockIdx.x, bh = blockIdx.y, hh = bh & 7;
  int s0 = c * 128;
  size_t base  = (size_t)bh * SEQ * DH;
  size_t vbase = (size_t)bh * DH * SEQ;
  float l2g = head_l2g(hh);
  float colf = exp2f(-l2g * (float)lr);
  float g16v[4];
  #pragma unroll
  for (int ts = 0; ts < 4; ++ts) g16v[ts] = exp2f(-l2g * (float)(16*ts));

  // Q fragments: row s0 + 16w + lr
  bf16x8 qh[4], ql[4];
  {
    const bf16_t* qph = Qhig + base + (size_t)(s0 + 16*w + lr) * DH + lg * 8;
    const bf16_t* qpl = Qlog + base + (size_t)(s0 + 16*w + lr) * DH + lg * 8;
    #pragma unroll
    for (int ks = 0; ks < 4; ++ks) {
      qh[ks] = *(const bf16x8*)(qph + 32*ks);
      ql[ks] = *(const bf16x8*)(qpl + 32*ks);
    }
  }
  f32x4 yacc[8];
  #pragma unroll
  for (int i = 0; i < 8; ++i) yacc[i] = (f32x4){0.f,0.f,0.f,0.f};

  // ---- stage intra tile 0 (keys s0..s0+63) ----
  for (int idx = t; idx < 1024; idx += 512) {
    int r = idx >> 4, kb = idx & 15;
    int kbs = kb ^ (r & 7);
    *(bf16x8*)&Ksh[r][kbs*8] = *(const bf16x8*)(Khig + base + (size_t)(s0 + r)*DH + kb*8);
    *(bf16x8*)&Ksl[r][kbs*8] = *(const bf16x8*)(Klog + base + (size_t)(s0 + r)*DH + kb*8);
  }
  for (int idx = t; idx < 1024; idx += 512) {
    int d = idx >> 3, cb = idx & 7;
    int cbs = cb ^ (d & 7);
    *(bf16x8*)&Vsh[d][cbs*8] = *(const bf16x8*)(VThg + vbase + (size_t)d*SEQ + s0 + cb*8);
    *(bf16x8*)&Vsl[d][cbs*8] = *(const bf16x8*)(VTlg + vbase + (size_t)d*SEQ + s0 + cb*8);
  }

  // ---- cross: yacc = Q · S^T  (B-frags straight from global; no LDS) ----
  {
    const bf16_t* sth = DSth + ((size_t)bh * 16 + c) * 16384;
    const bf16_t* stl = DStl + ((size_t)bh * 16 + c) * 16384;
    #pragma unroll
    for (int sub = 0; sub < 8; ++sub) {
      size_t ro = (size_t)(16*sub + lr) * 128 + 8*lg;
      #pragma unroll
      for (int ks = 0; ks < 4; ++ks) {
        bf16x8 bh_ = *(const bf16x8*)(sth + ro + 32*ks);
        bf16x8 bl_ = *(const bf16x8*)(stl + ro + 32*ks);
        yacc[sub] = __builtin_amdgcn_mfma_f32_16x16x32_bf16(qh[ks], bh_, yacc[sub], 0, 0, 0);
        yacc[sub] = __builtin_amdgcn_mfma_f32_16x16x32_bf16(qh[ks], bl_, yacc[sub], 0, 0, 0);
        yacc[sub] = __builtin_amdgcn_mfma_f32_16x16x32_bf16(ql[ks], bh_, yacc[sub], 0, 0, 0);
      }
    }
    float rowc[4];
    #pragma unroll
    for (int reg = 0; reg < 4; ++reg)
      rowc[reg] = exp2f(l2g * (float)(16*w + 4*lg + reg + 1));   // gamma^(tau+1)
    #pragma unroll
    for (int sub = 0; sub < 8; ++sub)
      #pragma unroll
      for (int reg = 0; reg < 4; ++reg)
        yacc[sub][reg] *= rowc[reg];
  }
  __syncthreads();

  // ---- intra tiles: kt=0 (all waves), kt=1 (waves 4-7 only) ----
  for (int kt = 0; kt < 2; ++kt) {
    int t0 = kt * 64;
    if (kt == 1) {
      __syncthreads();   // all waves done reading tile 0
      for (int idx = t; idx < 1024; idx += 512) {
        int r = idx >> 4, kb = idx & 15;
        int kbs = kb ^ (r & 7);
        *(bf16x8*)&Ksh[r][kbs*8] = *(const bf16x8*)(Khig + base + (size_t)(s0 + 64 + r)*DH + kb*8);
        *(bf16x8*)&Ksl[r][kbs*8] = *(const bf16x8*)(Klog + base + (size_t)(s0 + 64 + r)*DH + kb*8);
      }
      for (int idx = t; idx < 1024; idx += 512) {
        int d = idx >> 3, cb = idx & 7;
        int cbs = cb ^ (d & 7);
        *(bf16x8*)&Vsh[d][cbs*8] = *(const bf16x8*)(VThg + vbase + (size_t)d*SEQ + s0 + 64 + cb*8);
        *(bf16x8*)&Vsl[d][cbs*8] = *(const bf16x8*)(VTlg + vbase + (size_t)d*SEQ + s0 + 64 + cb*8);
      }
    }
    __syncthreads();
    if (kt == 1 && w < 4) break;   // idle waves exit after final barrier

    float rowf[4];
    #pragma unroll
    for (int reg = 0; reg < 4; ++reg)
      rowf[reg] = exp2f(l2g * (float)(16*w + 4*lg + reg - t0));

    #pragma unroll
    for (int ts = 0; ts < 4; ++ts) {
      f32x4 sacc = (f32x4){0.f,0.f,0.f,0.f};
      int trow = 16*ts + lr;
      #pragma unroll
      for (int ks = 0; ks < 4; ++ks) {
        int kbs = (4*ks + lg) ^ (trow & 7);
        bf16x8 kh8 = *(const bf16x8*)&Ksh[trow][kbs*8];
        bf16x8 kl8 = *(const bf16x8*)&Ksl[trow][kbs*8];
        sacc = __builtin_amdgcn_mfma_f32_16x16x32_bf16(qh[ks], kh8, sacc, 0, 0, 0);
        sacc = __builtin_amdgcn_mfma_f32_16x16x32_bf16(qh[ks], kl8, sacc, 0, 0, 0);
        sacc = __builtin_amdgcn_mfma_f32_16x16x32_bf16(ql[ks], kh8, sacc, 0, 0, 0);
      }
      float cf = colf * g16v[ts];
      #pragma unroll
      for (int reg = 0; reg < 4; ++reg) {
        int qloc = 4*lg + reg;
        int diff = (16*w + qloc) - (t0 + trow);
        float p = (diff >= 0) ? sacc[reg] * (rowf[reg] * cf) : 0.0f;
        bf16_t ph = (bf16_t)p;
        bf16_t pl = (bf16_t)(p - (float)ph);
        int cb = (trow >> 3) ^ (qloc & 7);
        Ph[16*w + qloc][cb*8 + (trow & 7)] = ph;
        Pl[16*w + qloc][cb*8 + (trow & 7)] = pl;
      }
    }
    #pragma unroll
    for (int ks = 0; ks < 2; ++ks) {
      int prow = 16*w + lr;
      int pcb = (4*ks + lg) ^ (lr & 7);
      bf16x8 pah = *(const bf16x8*)&Ph[prow][pcb*8];
      bf16x8 pal = *(const bf16x8*)&Pl[prow][pcb*8];
      #pragma unroll
      for (int sub = 0; sub < 8; ++sub) {
        int drow = 16*sub + lr;
        int vcb = (4*ks + lg) ^ (drow & 7);
        bf16x8 vh8 = *(const bf16x8*)&Vsh[drow][vcb*8];
        bf16x8 vl8 = *(const bf16x8*)&Vsl[drow][vcb*8];
        yacc[sub] = __builtin_amdgcn_mfma_f32_16x16x32_bf16(pah, vh8, yacc[sub], 0, 0, 0);
        yacc[sub] = __builtin_amdgcn_mfma_f32_16x16x32_bf16(pah, vl8, yacc[sub], 0, 0, 0);
        yacc[sub] = __builtin_amdgcn_mfma_f32_16x16x32_bf16(pal, vh8, yacc[sub], 0, 0, 0);
      }
    }
  }
  #pragma unroll
  for (int sub = 0; sub < 8; ++sub) {
    #pragma unroll
    for (int reg = 0; reg < 4; ++reg) {
      int row = s0 + 16*w + 4*lg + reg;
      Yo[base + (size_t)row*DH + 16*sub + lr] = yacc[sub][reg];
    }
  }
}

// ---------------- groupnorm over (B*S*h, 128) + transpose to (B,S,H) -------
__global__ __launch_bounds__(256) void k_gnorm(
    const float* __restrict__ Y, const float* __restrict__ gw,
    const float* __restrict__ gb, float* __restrict__ Yn) {
  int wave = threadIdx.x >> 6, lane = threadIdx.x & 63;
  int g = blockIdx.x * 4 + wave;
  int b = g >> 14;
  int hh = (g >> 11) & 7;
  int s = g & 2047;
  const float* yp = Y + (size_t)g * DH;
  float v0 = yp[lane], v1 = yp[64 + lane];
  float s1 = v0 + v1, s2 = v0*v0 + v1*v1;
  #pragma unroll
  for (int off = 32; off; off >>= 1) {
    s1 += __shfl_xor(s1, off);
    s2 += __shfl_xor(s2, off);
  }
  float mean = s1 * (1.0f/128.0f);
  float var = s2 * (1.0f/128.0f) - mean*mean;
  float inv = rsqrtf(var + 1e-5f);
  int c0 = hh*DH + lane;
  float* op = Yn + (size_t)(b*SEQ + s) * HD;
  op[c0]      = (v0 - mean) * inv * gw[c0]    + gb[c0];
  op[c0 + 64] = (v1 - mean) * inv * gw[c0+64] + gb[c0+64];
}

// ---------------- MFMA bf16x3 GEMM, M=4096 N=1024 K=1024 -------------------
__global__ __launch_bounds__(256, 2) void k_gemm(
    const float* __restrict__ Af, const bf16_t* __restrict__ Ahg,
    const bf16_t* __restrict__ Alg,
    const bf16_t* __restrict__ Bh, const bf16_t* __restrict__ Bl,
    const float* __restrict__ E,
    bf16_t* __restrict__ Oh, bf16_t* __restrict__ Ol,
    float* __restrict__ Of, int mode) {
  __shared__ bf16_t Ash[64][64], Asl[64][64];
  __shared__ bf16_t Bsh[128][64], Bsl[128][64];
  int t = threadIdx.x;
  int lane = t & 63, w = t >> 6;
  int lr = lane & 15, lg = lane >> 4;
  int n0 = blockIdx.x * 128, m0 = blockIdx.y * 64;

  f32x4 yacc[8];
  #pragma unroll
  for (int i = 0; i < 8; ++i) yacc[i] = (f32x4){0.f,0.f,0.f,0.f};

  for (int k0 = 0; k0 < HD; k0 += 64) {
    __syncthreads();
    if (mode == 1) {
      for (int idx = t; idx < 512; idx += 256) {
        int m = idx >> 3, kb = idx & 7;
        const float* src = Af + (size_t)(m0 + m) * HD + k0 + kb*8;
        float4 u = *(const float4*)src;
        float4 v = *(const float4*)(src + 4);
        float fv[8] = {u.x,u.y,u.z,u.w,v.x,v.y,v.z,v.w};
        bf16x8 h, l;
        #pragma unroll
        for (int j = 0; j < 8; ++j) {
          bf16_t hb = (bf16_t)fv[j];
          h[j] = hb;
          l[j] = (bf16_t)(fv[j] - (float)hb);
        }
        int kbs = kb ^ (m & 7);
        *(bf16x8*)&Ash[m][kbs*8] = h;
        *(bf16x8*)&Asl[m][kbs*8] = l;
      }
    } else {
      for (int idx = t; idx < 512; idx += 256) {
        int m = idx >> 3, kb = idx & 7;
        int kbs = kb ^ (m & 7);
        *(bf16x8*)&Ash[m][kbs*8] = *(const bf16x8*)(Ahg + (size_t)(m0+m)*HD + k0 + kb*8);
        *(bf16x8*)&Asl[m][kbs*8] = *(const bf16x8*)(Alg + (size_t)(m0+m)*HD + k0 + kb*8);
      }
    }
    for (int idx = t; idx < 1024; idx += 256) {
      int n = idx >> 3, kb = idx & 7;
      int kbs = kb ^ (n & 7);
      *(bf16x8*)&Bsh[n][kbs*8] = *(const bf16x8*)(Bh + (size_t)(n0+n)*HD + k0 + kb*8);
      *(bf16x8*)&Bsl[n][kbs*8] = *(const bf16x8*)(Bl + (size_t)(n0+n)*HD + k0 + kb*8);
    }
    __syncthreads();
    bf16x8 ah[2], al[2];
    #pragma unroll
    for (int ks = 0; ks < 2; ++ks) {
      int ch = (lg + 4*ks) ^ (lr & 7);
      ah[ks] = *(const bf16x8*)&Ash[16*w + lr][ch*8];
      al[ks] = *(const bf16x8*)&Asl[16*w + lr][ch*8];
    }
    #pragma unroll
    for (int sub = 0; sub < 8; ++sub) {
      int n = 16*sub + lr;
      #pragma unroll
      for (int ks = 0; ks < 2; ++ks) {
        int ch = (lg + 4*ks) ^ (lr & 7);
        bf16x8 bhv = *(const bf16x8*)&Bsh[n][ch*8];
        bf16x8 blv = *(const bf16x8*)&Bsl[n][ch*8];
        yacc[sub] = __builtin_amdgcn_mfma_f32_16x16x32_bf16(ah[ks], bhv, yacc[sub], 0, 0, 0);
        yacc[sub] = __builtin_amdgcn_mfma_f32_16x16x32_bf16(ah[ks], blv, yacc[sub], 0, 0, 0);
        yacc[sub] = __builtin_amdgcn_mfma_f32_16x16x32_bf16(al[ks], bhv, yacc[sub], 0, 0, 0);
      }
    }
  }
  #pragma unroll
  for (int sub = 0; sub < 8; ++sub) {
    #pragma unroll
    for (int reg = 0; reg < 4; ++reg) {
      int m = m0 + 16*w + 4*lg + reg;
      int n = n0 + 16*sub + lr;
      float g = yacc[sub][reg];
      if (mode == 1) {
        float sg = 1.0f / (1.0f + expf(-g));
        float a = g * sg * E[(size_t)m * HD + n];
        bf16_t hb = (bf16_t)a;
        Oh[(size_t)m * HD + n] = hb;
        Ol[(size_t)m * HD + n] = (bf16_t)(a - (float)hb);
      } else {
        Of[(size_t)m * HD + n] = g;
      }
    }
  }
}

extern "C" void kernel_launch(void* const* d_in, const int* in_sizes, int n_in,
                              void* d_out, int out_size, void* d_ws, size_t ws_size,
                              hipStream_t stream) {
  const float* X  = (const float*)d_in[0];
  const float* Wq = (const float*)d_in[1];
  const float* Wk = (const float*)d_in[2];
  const float* Wv = (const float*)d_in[3];
  const float* Wg = (const float*)d_in[4];
  const float* Wo = (const float*)d_in[5];
  const float* gw = (const float*)d_in[6];
  const float* gb = (const float*)d_in[7];
  float* out = (float*)d_out;
  float* ws = (float*)d_ws;

  // ws: tabs 2.1 | Q/K/VT hi-lo 50.3 | Y 16.8 | DSt hi-lo 16.8 | W 10  (~96MB)
  float* tabs = ws;
  bf16_t* Qh  = (bf16_t*)(ws + 524288);
  bf16_t* Ql  = Qh + 4194304;
  bf16_t* Kh  = Ql + 4194304;
  bf16_t* Kl  = Kh + 4194304;
  bf16_t* VTh = Kl + 4194304;
  bf16_t* VTl = VTh + 4194304;
  float*  Y   = (float*)(VTl + 4194304);
  bf16_t* DSth = (bf16_t*)(Y + 4194304);
  bf16_t* DStl = DSth + 4194304;
  bf16_t* Wqth = DStl + 4194304;
  bf16_t* Wqtl = Wqth + 131072;
  bf16_t* Wkth = Wqtl + 131072;
  bf16_t* Wktl = Wkth + 131072;
  bf16_t* Wvth = Wktl + 131072;
  bf16_t* Wvtl = Wvth + 131072;
  bf16_t* Wgth = Wvtl + 131072;
  bf16_t* Wgtl = Wgth + 1048576;
  bf16_t* Woth = Wgtl + 1048576;
  bf16_t* Wotl = Woth + 1048576;
  float*  Yn  = (float*)Qh;        // Q dead after k_ret
  bf16_t* A2h = (bf16_t*)Y;        // Y dead after k_gnorm
  bf16_t* A2l = A2h + 4194304;

  k_tables<<<dim3(512), dim3(256), 0, stream>>>(tabs);
  k_wsplit<<<dim3(2, 2, 8), dim3(256), 0, stream>>>(Wq, Wqth, Wqtl, DH, DH);
  k_wsplit<<<dim3(2, 2, 8), dim3(256), 0, stream>>>(Wk, Wkth, Wktl, DH, DH);
  k_wsplit<<<dim3(2, 2, 8), dim3(256), 0, stream>>>(Wv, Wvth, Wvtl, DH, DH);
  k_wsplit<<<dim3(16, 16, 1), dim3(256), 0, stream>>>(Wg, Wgth, Wgtl, HD, HD);
  k_wsplit<<<dim3(16, 16, 1), dim3(256), 0, stream>>>(Wo, Woth, Wotl, HD, HD);
  k_qkv<<<dim3(32, 8, 2), dim3(256), 0, stream>>>(X, tabs, Wqth, Wqtl, Wkth, Wktl,
                                                  Wvth, Wvtl, Qh, Ql, Kh, Kl, VTh, VTl);
  k_delta<<<dim3(16, 16), dim3(256), 0, stream>>>(Kh, Kl, VTh, VTl, DSth, DStl);
  k_scan<<<dim3(8, 16), dim3(256), 0, stream>>>(DSth, DStl);
  k_ret<<<dim3(16, 16), dim3(512), 0, stream>>>(Qh, Ql, Kh, Kl, VTh, VTl,
                                                DSth, DStl, Y);
  k_gnorm<<<dim3(8192), dim3(256), 0, stream>>>(Y, gw, gb, Yn);
  k_gemm<<<dim3(8, 64), dim3(256), 0, stream>>>(X, nullptr, nullptr, Wgth, Wgtl,
                                                Yn, A2h, A2l, nullptr, 1);
  k_gemm<<<dim3(8, 64), dim3(256), 0, stream>>>(nullptr, A2h, A2l, Woth, Wotl,
                                                nullptr, nullptr, nullptr, out, 0);
}

// Round 5
// 210.480 us; speedup vs baseline: 3.9988x; 1.0841x over previous
//
#include <hip/hip_runtime.h>
#include <math.h>

#define NB 2
#define SEQ 2048
#define HD 1024
#define NH 8
#define DH 128
#define HALF 64

typedef __bf16 bf16_t;
typedef __attribute__((ext_vector_type(8))) __bf16 bf16x8;
typedef __attribute__((ext_vector_type(4))) __bf16 bf16x4;
typedef __attribute__((ext_vector_type(4))) float f32x4;

typedef __attribute__((address_space(1))) void gvoid;
typedef __attribute__((address_space(3))) void lvoid;

__device__ __forceinline__ void gld16(const bf16_t* g, bf16_t* l) {
  __builtin_amdgcn_global_load_lds((gvoid*)g, (lvoid*)l, 16, 0, 0);
}

__device__ __forceinline__ float head_l2g(int hh) {
  double ga = log(1.0/32.0), gbb = log(1.0/512.0);
  float gamma = (float)(1.0 - exp(ga + (double)hh * (gbb - ga) / 7.0));
  return log2f(gamma);
}

// ---------------- xpos tables: sin_q, cos_q, sin_k, cos_k  (S x 64 each) ---
__global__ __launch_bounds__(256) void k_tables(float* __restrict__ tabs) {
  int idx = blockIdx.x * 256 + threadIdx.x;
  if (idx >= SEQ * HALF) return;
  int s = idx >> 6, i = idx & 63;
  float dd = (float)DH;
  float scale = (2.0f * (float)i + 0.4f * dd) / (1.4f * dd);
  float sc = expf(logf(scale) * ((float)s / 512.0f));
  float inv_freq = expf(-logf(10000.0f) * ((float)i / (float)HALF));
  float ang = (float)s * inv_freq;
  float sn, cs;
  sincosf(ang, &sn, &cs);
  float rsc = 1.0f / sc;
  tabs[idx]               = sn * sc;
  tabs[SEQ*HALF + idx]    = cs * sc;
  tabs[2*SEQ*HALF + idx]  = sn * rsc;
  tabs[3*SEQ*HALF + idx]  = cs * rsc;
}

// ---------------- transpose + hi/lo bf16 split of a weight matrix ----------
__global__ __launch_bounds__(256) void k_wsplit(
    const float* __restrict__ in, bf16_t* __restrict__ oh,
    bf16_t* __restrict__ ol, int M, int N) {
  __shared__ float tile[64][65];
  int z = blockIdx.z;
  in += (size_t)z * M * N; oh += (size_t)z * M * N; ol += (size_t)z * M * N;
  int r0 = blockIdx.y * 64, c0 = blockIdx.x * 64;
  int t = threadIdx.x;
  for (int idx = t; idx < 1024; idx += 256) {
    int r = idx >> 4, c4 = (idx & 15) * 4;
    float4 v = *(const float4*)(in + (size_t)(r0 + r) * N + c0 + c4);
    *(float4*)&tile[r][c4] = v;
  }
  __syncthreads();
  for (int idx = t; idx < 1024; idx += 256) {
    int c = idx >> 4, r4 = (idx & 15) * 4;
    bf16x4 h, l;
    #pragma unroll
    for (int j = 0; j < 4; ++j) {
      float f = tile[r4 + j][c];
      bf16_t hb = (bf16_t)f;
      h[j] = hb;
      l[j] = (bf16_t)(f - (float)hb);
    }
    size_t off = (size_t)(c0 + c) * M + r0 + r4;
    *(bf16x4*)(oh + off) = h;
    *(bf16x4*)(ol + off) = l;
  }
}

// ---------------- X fp32 -> hi/lo bf16 split (row-major pass-through) ------
__global__ __launch_bounds__(256) void k_xsplit(
    const float* __restrict__ X, bf16_t* __restrict__ Xh, bf16_t* __restrict__ Xl) {
  size_t i = ((size_t)blockIdx.x * 256 + threadIdx.x) * 8;
  float4 u = *(const float4*)(X + i);
  float4 v = *(const float4*)(X + i + 4);
  float fv[8] = {u.x,u.y,u.z,u.w,v.x,v.y,v.z,v.w};
  bf16x8 h, l;
  #pragma unroll
  for (int j = 0; j < 8; ++j) {
    bf16_t hb = (bf16_t)fv[j];
    h[j] = hb;
    l[j] = (bf16_t)(fv[j] - (float)hb);
  }
  *(bf16x8*)(Xh + i) = h;
  *(bf16x8*)(Xl + i) = l;
}

// ---------------- QKV projection via MFMA bf16x3 + fused xpos --------------
__global__ __launch_bounds__(256, 2) void k_qkv(
    const float* __restrict__ X, const float* __restrict__ tabs,
    const bf16_t* __restrict__ Wqth, const bf16_t* __restrict__ Wqtl,
    const bf16_t* __restrict__ Wkth, const bf16_t* __restrict__ Wktl,
    const bf16_t* __restrict__ Wvth, const bf16_t* __restrict__ Wvtl,
    bf16_t* __restrict__ Qh, bf16_t* __restrict__ Ql,
    bf16_t* __restrict__ Kh, bf16_t* __restrict__ Kl,
    bf16_t* __restrict__ Vh, bf16_t* __restrict__ Vl) {
  __shared__ bf16_t Wsh[128][128], Wsl[128][128];
  int t = threadIdx.x;
  int lane = t & 63, w = t >> 6;
  int lr = lane & 15, lg = lane >> 4;
  int s0 = blockIdx.x * 64;
  int hh = blockIdx.y;
  int b  = blockIdx.z;
  size_t bh = (size_t)(b*NH + hh);

  bf16x8 xh[4], xl[4];
  {
    const float* xp = X + ((size_t)(b*SEQ + s0 + 16*w + lr)) * HD + hh*DH + 8*lg;
    #pragma unroll
    for (int ks = 0; ks < 4; ++ks) {
      float4 u = *(const float4*)(xp + 32*ks);
      float4 v = *(const float4*)(xp + 32*ks + 4);
      float fv[8] = {u.x,u.y,u.z,u.w,v.x,v.y,v.z,v.w};
      #pragma unroll
      for (int j = 0; j < 8; ++j) {
        bf16_t hb = (bf16_t)fv[j];
        xh[ks][j] = hb;
        xl[ks][j] = (bf16_t)(fv[j] - (float)hb);
      }
    }
  }

  const bf16_t* Wh[3] = {Wqth, Wkth, Wvth};
  const bf16_t* Wl[3] = {Wqtl, Wktl, Wvtl};

  for (int which = 0; which < 3; ++which) {
    const bf16_t* wh = Wh[which] + (size_t)hh * (DH*DH);
    const bf16_t* wl = Wl[which] + (size_t)hh * (DH*DH);
    __syncthreads();
    for (int idx = t; idx < 2048; idx += 256) {
      int e = idx >> 4, kb = idx & 15;
      int kbs = kb ^ (e & 7);
      *(bf16x8*)&Wsh[e][kbs*8] = *(const bf16x8*)(wh + (size_t)e*DH + kb*8);
      *(bf16x8*)&Wsl[e][kbs*8] = *(const bf16x8*)(wl + (size_t)e*DH + kb*8);
    }
    __syncthreads();
    f32x4 yacc[8];
    #pragma unroll
    for (int i = 0; i < 8; ++i) yacc[i] = (f32x4){0.f,0.f,0.f,0.f};
    #pragma unroll
    for (int sub = 0; sub < 8; ++sub) {
      int e = 16*sub + lr;
      #pragma unroll
      for (int ks = 0; ks < 4; ++ks) {
        int ch = (lg + 4*ks) ^ (lr & 7);
        bf16x8 bhv = *(const bf16x8*)&Wsh[e][ch*8];
        bf16x8 blv = *(const bf16x8*)&Wsl[e][ch*8];
        yacc[sub] = __builtin_amdgcn_mfma_f32_16x16x32_bf16(xh[ks], bhv, yacc[sub], 0, 0, 0);
        yacc[sub] = __builtin_amdgcn_mfma_f32_16x16x32_bf16(xh[ks], blv, yacc[sub], 0, 0, 0);
        yacc[sub] = __builtin_amdgcn_mfma_f32_16x16x32_bf16(xl[ks], bhv, yacc[sub], 0, 0, 0);
      }
    }
    if (which < 2) {
      const float* st = tabs + (which ? 2*SEQ*HALF : 0);
      const float* ct = st + SEQ*HALF;
      bf16_t* Hp = which ? Kh : Qh;
      bf16_t* Lp = which ? Kl : Ql;
      #pragma unroll
      for (int sub = 0; sub < 8; ++sub) {
        int e = 16*sub + lr;
        int i = e >> 1;
        #pragma unroll
        for (int reg = 0; reg < 4; ++reg) {
          float v = yacc[sub][reg];
          float p = __shfl_xor(v, 1);
          int srow = s0 + 16*w + 4*lg + reg;
          float sv = st[srow*HALF + i], cv = ct[srow*HALF + i];
          float o = v * cv + ((e & 1) ? p : -p) * sv;
          bf16_t oh = (bf16_t)o;
          size_t off = (bh*SEQ + srow) * DH + e;
          Hp[off] = oh;
          Lp[off] = (bf16_t)(o - (float)oh);
        }
      }
    } else {
      #pragma unroll
      for (int sub = 0; sub < 8; ++sub) {
        int e = 16*sub + lr;
        bf16x4 hv, lv;
        #pragma unroll
        for (int reg = 0; reg < 4; ++reg) {
          float f = yacc[sub][reg];
          bf16_t hb = (bf16_t)f;
          hv[reg] = hb;
          lv[reg] = (bf16_t)(f - (float)hb);
        }
        size_t off = bh * (size_t)(DH*SEQ) + (size_t)e*SEQ + (s0 + 16*w + 4*lg);
        *(bf16x4*)(Vh + off) = hv;
        *(bf16x4*)(Vl + off) = lv;
      }
    }
  }
}

// ---------------- delta: Dt[dv][dk] = sum_tau g^(127-tau) V[tau][dv] K[tau][dk]
__global__ __launch_bounds__(256, 1) void k_delta(
    const bf16_t* __restrict__ Khg, const bf16_t* __restrict__ Klg,
    const bf16_t* __restrict__ VTh, const bf16_t* __restrict__ VTl,
    bf16_t* __restrict__ DSth, bf16_t* __restrict__ DStl) {
  __shared__ bf16_t KTh[128][128], KTl[128][128];   // [dk][tau], chunk-swz
  __shared__ bf16_t Vdh[128][128], Vdl[128][128];   // [dv][tau], chunk-swz
  int t = threadIdx.x;
  int lane = t & 63, w = t >> 6;
  int lr = lane & 15, lg = lane >> 4;
  int c = blockIdx.x, bh = blockIdx.y, hh = bh & 7;
  float l2g = head_l2g(hh);
  size_t kbase = (size_t)bh * SEQ * DH + (size_t)c * 128 * DH;
  size_t vtb   = (size_t)bh * DH * SEQ + (size_t)c * 128;

  for (int idx = t; idx < 2048; idx += 256) {
    int dc = idx >> 7, tau = idx & 127;
    bf16x8 h8 = *(const bf16x8*)(Khg + kbase + (size_t)tau*DH + dc*8);
    bf16x8 l8 = *(const bf16x8*)(Klg + kbase + (size_t)tau*DH + dc*8);
    #pragma unroll
    for (int j = 0; j < 8; ++j) {
      int d = dc*8 + j;
      int col = (((tau>>3) ^ (d & 7)) << 3) | (tau & 7);
      KTh[d][col] = h8[j];
      KTl[d][col] = l8[j];
    }
  }
  for (int idx = t; idx < 2048; idx += 256) {
    int dv = idx >> 4, tc = idx & 15;
    bf16x8 h8 = *(const bf16x8*)(VTh + vtb + (size_t)dv*SEQ + tc*8);
    bf16x8 l8 = *(const bf16x8*)(VTl + vtb + (size_t)dv*SEQ + tc*8);
    bf16x8 oh, ol;
    #pragma unroll
    for (int j = 0; j < 8; ++j) {
      int tau = tc*8 + j;
      float f = ((float)h8[j] + (float)l8[j]) * exp2f(l2g * (float)(127 - tau));
      bf16_t hb = (bf16_t)f;
      oh[j] = hb;
      ol[j] = (bf16_t)(f - (float)hb);
    }
    int cs = tc ^ (dv & 7);
    *(bf16x8*)&Vdh[dv][cs*8] = oh;
    *(bf16x8*)&Vdl[dv][cs*8] = ol;
  }
  __syncthreads();

  f32x4 acc[2][8];
  #pragma unroll
  for (int i = 0; i < 2; ++i)
    #pragma unroll
    for (int s = 0; s < 8; ++s) acc[i][s] = (f32x4){0.f,0.f,0.f,0.f};

  #pragma unroll
  for (int i = 0; i < 2; ++i) {
    int dv = 32*w + 16*i + lr;
    #pragma unroll
    for (int ks = 0; ks < 4; ++ks) {
      int ca = (lg + 4*ks) ^ (dv & 7);
      bf16x8 avh = *(const bf16x8*)&Vdh[dv][ca*8];
      bf16x8 avl = *(const bf16x8*)&Vdl[dv][ca*8];
      #pragma unroll
      for (int sub = 0; sub < 8; ++sub) {
        int dk = 16*sub + lr;
        int cb = (lg + 4*ks) ^ (dk & 7);
        bf16x8 bkh = *(const bf16x8*)&KTh[dk][cb*8];
        bf16x8 bkl = *(const bf16x8*)&KTl[dk][cb*8];
        acc[i][sub] = __builtin_amdgcn_mfma_f32_16x16x32_bf16(avh, bkh, acc[i][sub], 0, 0, 0);
        acc[i][sub] = __builtin_amdgcn_mfma_f32_16x16x32_bf16(avh, bkl, acc[i][sub], 0, 0, 0);
        acc[i][sub] = __builtin_amdgcn_mfma_f32_16x16x32_bf16(avl, bkh, acc[i][sub], 0, 0, 0);
      }
    }
  }
  size_t obase = ((size_t)bh * 16 + c) * 16384;
  #pragma unroll
  for (int i = 0; i < 2; ++i) {
    #pragma unroll
    for (int sub = 0; sub < 8; ++sub) {
      #pragma unroll
      for (int reg = 0; reg < 4; ++reg) {
        int dv = 32*w + 16*i + 4*lg + reg;
        int dk = 16*sub + lr;
        float f = acc[i][sub][reg];
        bf16_t hb = (bf16_t)f;
        size_t off = obase + (size_t)dv*128 + dk;
        DSth[off] = hb;
        DStl[off] = (bf16_t)(f - (float)hb);
      }
    }
  }
}

// ---------------- in-place prefix scan over chunks: DSt[c] Δ -> S_c --------
__global__ __launch_bounds__(256) void k_scan(
    bf16_t* __restrict__ DSth, bf16_t* __restrict__ DStl) {
  int t = threadIdx.x;
  int bh = blockIdx.y, hh = bh & 7;
  float l2g = head_l2g(hh);
  float g128 = exp2f(l2g * 128.0f);
  int dv = blockIdx.x * 16 + (t >> 4);
  int dk0 = (t & 15) * 8;
  size_t base = ((size_t)bh * 16) * 16384 + (size_t)dv*128 + dk0;
  float S[8] = {};
  for (int c = 0; c < 16; ++c) {
    size_t off = base + (size_t)c * 16384;
    bf16x8 dh = *(const bf16x8*)(DSth + off);
    bf16x8 dl = *(const bf16x8*)(DStl + off);
    bf16x8 sh, sl;
    #pragma unroll
    for (int j = 0; j < 8; ++j) {
      bf16_t hb = (bf16_t)S[j];
      sh[j] = hb;
      sl[j] = (bf16_t)(S[j] - (float)hb);
    }
    *(bf16x8*)(DSth + off) = sh;
    *(bf16x8*)(DStl + off) = sl;
    #pragma unroll
    for (int j = 0; j < 8; ++j)
      S[j] = g128*S[j] + ((float)dh[j] + (float)dl[j]);
  }
}

// ---------------- retention: cross (Q·S^T) + intra, uniform chunks ---------
__global__ __launch_bounds__(512, 1) void k_ret(
    const bf16_t* __restrict__ Qhig, const bf16_t* __restrict__ Qlog,
    const bf16_t* __restrict__ Khig, const bf16_t* __restrict__ Klog,
    const bf16_t* __restrict__ VThg, const bf16_t* __restrict__ VTlg,
    const bf16_t* __restrict__ DSth, const bf16_t* __restrict__ DStl,
    float* __restrict__ Yo) {
  __shared__ bf16_t Ksh[64][128], Ksl[64][128];
  __shared__ bf16_t Vsh[128][64], Vsl[128][64];
  __shared__ bf16_t Ph[128][64], Pl[128][64];
  int t = threadIdx.x;
  int lane = t & 63, w = t >> 6;          // 8 waves
  int lr = lane & 15, lg = lane >> 4;
  int c = blockIdx.x, bh = blockIdx.y, hh = bh & 7;
  int s0 = c * 128;
  size_t base  = (size_t)bh * SEQ * DH;
  size_t vbase = (size_t)bh * DH * SEQ;
  float l2g = head_l2g(hh);
  float colf = exp2f(-l2g * (float)lr);
  float g16v[4];
  #pragma unroll
  for (int ts = 0; ts < 4; ++ts) g16v[ts] = exp2f(-l2g * (float)(16*ts));

  bf16x8 qh[4], ql[4];
  {
    const bf16_t* qph = Qhig + base + (size_t)(s0 + 16*w + lr) * DH + lg * 8;
    const bf16_t* qpl = Qlog + base + (size_t)(s0 + 16*w + lr) * DH + lg * 8;
    #pragma unroll
    for (int ks = 0; ks < 4; ++ks) {
      qh[ks] = *(const bf16x8*)(qph + 32*ks);
      ql[ks] = *(const bf16x8*)(qpl + 32*ks);
    }
  }
  f32x4 yacc[8];
  #pragma unroll
  for (int i = 0; i < 8; ++i) yacc[i] = (f32x4){0.f,0.f,0.f,0.f};

  for (int idx = t; idx < 1024; idx += 512) {
    int r = idx >> 4, kb = idx & 15;
    int kbs = kb ^ (r & 7);
    *(bf16x8*)&Ksh[r][kbs*8] = *(const bf16x8*)(Khig + base + (size_t)(s0 + r)*DH + kb*8);
    *(bf16x8*)&Ksl[r][kbs*8] = *(const bf16x8*)(Klog + base + (size_t)(s0 + r)*DH + kb*8);
  }
  for (int idx = t; idx < 1024; idx += 512) {
    int d = idx >> 3, cb = idx & 7;
    int cbs = cb ^ (d & 7);
    *(bf16x8*)&Vsh[d][cbs*8] = *(const bf16x8*)(VThg + vbase + (size_t)d*SEQ + s0 + cb*8);
    *(bf16x8*)&Vsl[d][cbs*8] = *(const bf16x8*)(VTlg + vbase + (size_t)d*SEQ + s0 + cb*8);
  }

  {
    const bf16_t* sth = DSth + ((size_t)bh * 16 + c) * 16384;
    const bf16_t* stl = DStl + ((size_t)bh * 16 + c) * 16384;
    #pragma unroll
    for (int sub = 0; sub < 8; ++sub) {
      size_t ro = (size_t)(16*sub + lr) * 128 + 8*lg;
      #pragma unroll
      for (int ks = 0; ks < 4; ++ks) {
        bf16x8 bh_ = *(const bf16x8*)(sth + ro + 32*ks);
        bf16x8 bl_ = *(const bf16x8*)(stl + ro + 32*ks);
        yacc[sub] = __builtin_amdgcn_mfma_f32_16x16x32_bf16(qh[ks], bh_, yacc[sub], 0, 0, 0);
        yacc[sub] = __builtin_amdgcn_mfma_f32_16x16x32_bf16(qh[ks], bl_, yacc[sub], 0, 0, 0);
        yacc[sub] = __builtin_amdgcn_mfma_f32_16x16x32_bf16(ql[ks], bh_, yacc[sub], 0, 0, 0);
      }
    }
    float rowc[4];
    #pragma unroll
    for (int reg = 0; reg < 4; ++reg)
      rowc[reg] = exp2f(l2g * (float)(16*w + 4*lg + reg + 1));
    #pragma unroll
    for (int sub = 0; sub < 8; ++sub)
      #pragma unroll
      for (int reg = 0; reg < 4; ++reg)
        yacc[sub][reg] *= rowc[reg];
  }
  __syncthreads();

  for (int kt = 0; kt < 2; ++kt) {
    int t0 = kt * 64;
    if (kt == 1) {
      __syncthreads();
      for (int idx = t; idx < 1024; idx += 512) {
        int r = idx >> 4, kb = idx & 15;
        int kbs = kb ^ (r & 7);
        *(bf16x8*)&Ksh[r][kbs*8] = *(const bf16x8*)(Khig + base + (size_t)(s0 + 64 + r)*DH + kb*8);
        *(bf16x8*)&Ksl[r][kbs*8] = *(const bf16x8*)(Klog + base + (size_t)(s0 + 64 + r)*DH + kb*8);
      }
      for (int idx = t; idx < 1024; idx += 512) {
        int d = idx >> 3, cb = idx & 7;
        int cbs = cb ^ (d & 7);
        *(bf16x8*)&Vsh[d][cbs*8] = *(const bf16x8*)(VThg + vbase + (size_t)d*SEQ + s0 + 64 + cb*8);
        *(bf16x8*)&Vsl[d][cbs*8] = *(const bf16x8*)(VTlg + vbase + (size_t)d*SEQ + s0 + 64 + cb*8);
      }
    }
    __syncthreads();
    if (kt == 1 && w < 4) break;

    float rowf[4];
    #pragma unroll
    for (int reg = 0; reg < 4; ++reg)
      rowf[reg] = exp2f(l2g * (float)(16*w + 4*lg + reg - t0));

    #pragma unroll
    for (int ts = 0; ts < 4; ++ts) {
      f32x4 sacc = (f32x4){0.f,0.f,0.f,0.f};
      int trow = 16*ts + lr;
      #pragma unroll
      for (int ks = 0; ks < 4; ++ks) {
        int kbs = (4*ks + lg) ^ (trow & 7);
        bf16x8 kh8 = *(const bf16x8*)&Ksh[trow][kbs*8];
        bf16x8 kl8 = *(const bf16x8*)&Ksl[trow][kbs*8];
        sacc = __builtin_amdgcn_mfma_f32_16x16x32_bf16(qh[ks], kh8, sacc, 0, 0, 0);
        sacc = __builtin_amdgcn_mfma_f32_16x16x32_bf16(qh[ks], kl8, sacc, 0, 0, 0);
        sacc = __builtin_amdgcn_mfma_f32_16x16x32_bf16(ql[ks], kh8, sacc, 0, 0, 0);
      }
      float cf = colf * g16v[ts];
      #pragma unroll
      for (int reg = 0; reg < 4; ++reg) {
        int qloc = 4*lg + reg;
        int diff = (16*w + qloc) - (t0 + trow);
        float p = (diff >= 0) ? sacc[reg] * (rowf[reg] * cf) : 0.0f;
        bf16_t ph = (bf16_t)p;
        bf16_t pl = (bf16_t)(p - (float)ph);
        int cb = (trow >> 3) ^ (qloc & 7);
        Ph[16*w + qloc][cb*8 + (trow & 7)] = ph;
        Pl[16*w + qloc][cb*8 + (trow & 7)] = pl;
      }
    }
    #pragma unroll
    for (int ks = 0; ks < 2; ++ks) {
      int prow = 16*w + lr;
      int pcb = (4*ks + lg) ^ (lr & 7);
      bf16x8 pah = *(const bf16x8*)&Ph[prow][pcb*8];
      bf16x8 pal = *(const bf16x8*)&Pl[prow][pcb*8];
      #pragma unroll
      for (int sub = 0; sub < 8; ++sub) {
        int drow = 16*sub + lr;
        int vcb = (4*ks + lg) ^ (drow & 7);
        bf16x8 vh8 = *(const bf16x8*)&Vsh[drow][vcb*8];
        bf16x8 vl8 = *(const bf16x8*)&Vsl[drow][vcb*8];
        yacc[sub] = __builtin_amdgcn_mfma_f32_16x16x32_bf16(pah, vh8, yacc[sub], 0, 0, 0);
        yacc[sub] = __builtin_amdgcn_mfma_f32_16x16x32_bf16(pah, vl8, yacc[sub], 0, 0, 0);
        yacc[sub] = __builtin_amdgcn_mfma_f32_16x16x32_bf16(pal, vh8, yacc[sub], 0, 0, 0);
      }
    }
  }
  #pragma unroll
  for (int sub = 0; sub < 8; ++sub) {
    #pragma unroll
    for (int reg = 0; reg < 4; ++reg) {
      int row = s0 + 16*w + 4*lg + reg;
      Yo[base + (size_t)row*DH + 16*sub + lr] = yacc[sub][reg];
    }
  }
}

// ---------------- groupnorm over (B*S*h, 128) + transpose to (B,S,H) -------
__global__ __launch_bounds__(256) void k_gnorm(
    const float* __restrict__ Y, const float* __restrict__ gw,
    const float* __restrict__ gb, float* __restrict__ Yn) {
  int wave = threadIdx.x >> 6, lane = threadIdx.x & 63;
  int g = blockIdx.x * 4 + wave;
  int b = g >> 14;
  int hh = (g >> 11) & 7;
  int s = g & 2047;
  const float* yp = Y + (size_t)g * DH;
  float v0 = yp[lane], v1 = yp[64 + lane];
  float s1 = v0 + v1, s2 = v0*v0 + v1*v1;
  #pragma unroll
  for (int off = 32; off; off >>= 1) {
    s1 += __shfl_xor(s1, off);
    s2 += __shfl_xor(s2, off);
  }
  float mean = s1 * (1.0f/128.0f);
  float var = s2 * (1.0f/128.0f) - mean*mean;
  float inv = rsqrtf(var + 1e-5f);
  int c0 = hh*DH + lane;
  float* op = Yn + (size_t)(b*SEQ + s) * HD;
  op[c0]      = (v0 - mean) * inv * gw[c0]    + gb[c0];
  op[c0 + 64] = (v1 - mean) * inv * gw[c0+64] + gb[c0+64];
}

// ---------------- MFMA bf16x3 GEMM, 128x128 tile, gld_lds staging ----------
// A: Ah/Al bf16 [M][K] row-major. B: Bh/Bl bf16 [N][K] (W^T).
// mode 1: epilogue swish(G)*E -> split-store Oh/Ol. mode 0: fp32 out Of.
__global__ __launch_bounds__(256, 2) void k_gemm(
    const bf16_t* __restrict__ Ahg, const bf16_t* __restrict__ Alg,
    const bf16_t* __restrict__ Bhg, const bf16_t* __restrict__ Blg,
    const float* __restrict__ E,
    bf16_t* __restrict__ Oh, bf16_t* __restrict__ Ol,
    float* __restrict__ Of, int mode) {
  __shared__ bf16_t Ah[128][64], Al[128][64];
  __shared__ bf16_t Bh[128][64], Bl[128][64];
  int t = threadIdx.x;
  int lane = t & 63, w = t >> 6;
  int lr = lane & 15, lg = lane >> 4;
  int wr = w >> 1, wc = w & 1;          // wave quadrant (2x2 of 64x64)
  int n0 = blockIdx.x * 128, m0 = blockIdx.y * 128;

  f32x4 acc[4][4];
  #pragma unroll
  for (int i = 0; i < 4; ++i)
    #pragma unroll
    for (int j = 0; j < 4; ++j) acc[i][j] = (f32x4){0.f,0.f,0.f,0.f};

  // staging geometry: wave w covers rows [w*32, w*32+32) of each buffer;
  // per 1KB inst: lane l -> row_local l>>3, chunk l&7; source pre-swizzled.
  int srow_in = (lane >> 3);            // 0..7
  int schunk = lane & 7;

  for (int k0 = 0; k0 < HD; k0 += 64) {
    __syncthreads();
    #pragma unroll
    for (int i = 0; i < 4; ++i) {
      int row = w*32 + i*8 + srow_in;
      int kc = (schunk ^ (row & 7)) * 8;
      const bf16_t* as_h = Ahg + (size_t)(m0 + row) * HD + k0 + kc;
      const bf16_t* as_l = Alg + (size_t)(m0 + row) * HD + k0 + kc;
      const bf16_t* bs_h = Bhg + (size_t)(n0 + row) * HD + k0 + kc;
      const bf16_t* bs_l = Blg + (size_t)(n0 + row) * HD + k0 + kc;
      gld16(as_h, &Ah[w*32 + i*8][0]);
      gld16(as_l, &Al[w*32 + i*8][0]);
      gld16(bs_h, &Bh[w*32 + i*8][0]);
      gld16(bs_l, &Bl[w*32 + i*8][0]);
    }
    __syncthreads();
    #pragma unroll
    for (int ks = 0; ks < 2; ++ks) {
      bf16x8 ah_[4], al_[4], bh_[4], bl_[4];
      #pragma unroll
      for (int mf = 0; mf < 4; ++mf) {
        int row = wr*64 + mf*16 + lr;
        int ch = (lg + 4*ks) ^ (row & 7);
        ah_[mf] = *(const bf16x8*)&Ah[row][ch*8];
        al_[mf] = *(const bf16x8*)&Al[row][ch*8];
      }
      #pragma unroll
      for (int nf = 0; nf < 4; ++nf) {
        int row = wc*64 + nf*16 + lr;
        int ch = (lg + 4*ks) ^ (row & 7);
        bh_[nf] = *(const bf16x8*)&Bh[row][ch*8];
        bl_[nf] = *(const bf16x8*)&Bl[row][ch*8];
      }
      #pragma unroll
      for (int mf = 0; mf < 4; ++mf)
        #pragma unroll
        for (int nf = 0; nf < 4; ++nf) {
          acc[mf][nf] = __builtin_amdgcn_mfma_f32_16x16x32_bf16(ah_[mf], bh_[nf], acc[mf][nf], 0, 0, 0);
          acc[mf][nf] = __builtin_amdgcn_mfma_f32_16x16x32_bf16(ah_[mf], bl_[nf], acc[mf][nf], 0, 0, 0);
          acc[mf][nf] = __builtin_amdgcn_mfma_f32_16x16x32_bf16(al_[mf], bh_[nf], acc[mf][nf], 0, 0, 0);
        }
    }
  }
  #pragma unroll
  for (int mf = 0; mf < 4; ++mf) {
    #pragma unroll
    for (int nf = 0; nf < 4; ++nf) {
      #pragma unroll
      for (int reg = 0; reg < 4; ++reg) {
        int m = m0 + wr*64 + mf*16 + 4*lg + reg;
        int n = n0 + wc*64 + nf*16 + lr;
        float g = acc[mf][nf][reg];
        size_t off = (size_t)m * HD + n;
        if (mode == 1) {
          float sg = 1.0f / (1.0f + expf(-g));
          float a = g * sg * E[off];
          bf16_t hb = (bf16_t)a;
          Oh[off] = hb;
          Ol[off] = (bf16_t)(a - (float)hb);
        } else {
          Of[off] = g;
        }
      }
    }
  }
}

extern "C" void kernel_launch(void* const* d_in, const int* in_sizes, int n_in,
                              void* d_out, int out_size, void* d_ws, size_t ws_size,
                              hipStream_t stream) {
  const float* X  = (const float*)d_in[0];
  const float* Wq = (const float*)d_in[1];
  const float* Wk = (const float*)d_in[2];
  const float* Wv = (const float*)d_in[3];
  const float* Wg = (const float*)d_in[4];
  const float* Wo = (const float*)d_in[5];
  const float* gw = (const float*)d_in[6];
  const float* gb = (const float*)d_in[7];
  float* out = (float*)d_out;
  float* ws = (float*)d_ws;

  // ws: tabs 2.1 | Q/K/VT hi-lo 50.3 | Y 16.8 | DSt hi-lo 16.8 | W 10  (~96MB)
  float* tabs = ws;
  bf16_t* Qh  = (bf16_t*)(ws + 524288);
  bf16_t* Ql  = Qh + 4194304;
  bf16_t* Kh  = Ql + 4194304;
  bf16_t* Kl  = Kh + 4194304;
  bf16_t* VTh = Kl + 4194304;
  bf16_t* VTl = VTh + 4194304;
  float*  Y   = (float*)(VTl + 4194304);
  bf16_t* DSth = (bf16_t*)(Y + 4194304);
  bf16_t* DStl = DSth + 4194304;
  bf16_t* Wqth = DStl + 4194304;
  bf16_t* Wqtl = Wqth + 131072;
  bf16_t* Wkth = Wqtl + 131072;
  bf16_t* Wktl = Wkth + 131072;
  bf16_t* Wvth = Wktl + 131072;
  bf16_t* Wvtl = Wvth + 131072;
  bf16_t* Wgth = Wvtl + 131072;
  bf16_t* Wgtl = Wgth + 1048576;
  bf16_t* Woth = Wgtl + 1048576;
  bf16_t* Wotl = Woth + 1048576;
  float*  Yn  = (float*)Qh;        // Q dead after k_ret
  bf16_t* A2h = (bf16_t*)Y;        // Y dead after k_gnorm
  bf16_t* A2l = A2h + 4194304;
  bf16_t* Xh  = Kh;                // K dead after k_ret (split after k_gnorm)
  bf16_t* Xl  = Kl;

  k_tables<<<dim3(512), dim3(256), 0, stream>>>(tabs);
  k_wsplit<<<dim3(2, 2, 8), dim3(256), 0, stream>>>(Wq, Wqth, Wqtl, DH, DH);
  k_wsplit<<<dim3(2, 2, 8), dim3(256), 0, stream>>>(Wk, Wkth, Wktl, DH, DH);
  k_wsplit<<<dim3(2, 2, 8), dim3(256), 0, stream>>>(Wv, Wvth, Wvtl, DH, DH);
  k_wsplit<<<dim3(16, 16, 1), dim3(256), 0, stream>>>(Wg, Wgth, Wgtl, HD, HD);
  k_wsplit<<<dim3(16, 16, 1), dim3(256), 0, stream>>>(Wo, Woth, Wotl, HD, HD);
  k_qkv<<<dim3(32, 8, 2), dim3(256), 0, stream>>>(X, tabs, Wqth, Wqtl, Wkth, Wktl,
                                                  Wvth, Wvtl, Qh, Ql, Kh, Kl, VTh, VTl);
  k_delta<<<dim3(16, 16), dim3(256), 0, stream>>>(Kh, Kl, VTh, VTl, DSth, DStl);
  k_scan<<<dim3(8, 16), dim3(256), 0, stream>>>(DSth, DStl);
  k_ret<<<dim3(16, 16), dim3(512), 0, stream>>>(Qh, Ql, Kh, Kl, VTh, VTl,
                                                DSth, DStl, Y);
  k_gnorm<<<dim3(8192), dim3(256), 0, stream>>>(Y, gw, gb, Yn);
  k_xsplit<<<dim3(2048), dim3(256), 0, stream>>>(X, Xh, Xl);
  k_gemm<<<dim3(8, 32), dim3(256), 0, stream>>>(Xh, Xl, Wgth, Wgtl,
                                                Yn, A2h, A2l, nullptr, 1);
  k_gemm<<<dim3(8, 32), dim3(256), 0, stream>>>(A2h, A2l, Woth, Wotl,
                                                nullptr, nullptr, nullptr, out, 0);
}

// Round 6
// 174.387 us; speedup vs baseline: 4.8264x; 1.2070x over previous
//
#include <hip/hip_runtime.h>
#include <math.h>

#define NB 2
#define SEQ 2048
#define HD 1024
#define NH 8
#define DH 128
#define HALF 64

typedef __bf16 bf16_t;
typedef __attribute__((ext_vector_type(8))) __bf16 bf16x8;
typedef __attribute__((ext_vector_type(4))) __bf16 bf16x4;
typedef __attribute__((ext_vector_type(4))) float f32x4;

typedef __attribute__((address_space(1))) void gvoid;
typedef __attribute__((address_space(3))) void lvoid;

__device__ __forceinline__ void gld16(const bf16_t* g, bf16_t* l) {
  __builtin_amdgcn_global_load_lds((gvoid*)g, (lvoid*)l, 16, 0, 0);
}

__device__ __forceinline__ float head_l2g(int hh) {
  double ga = log(1.0/32.0), gbb = log(1.0/512.0);
  float gamma = (float)(1.0 - exp(ga + (double)hh * (gbb - ga) / 7.0));
  return log2f(gamma);
}

// ---------------- xpos tables: sin_q, cos_q, sin_k, cos_k  (S x 64 each) ---
__global__ __launch_bounds__(256) void k_tables(float* __restrict__ tabs) {
  int idx = blockIdx.x * 256 + threadIdx.x;
  if (idx >= SEQ * HALF) return;
  int s = idx >> 6, i = idx & 63;
  float dd = (float)DH;
  float scale = (2.0f * (float)i + 0.4f * dd) / (1.4f * dd);
  float sc = expf(logf(scale) * ((float)s / 512.0f));
  float inv_freq = expf(-logf(10000.0f) * ((float)i / (float)HALF));
  float ang = (float)s * inv_freq;
  float sn, cs;
  sincosf(ang, &sn, &cs);
  float rsc = 1.0f / sc;
  tabs[idx]               = sn * sc;
  tabs[SEQ*HALF + idx]    = cs * sc;
  tabs[2*SEQ*HALF + idx]  = sn * rsc;
  tabs[3*SEQ*HALF + idx]  = cs * rsc;
}

// ---------------- transpose + hi/lo bf16 split of a weight matrix ----------
__global__ __launch_bounds__(256) void k_wsplit(
    const float* __restrict__ in, bf16_t* __restrict__ oh,
    bf16_t* __restrict__ ol, int M, int N) {
  __shared__ float tile[64][65];
  int z = blockIdx.z;
  in += (size_t)z * M * N; oh += (size_t)z * M * N; ol += (size_t)z * M * N;
  int r0 = blockIdx.y * 64, c0 = blockIdx.x * 64;
  int t = threadIdx.x;
  for (int idx = t; idx < 1024; idx += 256) {
    int r = idx >> 4, c4 = (idx & 15) * 4;
    float4 v = *(const float4*)(in + (size_t)(r0 + r) * N + c0 + c4);
    *(float4*)&tile[r][c4] = v;
  }
  __syncthreads();
  for (int idx = t; idx < 1024; idx += 256) {
    int c = idx >> 4, r4 = (idx & 15) * 4;
    bf16x4 h, l;
    #pragma unroll
    for (int j = 0; j < 4; ++j) {
      float f = tile[r4 + j][c];
      bf16_t hb = (bf16_t)f;
      h[j] = hb;
      l[j] = (bf16_t)(f - (float)hb);
    }
    size_t off = (size_t)(c0 + c) * M + r0 + r4;
    *(bf16x4*)(oh + off) = h;
    *(bf16x4*)(ol + off) = l;
  }
}

// ---------------- X fp32 -> hi/lo bf16 split (row-major pass-through) ------
__global__ __launch_bounds__(256) void k_xsplit(
    const float* __restrict__ X, bf16_t* __restrict__ Xh, bf16_t* __restrict__ Xl) {
  size_t i = ((size_t)blockIdx.x * 256 + threadIdx.x) * 8;
  float4 u = *(const float4*)(X + i);
  float4 v = *(const float4*)(X + i + 4);
  float fv[8] = {u.x,u.y,u.z,u.w,v.x,v.y,v.z,v.w};
  bf16x8 h, l;
  #pragma unroll
  for (int j = 0; j < 8; ++j) {
    bf16_t hb = (bf16_t)fv[j];
    h[j] = hb;
    l[j] = (bf16_t)(fv[j] - (float)hb);
  }
  *(bf16x8*)(Xh + i) = h;
  *(bf16x8*)(Xl + i) = l;
}

// ---------------- QKV projection via MFMA bf16x3 + fused xpos --------------
__global__ __launch_bounds__(256, 2) void k_qkv(
    const float* __restrict__ X, const float* __restrict__ tabs,
    const bf16_t* __restrict__ Wqth, const bf16_t* __restrict__ Wqtl,
    const bf16_t* __restrict__ Wkth, const bf16_t* __restrict__ Wktl,
    const bf16_t* __restrict__ Wvth, const bf16_t* __restrict__ Wvtl,
    bf16_t* __restrict__ Qh, bf16_t* __restrict__ Ql,
    bf16_t* __restrict__ Kh, bf16_t* __restrict__ Kl,
    bf16_t* __restrict__ Vh, bf16_t* __restrict__ Vl) {
  __shared__ bf16_t Wsh[128][128], Wsl[128][128];
  int t = threadIdx.x;
  int lane = t & 63, w = t >> 6;
  int lr = lane & 15, lg = lane >> 4;
  int s0 = blockIdx.x * 64;
  int hh = blockIdx.y;
  int b  = blockIdx.z;
  size_t bh = (size_t)(b*NH + hh);

  bf16x8 xh[4], xl[4];
  {
    const float* xp = X + ((size_t)(b*SEQ + s0 + 16*w + lr)) * HD + hh*DH + 8*lg;
    #pragma unroll
    for (int ks = 0; ks < 4; ++ks) {
      float4 u = *(const float4*)(xp + 32*ks);
      float4 v = *(const float4*)(xp + 32*ks + 4);
      float fv[8] = {u.x,u.y,u.z,u.w,v.x,v.y,v.z,v.w};
      #pragma unroll
      for (int j = 0; j < 8; ++j) {
        bf16_t hb = (bf16_t)fv[j];
        xh[ks][j] = hb;
        xl[ks][j] = (bf16_t)(fv[j] - (float)hb);
      }
    }
  }

  const bf16_t* Wh[3] = {Wqth, Wkth, Wvth};
  const bf16_t* Wl[3] = {Wqtl, Wktl, Wvtl};

  for (int which = 0; which < 3; ++which) {
    const bf16_t* wh = Wh[which] + (size_t)hh * (DH*DH);
    const bf16_t* wl = Wl[which] + (size_t)hh * (DH*DH);
    __syncthreads();
    for (int idx = t; idx < 2048; idx += 256) {
      int e = idx >> 4, kb = idx & 15;
      int kbs = kb ^ (e & 7);
      *(bf16x8*)&Wsh[e][kbs*8] = *(const bf16x8*)(wh + (size_t)e*DH + kb*8);
      *(bf16x8*)&Wsl[e][kbs*8] = *(const bf16x8*)(wl + (size_t)e*DH + kb*8);
    }
    __syncthreads();
    f32x4 yacc[8];
    #pragma unroll
    for (int i = 0; i < 8; ++i) yacc[i] = (f32x4){0.f,0.f,0.f,0.f};
    #pragma unroll
    for (int sub = 0; sub < 8; ++sub) {
      int e = 16*sub + lr;
      #pragma unroll
      for (int ks = 0; ks < 4; ++ks) {
        int ch = (lg + 4*ks) ^ (lr & 7);
        bf16x8 bhv = *(const bf16x8*)&Wsh[e][ch*8];
        bf16x8 blv = *(const bf16x8*)&Wsl[e][ch*8];
        yacc[sub] = __builtin_amdgcn_mfma_f32_16x16x32_bf16(xh[ks], bhv, yacc[sub], 0, 0, 0);
        yacc[sub] = __builtin_amdgcn_mfma_f32_16x16x32_bf16(xh[ks], blv, yacc[sub], 0, 0, 0);
        yacc[sub] = __builtin_amdgcn_mfma_f32_16x16x32_bf16(xl[ks], bhv, yacc[sub], 0, 0, 0);
      }
    }
    if (which < 2) {
      const float* st = tabs + (which ? 2*SEQ*HALF : 0);
      const float* ct = st + SEQ*HALF;
      bf16_t* Hp = which ? Kh : Qh;
      bf16_t* Lp = which ? Kl : Ql;
      #pragma unroll
      for (int sub = 0; sub < 8; ++sub) {
        int e = 16*sub + lr;
        int i = e >> 1;
        #pragma unroll
        for (int reg = 0; reg < 4; ++reg) {
          float v = yacc[sub][reg];
          float p = __shfl_xor(v, 1);
          int srow = s0 + 16*w + 4*lg + reg;
          float sv = st[srow*HALF + i], cv = ct[srow*HALF + i];
          float o = v * cv + ((e & 1) ? p : -p) * sv;
          bf16_t oh = (bf16_t)o;
          size_t off = (bh*SEQ + srow) * DH + e;
          Hp[off] = oh;
          Lp[off] = (bf16_t)(o - (float)oh);
        }
      }
    } else {
      #pragma unroll
      for (int sub = 0; sub < 8; ++sub) {
        int e = 16*sub + lr;
        bf16x4 hv, lv;
        #pragma unroll
        for (int reg = 0; reg < 4; ++reg) {
          float f = yacc[sub][reg];
          bf16_t hb = (bf16_t)f;
          hv[reg] = hb;
          lv[reg] = (bf16_t)(f - (float)hb);
        }
        size_t off = bh * (size_t)(DH*SEQ) + (size_t)e*SEQ + (s0 + 16*w + 4*lg);
        *(bf16x4*)(Vh + off) = hv;
        *(bf16x4*)(Vl + off) = lv;
      }
    }
  }
}

// ---------------- delta: Dt[dv][dk] = sum_tau g^(127-tau) V[tau][dv] K[tau][dk]
__global__ __launch_bounds__(256, 1) void k_delta(
    const bf16_t* __restrict__ Khg, const bf16_t* __restrict__ Klg,
    const bf16_t* __restrict__ VTh, const bf16_t* __restrict__ VTl,
    bf16_t* __restrict__ DSth, bf16_t* __restrict__ DStl) {
  __shared__ bf16_t KTh[128][128], KTl[128][128];   // [dk][tau], chunk-swz
  __shared__ bf16_t Vdh[128][128], Vdl[128][128];   // [dv][tau], chunk-swz
  int t = threadIdx.x;
  int lane = t & 63, w = t >> 6;
  int lr = lane & 15, lg = lane >> 4;
  int c = blockIdx.x, bh = blockIdx.y, hh = bh & 7;
  float l2g = head_l2g(hh);
  size_t kbase = (size_t)bh * SEQ * DH + (size_t)c * 128 * DH;
  size_t vtb   = (size_t)bh * DH * SEQ + (size_t)c * 128;

  for (int idx = t; idx < 2048; idx += 256) {
    int dc = idx >> 7, tau = idx & 127;
    bf16x8 h8 = *(const bf16x8*)(Khg + kbase + (size_t)tau*DH + dc*8);
    bf16x8 l8 = *(const bf16x8*)(Klg + kbase + (size_t)tau*DH + dc*8);
    #pragma unroll
    for (int j = 0; j < 8; ++j) {
      int d = dc*8 + j;
      int col = (((tau>>3) ^ (d & 7)) << 3) | (tau & 7);
      KTh[d][col] = h8[j];
      KTl[d][col] = l8[j];
    }
  }
  for (int idx = t; idx < 2048; idx += 256) {
    int dv = idx >> 4, tc = idx & 15;
    bf16x8 h8 = *(const bf16x8*)(VTh + vtb + (size_t)dv*SEQ + tc*8);
    bf16x8 l8 = *(const bf16x8*)(VTl + vtb + (size_t)dv*SEQ + tc*8);
    bf16x8 oh, ol;
    #pragma unroll
    for (int j = 0; j < 8; ++j) {
      int tau = tc*8 + j;
      float f = ((float)h8[j] + (float)l8[j]) * exp2f(l2g * (float)(127 - tau));
      bf16_t hb = (bf16_t)f;
      oh[j] = hb;
      ol[j] = (bf16_t)(f - (float)hb);
    }
    int cs = tc ^ (dv & 7);
    *(bf16x8*)&Vdh[dv][cs*8] = oh;
    *(bf16x8*)&Vdl[dv][cs*8] = ol;
  }
  __syncthreads();

  f32x4 acc[2][8];
  #pragma unroll
  for (int i = 0; i < 2; ++i)
    #pragma unroll
    for (int s = 0; s < 8; ++s) acc[i][s] = (f32x4){0.f,0.f,0.f,0.f};

  #pragma unroll
  for (int i = 0; i < 2; ++i) {
    int dv = 32*w + 16*i + lr;
    #pragma unroll
    for (int ks = 0; ks < 4; ++ks) {
      int ca = (lg + 4*ks) ^ (dv & 7);
      bf16x8 avh = *(const bf16x8*)&Vdh[dv][ca*8];
      bf16x8 avl = *(const bf16x8*)&Vdl[dv][ca*8];
      #pragma unroll
      for (int sub = 0; sub < 8; ++sub) {
        int dk = 16*sub + lr;
        int cb = (lg + 4*ks) ^ (dk & 7);
        bf16x8 bkh = *(const bf16x8*)&KTh[dk][cb*8];
        bf16x8 bkl = *(const bf16x8*)&KTl[dk][cb*8];
        acc[i][sub] = __builtin_amdgcn_mfma_f32_16x16x32_bf16(avh, bkh, acc[i][sub], 0, 0, 0);
        acc[i][sub] = __builtin_amdgcn_mfma_f32_16x16x32_bf16(avh, bkl, acc[i][sub], 0, 0, 0);
        acc[i][sub] = __builtin_amdgcn_mfma_f32_16x16x32_bf16(avl, bkh, acc[i][sub], 0, 0, 0);
      }
    }
  }
  size_t obase = ((size_t)bh * 16 + c) * 16384;
  #pragma unroll
  for (int i = 0; i < 2; ++i) {
    #pragma unroll
    for (int sub = 0; sub < 8; ++sub) {
      #pragma unroll
      for (int reg = 0; reg < 4; ++reg) {
        int dv = 32*w + 16*i + 4*lg + reg;
        int dk = 16*sub + lr;
        float f = acc[i][sub][reg];
        bf16_t hb = (bf16_t)f;
        size_t off = obase + (size_t)dv*128 + dk;
        DSth[off] = hb;
        DStl[off] = (bf16_t)(f - (float)hb);
      }
    }
  }
}

// ---------------- in-place prefix scan over chunks: DSt[c] Δ -> S_c --------
__global__ __launch_bounds__(256) void k_scan(
    bf16_t* __restrict__ DSth, bf16_t* __restrict__ DStl) {
  int t = threadIdx.x;
  int bh = blockIdx.y, hh = bh & 7;
  float l2g = head_l2g(hh);
  float g128 = exp2f(l2g * 128.0f);
  int dv = blockIdx.x * 16 + (t >> 4);
  int dk0 = (t & 15) * 8;
  size_t base = ((size_t)bh * 16) * 16384 + (size_t)dv*128 + dk0;
  float S[8] = {};
  for (int c = 0; c < 16; ++c) {
    size_t off = base + (size_t)c * 16384;
    bf16x8 dh = *(const bf16x8*)(DSth + off);
    bf16x8 dl = *(const bf16x8*)(DStl + off);
    bf16x8 sh, sl;
    #pragma unroll
    for (int j = 0; j < 8; ++j) {
      bf16_t hb = (bf16_t)S[j];
      sh[j] = hb;
      sl[j] = (bf16_t)(S[j] - (float)hb);
    }
    *(bf16x8*)(DSth + off) = sh;
    *(bf16x8*)(DStl + off) = sl;
    #pragma unroll
    for (int j = 0; j < 8; ++j)
      S[j] = g128*S[j] + ((float)dh[j] + (float)dl[j]);
  }
}

// ---------------- retention: cross (Q·S^T) + intra + FUSED groupnorm -------
// grid (16 chunks, 16 bh), 512 thr (8 waves x 16 q-rows), 96KB LDS.
// Epilogue: per-row mean/var in-register (16-lane shfl groups), writes Yn
// directly in (b,s,H) layout.
__global__ __launch_bounds__(512, 1) void k_ret(
    const bf16_t* __restrict__ Qhig, const bf16_t* __restrict__ Qlog,
    const bf16_t* __restrict__ Khig, const bf16_t* __restrict__ Klog,
    const bf16_t* __restrict__ VThg, const bf16_t* __restrict__ VTlg,
    const bf16_t* __restrict__ DSth, const bf16_t* __restrict__ DStl,
    const float* __restrict__ gw, const float* __restrict__ gb,
    float* __restrict__ Yn) {
  __shared__ bf16_t Ksh[64][128], Ksl[64][128];
  __shared__ bf16_t Vsh[128][64], Vsl[128][64];
  __shared__ bf16_t Ph[128][64], Pl[128][64];
  int t = threadIdx.x;
  int lane = t & 63, w = t >> 6;          // 8 waves
  int lr = lane & 15, lg = lane >> 4;
  int c = blockIdx.x, bh = blockIdx.y, hh = bh & 7;
  int s0 = c * 128;
  size_t base  = (size_t)bh * SEQ * DH;
  size_t vbase = (size_t)bh * DH * SEQ;
  float l2g = head_l2g(hh);
  float colf = exp2f(-l2g * (float)lr);
  float g16v[4];
  #pragma unroll
  for (int ts = 0; ts < 4; ++ts) g16v[ts] = exp2f(-l2g * (float)(16*ts));

  bf16x8 qh[4], ql[4];
  {
    const bf16_t* qph = Qhig + base + (size_t)(s0 + 16*w + lr) * DH + lg * 8;
    const bf16_t* qpl = Qlog + base + (size_t)(s0 + 16*w + lr) * DH + lg * 8;
    #pragma unroll
    for (int ks = 0; ks < 4; ++ks) {
      qh[ks] = *(const bf16x8*)(qph + 32*ks);
      ql[ks] = *(const bf16x8*)(qpl + 32*ks);
    }
  }
  f32x4 yacc[8];
  #pragma unroll
  for (int i = 0; i < 8; ++i) yacc[i] = (f32x4){0.f,0.f,0.f,0.f};

  for (int idx = t; idx < 1024; idx += 512) {
    int r = idx >> 4, kb = idx & 15;
    int kbs = kb ^ (r & 7);
    *(bf16x8*)&Ksh[r][kbs*8] = *(const bf16x8*)(Khig + base + (size_t)(s0 + r)*DH + kb*8);
    *(bf16x8*)&Ksl[r][kbs*8] = *(const bf16x8*)(Klog + base + (size_t)(s0 + r)*DH + kb*8);
  }
  for (int idx = t; idx < 1024; idx += 512) {
    int d = idx >> 3, cb = idx & 7;
    int cbs = cb ^ (d & 7);
    *(bf16x8*)&Vsh[d][cbs*8] = *(const bf16x8*)(VThg + vbase + (size_t)d*SEQ + s0 + cb*8);
    *(bf16x8*)&Vsl[d][cbs*8] = *(const bf16x8*)(VTlg + vbase + (size_t)d*SEQ + s0 + cb*8);
  }

  {
    const bf16_t* sth = DSth + ((size_t)bh * 16 + c) * 16384;
    const bf16_t* stl = DStl + ((size_t)bh * 16 + c) * 16384;
    #pragma unroll
    for (int sub = 0; sub < 8; ++sub) {
      size_t ro = (size_t)(16*sub + lr) * 128 + 8*lg;
      #pragma unroll
      for (int ks = 0; ks < 4; ++ks) {
        bf16x8 bh_ = *(const bf16x8*)(sth + ro + 32*ks);
        bf16x8 bl_ = *(const bf16x8*)(stl + ro + 32*ks);
        yacc[sub] = __builtin_amdgcn_mfma_f32_16x16x32_bf16(qh[ks], bh_, yacc[sub], 0, 0, 0);
        yacc[sub] = __builtin_amdgcn_mfma_f32_16x16x32_bf16(qh[ks], bl_, yacc[sub], 0, 0, 0);
        yacc[sub] = __builtin_amdgcn_mfma_f32_16x16x32_bf16(ql[ks], bh_, yacc[sub], 0, 0, 0);
      }
    }
    float rowc[4];
    #pragma unroll
    for (int reg = 0; reg < 4; ++reg)
      rowc[reg] = exp2f(l2g * (float)(16*w + 4*lg + reg + 1));
    #pragma unroll
    for (int sub = 0; sub < 8; ++sub)
      #pragma unroll
      for (int reg = 0; reg < 4; ++reg)
        yacc[sub][reg] *= rowc[reg];
  }
  __syncthreads();

  for (int kt = 0; kt < 2; ++kt) {
    int t0 = kt * 64;
    if (kt == 1) {
      __syncthreads();
      for (int idx = t; idx < 1024; idx += 512) {
        int r = idx >> 4, kb = idx & 15;
        int kbs = kb ^ (r & 7);
        *(bf16x8*)&Ksh[r][kbs*8] = *(const bf16x8*)(Khig + base + (size_t)(s0 + 64 + r)*DH + kb*8);
        *(bf16x8*)&Ksl[r][kbs*8] = *(const bf16x8*)(Klog + base + (size_t)(s0 + 64 + r)*DH + kb*8);
      }
      for (int idx = t; idx < 1024; idx += 512) {
        int d = idx >> 3, cb = idx & 7;
        int cbs = cb ^ (d & 7);
        *(bf16x8*)&Vsh[d][cbs*8] = *(const bf16x8*)(VThg + vbase + (size_t)d*SEQ + s0 + 64 + cb*8);
        *(bf16x8*)&Vsl[d][cbs*8] = *(const bf16x8*)(VTlg + vbase + (size_t)d*SEQ + s0 + 64 + cb*8);
      }
    }
    __syncthreads();
    if (!(kt == 1 && w < 4)) {
      float rowf[4];
      #pragma unroll
      for (int reg = 0; reg < 4; ++reg)
        rowf[reg] = exp2f(l2g * (float)(16*w + 4*lg + reg - t0));

      #pragma unroll
      for (int ts = 0; ts < 4; ++ts) {
        f32x4 sacc = (f32x4){0.f,0.f,0.f,0.f};
        int trow = 16*ts + lr;
        #pragma unroll
        for (int ks = 0; ks < 4; ++ks) {
          int kbs = (4*ks + lg) ^ (trow & 7);
          bf16x8 kh8 = *(const bf16x8*)&Ksh[trow][kbs*8];
          bf16x8 kl8 = *(const bf16x8*)&Ksl[trow][kbs*8];
          sacc = __builtin_amdgcn_mfma_f32_16x16x32_bf16(qh[ks], kh8, sacc, 0, 0, 0);
          sacc = __builtin_amdgcn_mfma_f32_16x16x32_bf16(qh[ks], kl8, sacc, 0, 0, 0);
          sacc = __builtin_amdgcn_mfma_f32_16x16x32_bf16(ql[ks], kh8, sacc, 0, 0, 0);
        }
        float cf = colf * g16v[ts];
        #pragma unroll
        for (int reg = 0; reg < 4; ++reg) {
          int qloc = 4*lg + reg;
          int diff = (16*w + qloc) - (t0 + trow);
          float p = (diff >= 0) ? sacc[reg] * (rowf[reg] * cf) : 0.0f;
          bf16_t ph = (bf16_t)p;
          bf16_t pl = (bf16_t)(p - (float)ph);
          int cb = (trow >> 3) ^ (qloc & 7);
          Ph[16*w + qloc][cb*8 + (trow & 7)] = ph;
          Pl[16*w + qloc][cb*8 + (trow & 7)] = pl;
        }
      }
      #pragma unroll
      for (int ks = 0; ks < 2; ++ks) {
        int prow = 16*w + lr;
        int pcb = (4*ks + lg) ^ (lr & 7);
        bf16x8 pah = *(const bf16x8*)&Ph[prow][pcb*8];
        bf16x8 pal = *(const bf16x8*)&Pl[prow][pcb*8];
        #pragma unroll
        for (int sub = 0; sub < 8; ++sub) {
          int drow = 16*sub + lr;
          int vcb = (4*ks + lg) ^ (drow & 7);
          bf16x8 vh8 = *(const bf16x8*)&Vsh[drow][vcb*8];
          bf16x8 vl8 = *(const bf16x8*)&Vsl[drow][vcb*8];
          yacc[sub] = __builtin_amdgcn_mfma_f32_16x16x32_bf16(pah, vh8, yacc[sub], 0, 0, 0);
          yacc[sub] = __builtin_amdgcn_mfma_f32_16x16x32_bf16(pah, vl8, yacc[sub], 0, 0, 0);
          yacc[sub] = __builtin_amdgcn_mfma_f32_16x16x32_bf16(pal, vh8, yacc[sub], 0, 0, 0);
        }
      }
    }
  }

  // ---- fused groupnorm: row stats via in-register sums + 16-lane shfl ----
  float s1v[4] = {0.f,0.f,0.f,0.f}, s2v[4] = {0.f,0.f,0.f,0.f};
  #pragma unroll
  for (int sub = 0; sub < 8; ++sub)
    #pragma unroll
    for (int reg = 0; reg < 4; ++reg) {
      float v = yacc[sub][reg];
      s1v[reg] += v;
      s2v[reg] += v * v;
    }
  #pragma unroll
  for (int off = 8; off; off >>= 1)
    #pragma unroll
    for (int reg = 0; reg < 4; ++reg) {
      s1v[reg] += __shfl_xor(s1v[reg], off);
      s2v[reg] += __shfl_xor(s2v[reg], off);
    }
  float gwv[8], gbv[8];
  #pragma unroll
  for (int sub = 0; sub < 8; ++sub) {
    gwv[sub] = gw[hh*DH + 16*sub + lr];
    gbv[sub] = gb[hh*DH + 16*sub + lr];
  }
  int b = bh >> 3;
  #pragma unroll
  for (int reg = 0; reg < 4; ++reg) {
    float mean = s1v[reg] * (1.0f/128.0f);
    float var = s2v[reg] * (1.0f/128.0f) - mean*mean;
    float inv = rsqrtf(var + 1e-5f);
    int srow = s0 + 16*w + 4*lg + reg;
    float* op = Yn + (size_t)(b*SEQ + srow) * HD + hh*DH;
    #pragma unroll
    for (int sub = 0; sub < 8; ++sub)
      op[16*sub + lr] = (yacc[sub][reg] - mean) * inv * gwv[sub] + gbv[sub];
  }
}

// ---------------- MFMA bf16x3 GEMM, 128x128, 8 waves, double-buffered ------
// A: Ah/Al bf16 [M][K] row-major. B: Bh/Bl bf16 [N][K] (W^T).
// mode 1: epilogue swish(G)*E -> split-store Oh/Ol. mode 0: fp32 out Of.
// 2-phase pipeline: stage(kt+1 -> buf^1) issued before compute(buf);
// one __syncthreads per K-step drains vmcnt. XCD-swizzled flat grid.
__global__ __launch_bounds__(512, 1) void k_gemm(
    const bf16_t* __restrict__ Ahg, const bf16_t* __restrict__ Alg,
    const bf16_t* __restrict__ Bhg, const bf16_t* __restrict__ Blg,
    const float* __restrict__ E,
    bf16_t* __restrict__ Oh, bf16_t* __restrict__ Ol,
    float* __restrict__ Of, int mode) {
  __shared__ bf16_t SB[4][2][128][64];    // {Ah,Al,Bh,Bl} x dbuf
  int t = threadIdx.x;
  int lane = t & 63, w = t >> 6;          // 8 waves
  int lr = lane & 15, lg = lane >> 4;
  int wr = w >> 1, wc = w & 1;            // wave tile: 32(m) x 64(n)
  int bid = blockIdx.x;
  int swz = (bid & 7) * 32 + (bid >> 3);  // 256 blocks, bijective XCD chunking
  int n0 = (swz & 7) * 128, m0 = (swz >> 3) * 128;

  const bf16_t* srcs[4] = {
    Ahg + (size_t)m0 * HD, Alg + (size_t)m0 * HD,
    Bhg + (size_t)n0 * HD, Blg + (size_t)n0 * HD };

  f32x4 acc[2][4];
  #pragma unroll
  for (int i = 0; i < 2; ++i)
    #pragma unroll
    for (int j = 0; j < 4; ++j) acc[i][j] = (f32x4){0.f,0.f,0.f,0.f};

  int srow = lane >> 3, sch = lane & 7;

  // prologue: stage K-step 0 into buf 0
  #pragma unroll
  for (int bi = 0; bi < 4; ++bi)
    #pragma unroll
    for (int i = 0; i < 2; ++i) {
      int row = w*16 + i*8 + srow;
      int kc = (sch ^ (row & 7)) * 8;
      gld16(srcs[bi] + (size_t)row*HD + kc, &SB[bi][0][w*16 + i*8][0]);
    }
  __syncthreads();

  int buf = 0;
  for (int kt = 0; kt < 16; ++kt) {
    if (kt + 1 < 16) {
      int k0 = (kt + 1) * 64;
      #pragma unroll
      for (int bi = 0; bi < 4; ++bi)
        #pragma unroll
        for (int i = 0; i < 2; ++i) {
          int row = w*16 + i*8 + srow;
          int kc = (sch ^ (row & 7)) * 8;
          gld16(srcs[bi] + (size_t)row*HD + k0 + kc, &SB[bi][buf^1][w*16 + i*8][0]);
        }
    }
    #pragma unroll
    for (int ks = 0; ks < 2; ++ks) {
      bf16x8 ah_[2], al_[2], bh_[4], bl_[4];
      #pragma unroll
      for (int mf = 0; mf < 2; ++mf) {
        int row = wr*32 + mf*16 + lr;
        int ch = (lg + 4*ks) ^ (row & 7);
        ah_[mf] = *(const bf16x8*)&SB[0][buf][row][ch*8];
        al_[mf] = *(const bf16x8*)&SB[1][buf][row][ch*8];
      }
      #pragma unroll
      for (int nf = 0; nf < 4; ++nf) {
        int row = wc*64 + nf*16 + lr;
        int ch = (lg + 4*ks) ^ (row & 7);
        bh_[nf] = *(const bf16x8*)&SB[2][buf][row][ch*8];
        bl_[nf] = *(const bf16x8*)&SB[3][buf][row][ch*8];
      }
      #pragma unroll
      for (int mf = 0; mf < 2; ++mf)
        #pragma unroll
        for (int nf = 0; nf < 4; ++nf) {
          acc[mf][nf] = __builtin_amdgcn_mfma_f32_16x16x32_bf16(ah_[mf], bh_[nf], acc[mf][nf], 0, 0, 0);
          acc[mf][nf] = __builtin_amdgcn_mfma_f32_16x16x32_bf16(ah_[mf], bl_[nf], acc[mf][nf], 0, 0, 0);
          acc[mf][nf] = __builtin_amdgcn_mfma_f32_16x16x32_bf16(al_[mf], bh_[nf], acc[mf][nf], 0, 0, 0);
        }
    }
    __syncthreads();
    buf ^= 1;
  }
  #pragma unroll
  for (int mf = 0; mf < 2; ++mf) {
    #pragma unroll
    for (int nf = 0; nf < 4; ++nf) {
      #pragma unroll
      for (int reg = 0; reg < 4; ++reg) {
        int m = m0 + wr*32 + mf*16 + 4*lg + reg;
        int n = n0 + wc*64 + nf*16 + lr;
        float g = acc[mf][nf][reg];
        size_t off = (size_t)m * HD + n;
        if (mode == 1) {
          float sg = 1.0f / (1.0f + expf(-g));
          float a = g * sg * E[off];
          bf16_t hb = (bf16_t)a;
          Oh[off] = hb;
          Ol[off] = (bf16_t)(a - (float)hb);
        } else {
          Of[off] = g;
        }
      }
    }
  }
}

extern "C" void kernel_launch(void* const* d_in, const int* in_sizes, int n_in,
                              void* d_out, int out_size, void* d_ws, size_t ws_size,
                              hipStream_t stream) {
  const float* X  = (const float*)d_in[0];
  const float* Wq = (const float*)d_in[1];
  const float* Wk = (const float*)d_in[2];
  const float* Wv = (const float*)d_in[3];
  const float* Wg = (const float*)d_in[4];
  const float* Wo = (const float*)d_in[5];
  const float* gw = (const float*)d_in[6];
  const float* gb = (const float*)d_in[7];
  float* out = (float*)d_out;
  float* ws = (float*)d_ws;

  // ws: tabs 2.1 | Q/K/VT hi-lo 50.3 | Yn 16.8 | DSt hi-lo 16.8 | W 10 (~96MB)
  float* tabs = ws;
  bf16_t* Qh  = (bf16_t*)(ws + 524288);
  bf16_t* Ql  = Qh + 4194304;
  bf16_t* Kh  = Ql + 4194304;
  bf16_t* Kl  = Kh + 4194304;
  bf16_t* VTh = Kl + 4194304;
  bf16_t* VTl = VTh + 4194304;
  float*  Yn  = (float*)(VTl + 4194304);   // written by fused k_ret
  bf16_t* DSth = (bf16_t*)(Yn + 4194304);
  bf16_t* DStl = DSth + 4194304;
  bf16_t* Wqth = DStl + 4194304;
  bf16_t* Wqtl = Wqth + 131072;
  bf16_t* Wkth = Wqtl + 131072;
  bf16_t* Wktl = Wkth + 131072;
  bf16_t* Wvth = Wktl + 131072;
  bf16_t* Wvtl = Wvth + 131072;
  bf16_t* Wgth = Wvtl + 131072;
  bf16_t* Wgtl = Wgth + 1048576;
  bf16_t* Woth = Wgtl + 1048576;
  bf16_t* Wotl = Woth + 1048576;
  bf16_t* A2h = Qh;                // Q dead after k_ret
  bf16_t* A2l = Ql;
  bf16_t* Xh  = Kh;                // K dead after k_ret
  bf16_t* Xl  = Kl;

  k_tables<<<dim3(512), dim3(256), 0, stream>>>(tabs);
  k_wsplit<<<dim3(2, 2, 8), dim3(256), 0, stream>>>(Wq, Wqth, Wqtl, DH, DH);
  k_wsplit<<<dim3(2, 2, 8), dim3(256), 0, stream>>>(Wk, Wkth, Wktl, DH, DH);
  k_wsplit<<<dim3(2, 2, 8), dim3(256), 0, stream>>>(Wv, Wvth, Wvtl, DH, DH);
  k_wsplit<<<dim3(16, 16, 1), dim3(256), 0, stream>>>(Wg, Wgth, Wgtl, HD, HD);
  k_wsplit<<<dim3(16, 16, 1), dim3(256), 0, stream>>>(Wo, Woth, Wotl, HD, HD);
  k_qkv<<<dim3(32, 8, 2), dim3(256), 0, stream>>>(X, tabs, Wqth, Wqtl, Wkth, Wktl,
                                                  Wvth, Wvtl, Qh, Ql, Kh, Kl, VTh, VTl);
  k_delta<<<dim3(16, 16), dim3(256), 0, stream>>>(Kh, Kl, VTh, VTl, DSth, DStl);
  k_scan<<<dim3(8, 16), dim3(256), 0, stream>>>(DSth, DStl);
  k_ret<<<dim3(16, 16), dim3(512), 0, stream>>>(Qh, Ql, Kh, Kl, VTh, VTl,
                                                DSth, DStl, gw, gb, Yn);
  k_xsplit<<<dim3(2048), dim3(256), 0, stream>>>(X, Xh, Xl);
  k_gemm<<<dim3(256), dim3(512), 0, stream>>>(Xh, Xl, Wgth, Wgtl,
                                              Yn, A2h, A2l, nullptr, 1);
  k_gemm<<<dim3(256), dim3(512), 0, stream>>>(A2h, A2l, Woth, Wotl,
                                              nullptr, nullptr, nullptr, out, 0);
}

// Round 7
// 148.597 us; speedup vs baseline: 5.6641x; 1.1736x over previous
//
#include <hip/hip_runtime.h>
#include <math.h>

#define NB 2
#define SEQ 2048
#define HD 1024
#define NH 8
#define DH 128
#define HALF 64

typedef __bf16 bf16_t;
typedef __attribute__((ext_vector_type(8))) __bf16 bf16x8;
typedef __attribute__((ext_vector_type(4))) __bf16 bf16x4;
typedef __attribute__((ext_vector_type(4))) float f32x4;

typedef __attribute__((address_space(1))) void gvoid;
typedef __attribute__((address_space(3))) void lvoid;

__device__ __forceinline__ void gld16(const bf16_t* g, bf16_t* l) {
  __builtin_amdgcn_global_load_lds((gvoid*)g, (lvoid*)l, 16, 0, 0);
}

__device__ __forceinline__ float head_l2g(int hh) {
  double ga = log(1.0/32.0), gbb = log(1.0/512.0);
  float gamma = (float)(1.0 - exp(ga + (double)hh * (gbb - ga) / 7.0));
  return log2f(gamma);
}

// ---------------- xpos tables: sin_q, cos_q, sin_k, cos_k  (S x 64 each) ---
__global__ __launch_bounds__(256) void k_tables(float* __restrict__ tabs) {
  int idx = blockIdx.x * 256 + threadIdx.x;
  if (idx >= SEQ * HALF) return;
  int s = idx >> 6, i = idx & 63;
  float dd = (float)DH;
  float scale = (2.0f * (float)i + 0.4f * dd) / (1.4f * dd);
  float sc = expf(logf(scale) * ((float)s / 512.0f));
  float inv_freq = expf(-logf(10000.0f) * ((float)i / (float)HALF));
  float ang = (float)s * inv_freq;
  float sn, cs;
  sincosf(ang, &sn, &cs);
  float rsc = 1.0f / sc;
  tabs[idx]               = sn * sc;
  tabs[SEQ*HALF + idx]    = cs * sc;
  tabs[2*SEQ*HALF + idx]  = sn * rsc;
  tabs[3*SEQ*HALF + idx]  = cs * rsc;
}

// ---------------- transpose + hi/lo bf16 split of a weight matrix ----------
// ol == nullptr -> store hi only.
__global__ __launch_bounds__(256) void k_wsplit(
    const float* __restrict__ in, bf16_t* __restrict__ oh,
    bf16_t* __restrict__ ol, int M, int N) {
  __shared__ float tile[64][65];
  int z = blockIdx.z;
  in += (size_t)z * M * N; oh += (size_t)z * M * N;
  if (ol) ol += (size_t)z * M * N;
  int r0 = blockIdx.y * 64, c0 = blockIdx.x * 64;
  int t = threadIdx.x;
  for (int idx = t; idx < 1024; idx += 256) {
    int r = idx >> 4, c4 = (idx & 15) * 4;
    float4 v = *(const float4*)(in + (size_t)(r0 + r) * N + c0 + c4);
    *(float4*)&tile[r][c4] = v;
  }
  __syncthreads();
  for (int idx = t; idx < 1024; idx += 256) {
    int c = idx >> 4, r4 = (idx & 15) * 4;
    bf16x4 h, l;
    #pragma unroll
    for (int j = 0; j < 4; ++j) {
      float f = tile[r4 + j][c];
      bf16_t hb = (bf16_t)f;
      h[j] = hb;
      l[j] = (bf16_t)(f - (float)hb);
    }
    size_t off = (size_t)(c0 + c) * M + r0 + r4;
    *(bf16x4*)(oh + off) = h;
    if (ol) *(bf16x4*)(ol + off) = l;
  }
}

// ---------------- QKV projection via MFMA bf16x3 + fused xpos --------------
// Also emits Xh (bf16 hi of X) for the gate GEMM -- free, fragments in regs.
__global__ __launch_bounds__(256, 2) void k_qkv(
    const float* __restrict__ X, const float* __restrict__ tabs,
    const bf16_t* __restrict__ Wqth, const bf16_t* __restrict__ Wqtl,
    const bf16_t* __restrict__ Wkth, const bf16_t* __restrict__ Wktl,
    const bf16_t* __restrict__ Wvth, const bf16_t* __restrict__ Wvtl,
    bf16_t* __restrict__ Qh, bf16_t* __restrict__ Ql,
    bf16_t* __restrict__ Kh, bf16_t* __restrict__ Kl,
    bf16_t* __restrict__ Vh, bf16_t* __restrict__ Vl,
    bf16_t* __restrict__ Xhg) {
  __shared__ bf16_t Wsh[128][128], Wsl[128][128];
  int t = threadIdx.x;
  int lane = t & 63, w = t >> 6;
  int lr = lane & 15, lg = lane >> 4;
  int s0 = blockIdx.x * 64;
  int hh = blockIdx.y;
  int b  = blockIdx.z;
  size_t bh = (size_t)(b*NH + hh);

  bf16x8 xh[4], xl[4];
  {
    const float* xp = X + ((size_t)(b*SEQ + s0 + 16*w + lr)) * HD + hh*DH + 8*lg;
    #pragma unroll
    for (int ks = 0; ks < 4; ++ks) {
      float4 u = *(const float4*)(xp + 32*ks);
      float4 v = *(const float4*)(xp + 32*ks + 4);
      float fv[8] = {u.x,u.y,u.z,u.w,v.x,v.y,v.z,v.w};
      #pragma unroll
      for (int j = 0; j < 8; ++j) {
        bf16_t hb = (bf16_t)fv[j];
        xh[ks][j] = hb;
        xl[ks][j] = (bf16_t)(fv[j] - (float)hb);
      }
    }
  }
  // store X-hi for gate GEMM (bf16-only path)
  {
    bf16_t* xo = Xhg + ((size_t)(b*SEQ + s0 + 16*w + lr)) * HD + hh*DH + 8*lg;
    #pragma unroll
    for (int ks = 0; ks < 4; ++ks)
      *(bf16x8*)(xo + 32*ks) = xh[ks];
  }

  const bf16_t* Wh[3] = {Wqth, Wkth, Wvth};
  const bf16_t* Wl[3] = {Wqtl, Wktl, Wvtl};

  for (int which = 0; which < 3; ++which) {
    const bf16_t* wh = Wh[which] + (size_t)hh * (DH*DH);
    const bf16_t* wl = Wl[which] + (size_t)hh * (DH*DH);
    __syncthreads();
    for (int idx = t; idx < 2048; idx += 256) {
      int e = idx >> 4, kb = idx & 15;
      int kbs = kb ^ (e & 7);
      *(bf16x8*)&Wsh[e][kbs*8] = *(const bf16x8*)(wh + (size_t)e*DH + kb*8);
      *(bf16x8*)&Wsl[e][kbs*8] = *(const bf16x8*)(wl + (size_t)e*DH + kb*8);
    }
    __syncthreads();
    f32x4 yacc[8];
    #pragma unroll
    for (int i = 0; i < 8; ++i) yacc[i] = (f32x4){0.f,0.f,0.f,0.f};
    #pragma unroll
    for (int sub = 0; sub < 8; ++sub) {
      int e = 16*sub + lr;
      #pragma unroll
      for (int ks = 0; ks < 4; ++ks) {
        int ch = (lg + 4*ks) ^ (lr & 7);
        bf16x8 bhv = *(const bf16x8*)&Wsh[e][ch*8];
        bf16x8 blv = *(const bf16x8*)&Wsl[e][ch*8];
        yacc[sub] = __builtin_amdgcn_mfma_f32_16x16x32_bf16(xh[ks], bhv, yacc[sub], 0, 0, 0);
        yacc[sub] = __builtin_amdgcn_mfma_f32_16x16x32_bf16(xh[ks], blv, yacc[sub], 0, 0, 0);
        yacc[sub] = __builtin_amdgcn_mfma_f32_16x16x32_bf16(xl[ks], bhv, yacc[sub], 0, 0, 0);
      }
    }
    if (which < 2) {
      const float* st = tabs + (which ? 2*SEQ*HALF : 0);
      const float* ct = st + SEQ*HALF;
      bf16_t* Hp = which ? Kh : Qh;
      bf16_t* Lp = which ? Kl : Ql;
      #pragma unroll
      for (int sub = 0; sub < 8; ++sub) {
        int e = 16*sub + lr;
        int i = e >> 1;
        #pragma unroll
        for (int reg = 0; reg < 4; ++reg) {
          float v = yacc[sub][reg];
          float p = __shfl_xor(v, 1);
          int srow = s0 + 16*w + 4*lg + reg;
          float sv = st[srow*HALF + i], cv = ct[srow*HALF + i];
          float o = v * cv + ((e & 1) ? p : -p) * sv;
          bf16_t oh = (bf16_t)o;
          size_t off = (bh*SEQ + srow) * DH + e;
          Hp[off] = oh;
          Lp[off] = (bf16_t)(o - (float)oh);
        }
      }
    } else {
      #pragma unroll
      for (int sub = 0; sub < 8; ++sub) {
        int e = 16*sub + lr;
        bf16x4 hv, lv;
        #pragma unroll
        for (int reg = 0; reg < 4; ++reg) {
          float f = yacc[sub][reg];
          bf16_t hb = (bf16_t)f;
          hv[reg] = hb;
          lv[reg] = (bf16_t)(f - (float)hb);
        }
        size_t off = bh * (size_t)(DH*SEQ) + (size_t)e*SEQ + (s0 + 16*w + 4*lg);
        *(bf16x4*)(Vh + off) = hv;
        *(bf16x4*)(Vl + off) = lv;
      }
    }
  }
}

// ---------------- delta: Dt[dv][dk] = sum_tau g^(127-tau) V[tau][dv] K[tau][dk]
__global__ __launch_bounds__(256, 1) void k_delta(
    const bf16_t* __restrict__ Khg, const bf16_t* __restrict__ Klg,
    const bf16_t* __restrict__ VTh, const bf16_t* __restrict__ VTl,
    bf16_t* __restrict__ DSth, bf16_t* __restrict__ DStl) {
  __shared__ bf16_t KTh[128][128], KTl[128][128];   // [dk][tau], chunk-swz
  __shared__ bf16_t Vdh[128][128], Vdl[128][128];   // [dv][tau], chunk-swz
  int t = threadIdx.x;
  int lane = t & 63, w = t >> 6;
  int lr = lane & 15, lg = lane >> 4;
  int c = blockIdx.x, bh = blockIdx.y, hh = bh & 7;
  float l2g = head_l2g(hh);
  size_t kbase = (size_t)bh * SEQ * DH + (size_t)c * 128 * DH;
  size_t vtb   = (size_t)bh * DH * SEQ + (size_t)c * 128;

  for (int idx = t; idx < 2048; idx += 256) {
    int dc = idx >> 7, tau = idx & 127;
    bf16x8 h8 = *(const bf16x8*)(Khg + kbase + (size_t)tau*DH + dc*8);
    bf16x8 l8 = *(const bf16x8*)(Klg + kbase + (size_t)tau*DH + dc*8);
    #pragma unroll
    for (int j = 0; j < 8; ++j) {
      int d = dc*8 + j;
      int col = (((tau>>3) ^ (d & 7)) << 3) | (tau & 7);
      KTh[d][col] = h8[j];
      KTl[d][col] = l8[j];
    }
  }
  for (int idx = t; idx < 2048; idx += 256) {
    int dv = idx >> 4, tc = idx & 15;
    bf16x8 h8 = *(const bf16x8*)(VTh + vtb + (size_t)dv*SEQ + tc*8);
    bf16x8 l8 = *(const bf16x8*)(VTl + vtb + (size_t)dv*SEQ + tc*8);
    bf16x8 oh, ol;
    #pragma unroll
    for (int j = 0; j < 8; ++j) {
      int tau = tc*8 + j;
      float f = ((float)h8[j] + (float)l8[j]) * exp2f(l2g * (float)(127 - tau));
      bf16_t hb = (bf16_t)f;
      oh[j] = hb;
      ol[j] = (bf16_t)(f - (float)hb);
    }
    int cs = tc ^ (dv & 7);
    *(bf16x8*)&Vdh[dv][cs*8] = oh;
    *(bf16x8*)&Vdl[dv][cs*8] = ol;
  }
  __syncthreads();

  f32x4 acc[2][8];
  #pragma unroll
  for (int i = 0; i < 2; ++i)
    #pragma unroll
    for (int s = 0; s < 8; ++s) acc[i][s] = (f32x4){0.f,0.f,0.f,0.f};

  #pragma unroll
  for (int i = 0; i < 2; ++i) {
    int dv = 32*w + 16*i + lr;
    #pragma unroll
    for (int ks = 0; ks < 4; ++ks) {
      int ca = (lg + 4*ks) ^ (dv & 7);
      bf16x8 avh = *(const bf16x8*)&Vdh[dv][ca*8];
      bf16x8 avl = *(const bf16x8*)&Vdl[dv][ca*8];
      #pragma unroll
      for (int sub = 0; sub < 8; ++sub) {
        int dk = 16*sub + lr;
        int cb = (lg + 4*ks) ^ (dk & 7);
        bf16x8 bkh = *(const bf16x8*)&KTh[dk][cb*8];
        bf16x8 bkl = *(const bf16x8*)&KTl[dk][cb*8];
        acc[i][sub] = __builtin_amdgcn_mfma_f32_16x16x32_bf16(avh, bkh, acc[i][sub], 0, 0, 0);
        acc[i][sub] = __builtin_amdgcn_mfma_f32_16x16x32_bf16(avh, bkl, acc[i][sub], 0, 0, 0);
        acc[i][sub] = __builtin_amdgcn_mfma_f32_16x16x32_bf16(avl, bkh, acc[i][sub], 0, 0, 0);
      }
    }
  }
  size_t obase = ((size_t)bh * 16 + c) * 16384;
  #pragma unroll
  for (int i = 0; i < 2; ++i) {
    #pragma unroll
    for (int sub = 0; sub < 8; ++sub) {
      #pragma unroll
      for (int reg = 0; reg < 4; ++reg) {
        int dv = 32*w + 16*i + 4*lg + reg;
        int dk = 16*sub + lr;
        float f = acc[i][sub][reg];
        bf16_t hb = (bf16_t)f;
        size_t off = obase + (size_t)dv*128 + dk;
        DSth[off] = hb;
        DStl[off] = (bf16_t)(f - (float)hb);
      }
    }
  }
}

// ---------------- in-place prefix scan over chunks: DSt[c] Δ -> S_c --------
__global__ __launch_bounds__(256) void k_scan(
    bf16_t* __restrict__ DSth, bf16_t* __restrict__ DStl) {
  int t = threadIdx.x;
  int bh = blockIdx.y, hh = bh & 7;
  float l2g = head_l2g(hh);
  float g128 = exp2f(l2g * 128.0f);
  int dv = blockIdx.x * 16 + (t >> 4);
  int dk0 = (t & 15) * 8;
  size_t base = ((size_t)bh * 16) * 16384 + (size_t)dv*128 + dk0;
  float S[8] = {};
  for (int c = 0; c < 16; ++c) {
    size_t off = base + (size_t)c * 16384;
    bf16x8 dh = *(const bf16x8*)(DSth + off);
    bf16x8 dl = *(const bf16x8*)(DStl + off);
    bf16x8 sh, sl;
    #pragma unroll
    for (int j = 0; j < 8; ++j) {
      bf16_t hb = (bf16_t)S[j];
      sh[j] = hb;
      sl[j] = (bf16_t)(S[j] - (float)hb);
    }
    *(bf16x8*)(DSth + off) = sh;
    *(bf16x8*)(DStl + off) = sl;
    #pragma unroll
    for (int j = 0; j < 8; ++j)
      S[j] = g128*S[j] + ((float)dh[j] + (float)dl[j]);
  }
}

// ---------------- retention: cross (Q·S^T) + intra + FUSED groupnorm -------
__global__ __launch_bounds__(512, 1) void k_ret(
    const bf16_t* __restrict__ Qhig, const bf16_t* __restrict__ Qlog,
    const bf16_t* __restrict__ Khig, const bf16_t* __restrict__ Klog,
    const bf16_t* __restrict__ VThg, const bf16_t* __restrict__ VTlg,
    const bf16_t* __restrict__ DSth, const bf16_t* __restrict__ DStl,
    const float* __restrict__ gw, const float* __restrict__ gb,
    float* __restrict__ Yn) {
  __shared__ bf16_t Ksh[64][128], Ksl[64][128];
  __shared__ bf16_t Vsh[128][64], Vsl[128][64];
  __shared__ bf16_t Ph[128][64], Pl[128][64];
  int t = threadIdx.x;
  int lane = t & 63, w = t >> 6;          // 8 waves
  int lr = lane & 15, lg = lane >> 4;
  int c = blockIdx.x, bh = blockIdx.y, hh = bh & 7;
  int s0 = c * 128;
  size_t base  = (size_t)bh * SEQ * DH;
  size_t vbase = (size_t)bh * DH * SEQ;
  float l2g = head_l2g(hh);
  float colf = exp2f(-l2g * (float)lr);
  float g16v[4];
  #pragma unroll
  for (int ts = 0; ts < 4; ++ts) g16v[ts] = exp2f(-l2g * (float)(16*ts));

  bf16x8 qh[4], ql[4];
  {
    const bf16_t* qph = Qhig + base + (size_t)(s0 + 16*w + lr) * DH + lg * 8;
    const bf16_t* qpl = Qlog + base + (size_t)(s0 + 16*w + lr) * DH + lg * 8;
    #pragma unroll
    for (int ks = 0; ks < 4; ++ks) {
      qh[ks] = *(const bf16x8*)(qph + 32*ks);
      ql[ks] = *(const bf16x8*)(qpl + 32*ks);
    }
  }
  f32x4 yacc[8];
  #pragma unroll
  for (int i = 0; i < 8; ++i) yacc[i] = (f32x4){0.f,0.f,0.f,0.f};

  for (int idx = t; idx < 1024; idx += 512) {
    int r = idx >> 4, kb = idx & 15;
    int kbs = kb ^ (r & 7);
    *(bf16x8*)&Ksh[r][kbs*8] = *(const bf16x8*)(Khig + base + (size_t)(s0 + r)*DH + kb*8);
    *(bf16x8*)&Ksl[r][kbs*8] = *(const bf16x8*)(Klog + base + (size_t)(s0 + r)*DH + kb*8);
  }
  for (int idx = t; idx < 1024; idx += 512) {
    int d = idx >> 3, cb = idx & 7;
    int cbs = cb ^ (d & 7);
    *(bf16x8*)&Vsh[d][cbs*8] = *(const bf16x8*)(VThg + vbase + (size_t)d*SEQ + s0 + cb*8);
    *(bf16x8*)&Vsl[d][cbs*8] = *(const bf16x8*)(VTlg + vbase + (size_t)d*SEQ + s0 + cb*8);
  }

  {
    const bf16_t* sth = DSth + ((size_t)bh * 16 + c) * 16384;
    const bf16_t* stl = DStl + ((size_t)bh * 16 + c) * 16384;
    #pragma unroll
    for (int sub = 0; sub < 8; ++sub) {
      size_t ro = (size_t)(16*sub + lr) * 128 + 8*lg;
      #pragma unroll
      for (int ks = 0; ks < 4; ++ks) {
        bf16x8 bh_ = *(const bf16x8*)(sth + ro + 32*ks);
        bf16x8 bl_ = *(const bf16x8*)(stl + ro + 32*ks);
        yacc[sub] = __builtin_amdgcn_mfma_f32_16x16x32_bf16(qh[ks], bh_, yacc[sub], 0, 0, 0);
        yacc[sub] = __builtin_amdgcn_mfma_f32_16x16x32_bf16(qh[ks], bl_, yacc[sub], 0, 0, 0);
        yacc[sub] = __builtin_amdgcn_mfma_f32_16x16x32_bf16(ql[ks], bh_, yacc[sub], 0, 0, 0);
      }
    }
    float rowc[4];
    #pragma unroll
    for (int reg = 0; reg < 4; ++reg)
      rowc[reg] = exp2f(l2g * (float)(16*w + 4*lg + reg + 1));
    #pragma unroll
    for (int sub = 0; sub < 8; ++sub)
      #pragma unroll
      for (int reg = 0; reg < 4; ++reg)
        yacc[sub][reg] *= rowc[reg];
  }
  __syncthreads();

  for (int kt = 0; kt < 2; ++kt) {
    int t0 = kt * 64;
    if (kt == 1) {
      __syncthreads();
      for (int idx = t; idx < 1024; idx += 512) {
        int r = idx >> 4, kb = idx & 15;
        int kbs = kb ^ (r & 7);
        *(bf16x8*)&Ksh[r][kbs*8] = *(const bf16x8*)(Khig + base + (size_t)(s0 + 64 + r)*DH + kb*8);
        *(bf16x8*)&Ksl[r][kbs*8] = *(const bf16x8*)(Klog + base + (size_t)(s0 + 64 + r)*DH + kb*8);
      }
      for (int idx = t; idx < 1024; idx += 512) {
        int d = idx >> 3, cb = idx & 7;
        int cbs = cb ^ (d & 7);
        *(bf16x8*)&Vsh[d][cbs*8] = *(const bf16x8*)(VThg + vbase + (size_t)d*SEQ + s0 + 64 + cb*8);
        *(bf16x8*)&Vsl[d][cbs*8] = *(const bf16x8*)(VTlg + vbase + (size_t)d*SEQ + s0 + 64 + cb*8);
      }
    }
    __syncthreads();
    if (!(kt == 1 && w < 4)) {
      float rowf[4];
      #pragma unroll
      for (int reg = 0; reg < 4; ++reg)
        rowf[reg] = exp2f(l2g * (float)(16*w + 4*lg + reg - t0));

      #pragma unroll
      for (int ts = 0; ts < 4; ++ts) {
        f32x4 sacc = (f32x4){0.f,0.f,0.f,0.f};
        int trow = 16*ts + lr;
        #pragma unroll
        for (int ks = 0; ks < 4; ++ks) {
          int kbs = (4*ks + lg) ^ (trow & 7);
          bf16x8 kh8 = *(const bf16x8*)&Ksh[trow][kbs*8];
          bf16x8 kl8 = *(const bf16x8*)&Ksl[trow][kbs*8];
          sacc = __builtin_amdgcn_mfma_f32_16x16x32_bf16(qh[ks], kh8, sacc, 0, 0, 0);
          sacc = __builtin_amdgcn_mfma_f32_16x16x32_bf16(qh[ks], kl8, sacc, 0, 0, 0);
          sacc = __builtin_amdgcn_mfma_f32_16x16x32_bf16(ql[ks], kh8, sacc, 0, 0, 0);
        }
        float cf = colf * g16v[ts];
        #pragma unroll
        for (int reg = 0; reg < 4; ++reg) {
          int qloc = 4*lg + reg;
          int diff = (16*w + qloc) - (t0 + trow);
          float p = (diff >= 0) ? sacc[reg] * (rowf[reg] * cf) : 0.0f;
          bf16_t ph = (bf16_t)p;
          bf16_t pl = (bf16_t)(p - (float)ph);
          int cb = (trow >> 3) ^ (qloc & 7);
          Ph[16*w + qloc][cb*8 + (trow & 7)] = ph;
          Pl[16*w + qloc][cb*8 + (trow & 7)] = pl;
        }
      }
      #pragma unroll
      for (int ks = 0; ks < 2; ++ks) {
        int prow = 16*w + lr;
        int pcb = (4*ks + lg) ^ (lr & 7);
        bf16x8 pah = *(const bf16x8*)&Ph[prow][pcb*8];
        bf16x8 pal = *(const bf16x8*)&Pl[prow][pcb*8];
        #pragma unroll
        for (int sub = 0; sub < 8; ++sub) {
          int drow = 16*sub + lr;
          int vcb = (4*ks + lg) ^ (drow & 7);
          bf16x8 vh8 = *(const bf16x8*)&Vsh[drow][vcb*8];
          bf16x8 vl8 = *(const bf16x8*)&Vsl[drow][vcb*8];
          yacc[sub] = __builtin_amdgcn_mfma_f32_16x16x32_bf16(pah, vh8, yacc[sub], 0, 0, 0);
          yacc[sub] = __builtin_amdgcn_mfma_f32_16x16x32_bf16(pah, vl8, yacc[sub], 0, 0, 0);
          yacc[sub] = __builtin_amdgcn_mfma_f32_16x16x32_bf16(pal, vh8, yacc[sub], 0, 0, 0);
        }
      }
    }
  }

  // ---- fused groupnorm ----
  float s1v[4] = {0.f,0.f,0.f,0.f}, s2v[4] = {0.f,0.f,0.f,0.f};
  #pragma unroll
  for (int sub = 0; sub < 8; ++sub)
    #pragma unroll
    for (int reg = 0; reg < 4; ++reg) {
      float v = yacc[sub][reg];
      s1v[reg] += v;
      s2v[reg] += v * v;
    }
  #pragma unroll
  for (int off = 8; off; off >>= 1)
    #pragma unroll
    for (int reg = 0; reg < 4; ++reg) {
      s1v[reg] += __shfl_xor(s1v[reg], off);
      s2v[reg] += __shfl_xor(s2v[reg], off);
    }
  float gwv[8], gbv[8];
  #pragma unroll
  for (int sub = 0; sub < 8; ++sub) {
    gwv[sub] = gw[hh*DH + 16*sub + lr];
    gbv[sub] = gb[hh*DH + 16*sub + lr];
  }
  int b = bh >> 3;
  #pragma unroll
  for (int reg = 0; reg < 4; ++reg) {
    float mean = s1v[reg] * (1.0f/128.0f);
    float var = s2v[reg] * (1.0f/128.0f) - mean*mean;
    float inv = rsqrtf(var + 1e-5f);
    int srow = s0 + 16*w + 4*lg + reg;
    float* op = Yn + (size_t)(b*SEQ + srow) * HD + hh*DH;
    #pragma unroll
    for (int sub = 0; sub < 8; ++sub)
      op[16*sub + lr] = (yacc[sub][reg] - mean) * inv * gwv[sub] + gbv[sub];
  }
}

// ---------------- plain-bf16 MFMA GEMM, 128x128, 8 waves, double-buffered --
// A: bf16 [M][K]. B: bf16 [N][K] (W^T). mode 1: swish(G)*E -> bf16 Oh.
// mode 0: fp32 Of.
__global__ __launch_bounds__(512, 1) void k_gemm(
    const bf16_t* __restrict__ Ag, const bf16_t* __restrict__ Bg,
    const float* __restrict__ E,
    bf16_t* __restrict__ Oh, float* __restrict__ Of, int mode) {
  __shared__ bf16_t SB[2][2][128][64];    // {A,B} x dbuf
  int t = threadIdx.x;
  int lane = t & 63, w = t >> 6;          // 8 waves
  int lr = lane & 15, lg = lane >> 4;
  int wr = w >> 1, wc = w & 1;            // wave tile: 32(m) x 64(n)
  int bid = blockIdx.x;
  int swz = (bid & 7) * 32 + (bid >> 3);  // bijective XCD chunking (256 blocks)
  int n0 = (swz & 7) * 128, m0 = (swz >> 3) * 128;

  const bf16_t* srcs[2] = { Ag + (size_t)m0 * HD, Bg + (size_t)n0 * HD };

  f32x4 acc[2][4];
  #pragma unroll
  for (int i = 0; i < 2; ++i)
    #pragma unroll
    for (int j = 0; j < 4; ++j) acc[i][j] = (f32x4){0.f,0.f,0.f,0.f};

  int srow = lane >> 3, sch = lane & 7;

  #pragma unroll
  for (int bi = 0; bi < 2; ++bi)
    #pragma unroll
    for (int i = 0; i < 2; ++i) {
      int row = w*16 + i*8 + srow;
      int kc = (sch ^ (row & 7)) * 8;
      gld16(srcs[bi] + (size_t)row*HD + kc, &SB[bi][0][w*16 + i*8][0]);
    }
  __syncthreads();

  int buf = 0;
  for (int kt = 0; kt < 16; ++kt) {
    if (kt + 1 < 16) {
      int k0 = (kt + 1) * 64;
      #pragma unroll
      for (int bi = 0; bi < 2; ++bi)
        #pragma unroll
        for (int i = 0; i < 2; ++i) {
          int row = w*16 + i*8 + srow;
          int kc = (sch ^ (row & 7)) * 8;
          gld16(srcs[bi] + (size_t)row*HD + k0 + kc, &SB[bi][buf^1][w*16 + i*8][0]);
        }
    }
    #pragma unroll
    for (int ks = 0; ks < 2; ++ks) {
      bf16x8 a_[2], b_[4];
      #pragma unroll
      for (int mf = 0; mf < 2; ++mf) {
        int row = wr*32 + mf*16 + lr;
        int ch = (lg + 4*ks) ^ (row & 7);
        a_[mf] = *(const bf16x8*)&SB[0][buf][row][ch*8];
      }
      #pragma unroll
      for (int nf = 0; nf < 4; ++nf) {
        int row = wc*64 + nf*16 + lr;
        int ch = (lg + 4*ks) ^ (row & 7);
        b_[nf] = *(const bf16x8*)&SB[1][buf][row][ch*8];
      }
      #pragma unroll
      for (int mf = 0; mf < 2; ++mf)
        #pragma unroll
        for (int nf = 0; nf < 4; ++nf)
          acc[mf][nf] = __builtin_amdgcn_mfma_f32_16x16x32_bf16(a_[mf], b_[nf], acc[mf][nf], 0, 0, 0);
    }
    __syncthreads();
    buf ^= 1;
  }
  #pragma unroll
  for (int mf = 0; mf < 2; ++mf) {
    #pragma unroll
    for (int nf = 0; nf < 4; ++nf) {
      #pragma unroll
      for (int reg = 0; reg < 4; ++reg) {
        int m = m0 + wr*32 + mf*16 + 4*lg + reg;
        int n = n0 + wc*64 + nf*16 + lr;
        float g = acc[mf][nf][reg];
        size_t off = (size_t)m * HD + n;
        if (mode == 1) {
          float sg = 1.0f / (1.0f + expf(-g));
          Oh[off] = (bf16_t)(g * sg * E[off]);
        } else {
          Of[off] = g;
        }
      }
    }
  }
}

extern "C" void kernel_launch(void* const* d_in, const int* in_sizes, int n_in,
                              void* d_out, int out_size, void* d_ws, size_t ws_size,
                              hipStream_t stream) {
  const float* X  = (const float*)d_in[0];
  const float* Wq = (const float*)d_in[1];
  const float* Wk = (const float*)d_in[2];
  const float* Wv = (const float*)d_in[3];
  const float* Wg = (const float*)d_in[4];
  const float* Wo = (const float*)d_in[5];
  const float* gw = (const float*)d_in[6];
  const float* gb = (const float*)d_in[7];
  float* out = (float*)d_out;
  float* ws = (float*)d_ws;

  float* tabs = ws;
  bf16_t* Qh  = (bf16_t*)(ws + 524288);
  bf16_t* Ql  = Qh + 4194304;
  bf16_t* Kh  = Ql + 4194304;
  bf16_t* Kl  = Kh + 4194304;
  bf16_t* VTh = Kl + 4194304;
  bf16_t* VTl = VTh + 4194304;
  float*  Yn  = (float*)(VTl + 4194304);   // written by fused k_ret
  bf16_t* DSth = (bf16_t*)(Yn + 4194304);
  bf16_t* DStl = DSth + 4194304;
  bf16_t* Wqth = DStl + 4194304;
  bf16_t* Wqtl = Wqth + 131072;
  bf16_t* Wkth = Wqtl + 131072;
  bf16_t* Wktl = Wkth + 131072;
  bf16_t* Wvth = Wktl + 131072;
  bf16_t* Wvtl = Wvth + 131072;
  bf16_t* Wgth = Wvtl + 131072;
  bf16_t* Woth = Wgth + 1048576;
  bf16_t* Xh   = Woth + 1048576;   // X hi, written by k_qkv
  bf16_t* A2h = Qh;                // Q dead after k_ret

  k_tables<<<dim3(512), dim3(256), 0, stream>>>(tabs);
  k_wsplit<<<dim3(2, 2, 8), dim3(256), 0, stream>>>(Wq, Wqth, Wqtl, DH, DH);
  k_wsplit<<<dim3(2, 2, 8), dim3(256), 0, stream>>>(Wk, Wkth, Wktl, DH, DH);
  k_wsplit<<<dim3(2, 2, 8), dim3(256), 0, stream>>>(Wv, Wvth, Wvtl, DH, DH);
  k_wsplit<<<dim3(16, 16, 1), dim3(256), 0, stream>>>(Wg, Wgth, nullptr, HD, HD);
  k_wsplit<<<dim3(16, 16, 1), dim3(256), 0, stream>>>(Wo, Woth, nullptr, HD, HD);
  k_qkv<<<dim3(32, 8, 2), dim3(256), 0, stream>>>(X, tabs, Wqth, Wqtl, Wkth, Wktl,
                                                  Wvth, Wvtl, Qh, Ql, Kh, Kl, VTh, VTl, Xh);
  k_delta<<<dim3(16, 16), dim3(256), 0, stream>>>(Kh, Kl, VTh, VTl, DSth, DStl);
  k_scan<<<dim3(8, 16), dim3(256), 0, stream>>>(DSth, DStl);
  k_ret<<<dim3(16, 16), dim3(512), 0, stream>>>(Qh, Ql, Kh, Kl, VTh, VTl,
                                                DSth, DStl, gw, gb, Yn);
  k_gemm<<<dim3(256), dim3(512), 0, stream>>>(Xh, Wgth, Yn, A2h, nullptr, 1);
  k_gemm<<<dim3(256), dim3(512), 0, stream>>>(A2h, Woth, nullptr, nullptr, out, 0);
}

// Round 8
// 116.387 us; speedup vs baseline: 7.2316x; 1.2767x over previous
//
#include <hip/hip_runtime.h>
#include <math.h>

#define NB 2
#define SEQ 2048
#define HD 1024
#define NH 8
#define DH 128
#define HALF 64

typedef __bf16 bf16_t;
typedef __attribute__((ext_vector_type(8))) __bf16 bf16x8;
typedef __attribute__((ext_vector_type(4))) __bf16 bf16x4;
typedef __attribute__((ext_vector_type(4))) float f32x4;

typedef __attribute__((address_space(1))) void gvoid;
typedef __attribute__((address_space(3))) void lvoid;

__device__ __forceinline__ void gld16(const bf16_t* g, bf16_t* l) {
  __builtin_amdgcn_global_load_lds((gvoid*)g, (lvoid*)l, 16, 0, 0);
}

__device__ __forceinline__ float head_l2g(int hh) {
  double ga = log(1.0/32.0), gbb = log(1.0/512.0);
  float gamma = (float)(1.0 - exp(ga + (double)hh * (gbb - ga) / 7.0));
  return log2f(gamma);
}

// ---------------- xpos tables: sin_q, cos_q, sin_k, cos_k  (S x 64 each) ---
__global__ __launch_bounds__(256) void k_tables(float* __restrict__ tabs) {
  int idx = blockIdx.x * 256 + threadIdx.x;
  if (idx >= SEQ * HALF) return;
  int s = idx >> 6, i = idx & 63;
  float dd = (float)DH;
  float scale = (2.0f * (float)i + 0.4f * dd) / (1.4f * dd);
  float sc = expf(logf(scale) * ((float)s / 512.0f));
  float inv_freq = expf(-logf(10000.0f) * ((float)i / (float)HALF));
  float ang = (float)s * inv_freq;
  float sn, cs;
  sincosf(ang, &sn, &cs);
  float rsc = 1.0f / sc;
  tabs[idx]               = sn * sc;
  tabs[SEQ*HALF + idx]    = cs * sc;
  tabs[2*SEQ*HALF + idx]  = sn * rsc;
  tabs[3*SEQ*HALF + idx]  = cs * rsc;
}

// ---------------- transpose + bf16 cast (hi) of a weight matrix ------------
__global__ __launch_bounds__(256) void k_wsplit(
    const float* __restrict__ in, bf16_t* __restrict__ oh, int M, int N) {
  __shared__ float tile[64][65];
  int z = blockIdx.z;
  in += (size_t)z * M * N; oh += (size_t)z * M * N;
  int r0 = blockIdx.y * 64, c0 = blockIdx.x * 64;
  int t = threadIdx.x;
  for (int idx = t; idx < 1024; idx += 256) {
    int r = idx >> 4, c4 = (idx & 15) * 4;
    float4 v = *(const float4*)(in + (size_t)(r0 + r) * N + c0 + c4);
    *(float4*)&tile[r][c4] = v;
  }
  __syncthreads();
  for (int idx = t; idx < 1024; idx += 256) {
    int c = idx >> 4, r4 = (idx & 15) * 4;
    bf16x4 h;
    #pragma unroll
    for (int j = 0; j < 4; ++j)
      h[j] = (bf16_t)tile[r4 + j][c];
    *(bf16x4*)(oh + (size_t)(c0 + c) * M + r0 + r4) = h;
  }
}

// ---------------- QKV projection (plain bf16 MFMA) + fused xpos ------------
// Outputs: Q, K row-major [bh][s][d]; VT transposed [bh][d][s]; Xh bf16.
__global__ __launch_bounds__(256, 2) void k_qkv(
    const float* __restrict__ X, const float* __restrict__ tabs,
    const bf16_t* __restrict__ Wqt, const bf16_t* __restrict__ Wkt,
    const bf16_t* __restrict__ Wvt,
    bf16_t* __restrict__ Qo, bf16_t* __restrict__ Ko,
    bf16_t* __restrict__ VTo, bf16_t* __restrict__ Xhg) {
  __shared__ bf16_t Wsh[128][128];
  int t = threadIdx.x;
  int lane = t & 63, w = t >> 6;
  int lr = lane & 15, lg = lane >> 4;
  int s0 = blockIdx.x * 64;
  int hh = blockIdx.y;
  int b  = blockIdx.z;
  size_t bh = (size_t)(b*NH + hh);

  bf16x8 xh[4];
  {
    const float* xp = X + ((size_t)(b*SEQ + s0 + 16*w + lr)) * HD + hh*DH + 8*lg;
    #pragma unroll
    for (int ks = 0; ks < 4; ++ks) {
      float4 u = *(const float4*)(xp + 32*ks);
      float4 v = *(const float4*)(xp + 32*ks + 4);
      float fv[8] = {u.x,u.y,u.z,u.w,v.x,v.y,v.z,v.w};
      #pragma unroll
      for (int j = 0; j < 8; ++j) xh[ks][j] = (bf16_t)fv[j];
    }
  }
  {
    bf16_t* xo = Xhg + ((size_t)(b*SEQ + s0 + 16*w + lr)) * HD + hh*DH + 8*lg;
    #pragma unroll
    for (int ks = 0; ks < 4; ++ks)
      *(bf16x8*)(xo + 32*ks) = xh[ks];
  }

  const bf16_t* Wp[3] = {Wqt, Wkt, Wvt};

  for (int which = 0; which < 3; ++which) {
    const bf16_t* wp = Wp[which] + (size_t)hh * (DH*DH);
    __syncthreads();
    for (int idx = t; idx < 2048; idx += 256) {
      int e = idx >> 4, kb = idx & 15;
      int kbs = kb ^ (e & 7);
      *(bf16x8*)&Wsh[e][kbs*8] = *(const bf16x8*)(wp + (size_t)e*DH + kb*8);
    }
    __syncthreads();
    f32x4 yacc[8];
    #pragma unroll
    for (int i = 0; i < 8; ++i) yacc[i] = (f32x4){0.f,0.f,0.f,0.f};
    #pragma unroll
    for (int sub = 0; sub < 8; ++sub) {
      int e = 16*sub + lr;
      #pragma unroll
      for (int ks = 0; ks < 4; ++ks) {
        int ch = (lg + 4*ks) ^ (lr & 7);
        bf16x8 bhv = *(const bf16x8*)&Wsh[e][ch*8];
        yacc[sub] = __builtin_amdgcn_mfma_f32_16x16x32_bf16(xh[ks], bhv, yacc[sub], 0, 0, 0);
      }
    }
    if (which < 2) {
      const float* st = tabs + (which ? 2*SEQ*HALF : 0);
      const float* ct = st + SEQ*HALF;
      bf16_t* Op = which ? Ko : Qo;
      #pragma unroll
      for (int sub = 0; sub < 8; ++sub) {
        int e = 16*sub + lr;
        int i = e >> 1;
        #pragma unroll
        for (int reg = 0; reg < 4; ++reg) {
          float v = yacc[sub][reg];
          float p = __shfl_xor(v, 1);
          int srow = s0 + 16*w + 4*lg + reg;
          float sv = st[srow*HALF + i], cv = ct[srow*HALF + i];
          float o = v * cv + ((e & 1) ? p : -p) * sv;
          Op[(bh*SEQ + srow) * DH + e] = (bf16_t)o;
        }
      }
    } else {
      #pragma unroll
      for (int sub = 0; sub < 8; ++sub) {
        int e = 16*sub + lr;
        bf16x4 hv;
        #pragma unroll
        for (int reg = 0; reg < 4; ++reg)
          hv[reg] = (bf16_t)yacc[sub][reg];
        *(bf16x4*)(VTo + bh * (size_t)(DH*SEQ) + (size_t)e*SEQ + (s0 + 16*w + 4*lg)) = hv;
      }
    }
  }
}

// ---------------- delta: Dt[dv][dk] = sum_tau g^(127-tau) V[tau][dv] K[tau][dk]
__global__ __launch_bounds__(256, 1) void k_delta(
    const bf16_t* __restrict__ Kg, const bf16_t* __restrict__ VTg,
    bf16_t* __restrict__ DSt) {
  __shared__ bf16_t KT[128][128];   // [dk][tau], chunk-swz
  __shared__ bf16_t Vd[128][128];   // [dv][tau], chunk-swz
  int t = threadIdx.x;
  int lane = t & 63, w = t >> 6;
  int lr = lane & 15, lg = lane >> 4;
  int c = blockIdx.x, bh = blockIdx.y, hh = bh & 7;
  float l2g = head_l2g(hh);
  size_t kbase = (size_t)bh * SEQ * DH + (size_t)c * 128 * DH;
  size_t vtb   = (size_t)bh * DH * SEQ + (size_t)c * 128;

  for (int idx = t; idx < 2048; idx += 256) {
    int dc = idx >> 7, tau = idx & 127;
    bf16x8 h8 = *(const bf16x8*)(Kg + kbase + (size_t)tau*DH + dc*8);
    #pragma unroll
    for (int j = 0; j < 8; ++j) {
      int d = dc*8 + j;
      int col = (((tau>>3) ^ (d & 7)) << 3) | (tau & 7);
      KT[d][col] = h8[j];
    }
  }
  for (int idx = t; idx < 2048; idx += 256) {
    int dv = idx >> 4, tc = idx & 15;
    bf16x8 h8 = *(const bf16x8*)(VTg + vtb + (size_t)dv*SEQ + tc*8);
    bf16x8 oh;
    #pragma unroll
    for (int j = 0; j < 8; ++j) {
      int tau = tc*8 + j;
      oh[j] = (bf16_t)((float)h8[j] * exp2f(l2g * (float)(127 - tau)));
    }
    int cs = tc ^ (dv & 7);
    *(bf16x8*)&Vd[dv][cs*8] = oh;
  }
  __syncthreads();

  f32x4 acc[2][8];
  #pragma unroll
  for (int i = 0; i < 2; ++i)
    #pragma unroll
    for (int s = 0; s < 8; ++s) acc[i][s] = (f32x4){0.f,0.f,0.f,0.f};

  #pragma unroll
  for (int i = 0; i < 2; ++i) {
    int dv = 32*w + 16*i + lr;
    #pragma unroll
    for (int ks = 0; ks < 4; ++ks) {
      int ca = (lg + 4*ks) ^ (dv & 7);
      bf16x8 avh = *(const bf16x8*)&Vd[dv][ca*8];
      #pragma unroll
      for (int sub = 0; sub < 8; ++sub) {
        int dk = 16*sub + lr;
        int cb = (lg + 4*ks) ^ (dk & 7);
        bf16x8 bkh = *(const bf16x8*)&KT[dk][cb*8];
        acc[i][sub] = __builtin_amdgcn_mfma_f32_16x16x32_bf16(avh, bkh, acc[i][sub], 0, 0, 0);
      }
    }
  }
  size_t obase = ((size_t)bh * 16 + c) * 16384;
  #pragma unroll
  for (int i = 0; i < 2; ++i)
    #pragma unroll
    for (int sub = 0; sub < 8; ++sub)
      #pragma unroll
      for (int reg = 0; reg < 4; ++reg) {
        int dv = 32*w + 16*i + 4*lg + reg;
        int dk = 16*sub + lr;
        DSt[obase + (size_t)dv*128 + dk] = (bf16_t)acc[i][sub][reg];
      }
}

// ---------------- in-place prefix scan over chunks: DSt[c] Δ -> S_c --------
__global__ __launch_bounds__(256) void k_scan(bf16_t* __restrict__ DSt) {
  int t = threadIdx.x;
  int bh = blockIdx.y, hh = bh & 7;
  float l2g = head_l2g(hh);
  float g128 = exp2f(l2g * 128.0f);
  int dv = blockIdx.x * 16 + (t >> 4);
  int dk0 = (t & 15) * 8;
  size_t base = ((size_t)bh * 16) * 16384 + (size_t)dv*128 + dk0;
  float S[8] = {};
  for (int c = 0; c < 16; ++c) {
    size_t off = base + (size_t)c * 16384;
    bf16x8 dh = *(const bf16x8*)(DSt + off);
    bf16x8 sh;
    #pragma unroll
    for (int j = 0; j < 8; ++j) sh[j] = (bf16_t)S[j];
    *(bf16x8*)(DSt + off) = sh;
    #pragma unroll
    for (int j = 0; j < 8; ++j)
      S[j] = g128*S[j] + (float)dh[j];
  }
}

// ---------------- retention: cross (Q·S^T) + intra + FUSED groupnorm -------
// grid (16 chunks, 16 bh), 512 thr (8 waves x 16 q-rows), 48KB LDS.
__global__ __launch_bounds__(512, 1) void k_ret(
    const bf16_t* __restrict__ Qg, const bf16_t* __restrict__ Kg,
    const bf16_t* __restrict__ VTg, const bf16_t* __restrict__ DSt,
    const float* __restrict__ gw, const float* __restrict__ gb,
    float* __restrict__ Yn) {
  __shared__ bf16_t Ksh[64][128];
  __shared__ bf16_t Vsh[128][64];
  __shared__ bf16_t Ph[128][64];
  int t = threadIdx.x;
  int lane = t & 63, w = t >> 6;          // 8 waves
  int lr = lane & 15, lg = lane >> 4;
  int c = blockIdx.x, bh = blockIdx.y, hh = bh & 7;
  int s0 = c * 128;
  size_t base  = (size_t)bh * SEQ * DH;
  size_t vbase = (size_t)bh * DH * SEQ;
  float l2g = head_l2g(hh);
  float colf = exp2f(-l2g * (float)lr);
  float g16v[4];
  #pragma unroll
  for (int ts = 0; ts < 4; ++ts) g16v[ts] = exp2f(-l2g * (float)(16*ts));

  bf16x8 qh[4];
  {
    const bf16_t* qp = Qg + base + (size_t)(s0 + 16*w + lr) * DH + lg * 8;
    #pragma unroll
    for (int ks = 0; ks < 4; ++ks)
      qh[ks] = *(const bf16x8*)(qp + 32*ks);
  }
  f32x4 yacc[8];
  #pragma unroll
  for (int i = 0; i < 8; ++i) yacc[i] = (f32x4){0.f,0.f,0.f,0.f};

  for (int idx = t; idx < 1024; idx += 512) {
    int r = idx >> 4, kb = idx & 15;
    int kbs = kb ^ (r & 7);
    *(bf16x8*)&Ksh[r][kbs*8] = *(const bf16x8*)(Kg + base + (size_t)(s0 + r)*DH + kb*8);
  }
  for (int idx = t; idx < 1024; idx += 512) {
    int d = idx >> 3, cb = idx & 7;
    int cbs = cb ^ (d & 7);
    *(bf16x8*)&Vsh[d][cbs*8] = *(const bf16x8*)(VTg + vbase + (size_t)d*SEQ + s0 + cb*8);
  }

  // ---- cross: yacc = Q · S^T (B-frags from global, L2-hot) ----
  {
    const bf16_t* sth = DSt + ((size_t)bh * 16 + c) * 16384;
    #pragma unroll
    for (int sub = 0; sub < 8; ++sub) {
      size_t ro = (size_t)(16*sub + lr) * 128 + 8*lg;
      #pragma unroll
      for (int ks = 0; ks < 4; ++ks) {
        bf16x8 bh_ = *(const bf16x8*)(sth + ro + 32*ks);
        yacc[sub] = __builtin_amdgcn_mfma_f32_16x16x32_bf16(qh[ks], bh_, yacc[sub], 0, 0, 0);
      }
    }
    float rowc[4];
    #pragma unroll
    for (int reg = 0; reg < 4; ++reg)
      rowc[reg] = exp2f(l2g * (float)(16*w + 4*lg + reg + 1));
    #pragma unroll
    for (int sub = 0; sub < 8; ++sub)
      #pragma unroll
      for (int reg = 0; reg < 4; ++reg)
        yacc[sub][reg] *= rowc[reg];
  }
  __syncthreads();

  for (int kt = 0; kt < 2; ++kt) {
    int t0 = kt * 64;
    if (kt == 1) {
      __syncthreads();
      for (int idx = t; idx < 1024; idx += 512) {
        int r = idx >> 4, kb = idx & 15;
        int kbs = kb ^ (r & 7);
        *(bf16x8*)&Ksh[r][kbs*8] = *(const bf16x8*)(Kg + base + (size_t)(s0 + 64 + r)*DH + kb*8);
      }
      for (int idx = t; idx < 1024; idx += 512) {
        int d = idx >> 3, cb = idx & 7;
        int cbs = cb ^ (d & 7);
        *(bf16x8*)&Vsh[d][cbs*8] = *(const bf16x8*)(VTg + vbase + (size_t)d*SEQ + s0 + 64 + cb*8);
      }
    }
    __syncthreads();
    if (!(kt == 1 && w < 4)) {
      float rowf[4];
      #pragma unroll
      for (int reg = 0; reg < 4; ++reg)
        rowf[reg] = exp2f(l2g * (float)(16*w + 4*lg + reg - t0));

      #pragma unroll
      for (int ts = 0; ts < 4; ++ts) {
        f32x4 sacc = (f32x4){0.f,0.f,0.f,0.f};
        int trow = 16*ts + lr;
        #pragma unroll
        for (int ks = 0; ks < 4; ++ks) {
          int kbs = (4*ks + lg) ^ (trow & 7);
          bf16x8 kh8 = *(const bf16x8*)&Ksh[trow][kbs*8];
          sacc = __builtin_amdgcn_mfma_f32_16x16x32_bf16(qh[ks], kh8, sacc, 0, 0, 0);
        }
        float cf = colf * g16v[ts];
        #pragma unroll
        for (int reg = 0; reg < 4; ++reg) {
          int qloc = 4*lg + reg;
          int diff = (16*w + qloc) - (t0 + trow);
          float p = (diff >= 0) ? sacc[reg] * (rowf[reg] * cf) : 0.0f;
          int cb = (trow >> 3) ^ (qloc & 7);
          Ph[16*w + qloc][cb*8 + (trow & 7)] = (bf16_t)p;
        }
      }
      #pragma unroll
      for (int ks = 0; ks < 2; ++ks) {
        int prow = 16*w + lr;
        int pcb = (4*ks + lg) ^ (lr & 7);
        bf16x8 pah = *(const bf16x8*)&Ph[prow][pcb*8];
        #pragma unroll
        for (int sub = 0; sub < 8; ++sub) {
          int drow = 16*sub + lr;
          int vcb = (4*ks + lg) ^ (drow & 7);
          bf16x8 vh8 = *(const bf16x8*)&Vsh[drow][vcb*8];
          yacc[sub] = __builtin_amdgcn_mfma_f32_16x16x32_bf16(pah, vh8, yacc[sub], 0, 0, 0);
        }
      }
    }
  }

  // ---- fused groupnorm ----
  float s1v[4] = {0.f,0.f,0.f,0.f}, s2v[4] = {0.f,0.f,0.f,0.f};
  #pragma unroll
  for (int sub = 0; sub < 8; ++sub)
    #pragma unroll
    for (int reg = 0; reg < 4; ++reg) {
      float v = yacc[sub][reg];
      s1v[reg] += v;
      s2v[reg] += v * v;
    }
  #pragma unroll
  for (int off = 8; off; off >>= 1)
    #pragma unroll
    for (int reg = 0; reg < 4; ++reg) {
      s1v[reg] += __shfl_xor(s1v[reg], off);
      s2v[reg] += __shfl_xor(s2v[reg], off);
    }
  float gwv[8], gbv[8];
  #pragma unroll
  for (int sub = 0; sub < 8; ++sub) {
    gwv[sub] = gw[hh*DH + 16*sub + lr];
    gbv[sub] = gb[hh*DH + 16*sub + lr];
  }
  int b = bh >> 3;
  #pragma unroll
  for (int reg = 0; reg < 4; ++reg) {
    float mean = s1v[reg] * (1.0f/128.0f);
    float var = s2v[reg] * (1.0f/128.0f) - mean*mean;
    float inv = rsqrtf(var + 1e-5f);
    int srow = s0 + 16*w + 4*lg + reg;
    float* op = Yn + (size_t)(b*SEQ + srow) * HD + hh*DH;
    #pragma unroll
    for (int sub = 0; sub < 8; ++sub)
      op[16*sub + lr] = (yacc[sub][reg] - mean) * inv * gwv[sub] + gbv[sub];
  }
}

// ---------------- plain-bf16 MFMA GEMM, 128x128, 8 waves, double-buffered --
__global__ __launch_bounds__(512, 1) void k_gemm(
    const bf16_t* __restrict__ Ag, const bf16_t* __restrict__ Bg,
    const float* __restrict__ E,
    bf16_t* __restrict__ Oh, float* __restrict__ Of, int mode) {
  __shared__ bf16_t SB[2][2][128][64];    // {A,B} x dbuf
  int t = threadIdx.x;
  int lane = t & 63, w = t >> 6;          // 8 waves
  int lr = lane & 15, lg = lane >> 4;
  int wr = w >> 1, wc = w & 1;            // wave tile: 32(m) x 64(n)
  int bid = blockIdx.x;
  int swz = (bid & 7) * 32 + (bid >> 3);  // bijective XCD chunking (256 blocks)
  int n0 = (swz & 7) * 128, m0 = (swz >> 3) * 128;

  const bf16_t* srcs[2] = { Ag + (size_t)m0 * HD, Bg + (size_t)n0 * HD };

  f32x4 acc[2][4];
  #pragma unroll
  for (int i = 0; i < 2; ++i)
    #pragma unroll
    for (int j = 0; j < 4; ++j) acc[i][j] = (f32x4){0.f,0.f,0.f,0.f};

  int srow = lane >> 3, sch = lane & 7;

  #pragma unroll
  for (int bi = 0; bi < 2; ++bi)
    #pragma unroll
    for (int i = 0; i < 2; ++i) {
      int row = w*16 + i*8 + srow;
      int kc = (sch ^ (row & 7)) * 8;
      gld16(srcs[bi] + (size_t)row*HD + kc, &SB[bi][0][w*16 + i*8][0]);
    }
  __syncthreads();

  int buf = 0;
  for (int kt = 0; kt < 16; ++kt) {
    if (kt + 1 < 16) {
      int k0 = (kt + 1) * 64;
      #pragma unroll
      for (int bi = 0; bi < 2; ++bi)
        #pragma unroll
        for (int i = 0; i < 2; ++i) {
          int row = w*16 + i*8 + srow;
          int kc = (sch ^ (row & 7)) * 8;
          gld16(srcs[bi] + (size_t)row*HD + k0 + kc, &SB[bi][buf^1][w*16 + i*8][0]);
        }
    }
    #pragma unroll
    for (int ks = 0; ks < 2; ++ks) {
      bf16x8 a_[2], b_[4];
      #pragma unroll
      for (int mf = 0; mf < 2; ++mf) {
        int row = wr*32 + mf*16 + lr;
        int ch = (lg + 4*ks) ^ (row & 7);
        a_[mf] = *(const bf16x8*)&SB[0][buf][row][ch*8];
      }
      #pragma unroll
      for (int nf = 0; nf < 4; ++nf) {
        int row = wc*64 + nf*16 + lr;
        int ch = (lg + 4*ks) ^ (row & 7);
        b_[nf] = *(const bf16x8*)&SB[1][buf][row][ch*8];
      }
      #pragma unroll
      for (int mf = 0; mf < 2; ++mf)
        #pragma unroll
        for (int nf = 0; nf < 4; ++nf)
          acc[mf][nf] = __builtin_amdgcn_mfma_f32_16x16x32_bf16(a_[mf], b_[nf], acc[mf][nf], 0, 0, 0);
    }
    __syncthreads();
    buf ^= 1;
  }
  #pragma unroll
  for (int mf = 0; mf < 2; ++mf) {
    #pragma unroll
    for (int nf = 0; nf < 4; ++nf) {
      #pragma unroll
      for (int reg = 0; reg < 4; ++reg) {
        int m = m0 + wr*32 + mf*16 + 4*lg + reg;
        int n = n0 + wc*64 + nf*16 + lr;
        float g = acc[mf][nf][reg];
        size_t off = (size_t)m * HD + n;
        if (mode == 1) {
          float sg = 1.0f / (1.0f + expf(-g));
          Oh[off] = (bf16_t)(g * sg * E[off]);
        } else {
          Of[off] = g;
        }
      }
    }
  }
}

extern "C" void kernel_launch(void* const* d_in, const int* in_sizes, int n_in,
                              void* d_out, int out_size, void* d_ws, size_t ws_size,
                              hipStream_t stream) {
  const float* X  = (const float*)d_in[0];
  const float* Wq = (const float*)d_in[1];
  const float* Wk = (const float*)d_in[2];
  const float* Wv = (const float*)d_in[3];
  const float* Wg = (const float*)d_in[4];
  const float* Wo = (const float*)d_in[5];
  const float* gw = (const float*)d_in[6];
  const float* gb = (const float*)d_in[7];
  float* out = (float*)d_out;
  float* ws = (float*)d_ws;

  // ws: tabs 2.1 | Q K VT 3x8.4 | Yn 16.8 | DSt 8.4 | W ~4.8 | Xh 8.4 (~65MB)
  float* tabs = ws;
  bf16_t* Q   = (bf16_t*)(ws + 524288);
  bf16_t* K   = Q + 4194304;
  bf16_t* VT  = K + 4194304;
  float*  Yn  = (float*)(VT + 4194304);
  bf16_t* DSt = (bf16_t*)(Yn + 4194304);
  bf16_t* Wqt = DSt + 4194304;
  bf16_t* Wkt = Wqt + 131072;
  bf16_t* Wvt = Wkt + 131072;
  bf16_t* Wgt = Wvt + 131072;
  bf16_t* Wot = Wgt + 1048576;
  bf16_t* Xh  = Wot + 1048576;
  bf16_t* A2  = Q;                 // Q dead after k_ret

  k_tables<<<dim3(512), dim3(256), 0, stream>>>(tabs);
  k_wsplit<<<dim3(2, 2, 8), dim3(256), 0, stream>>>(Wq, Wqt, DH, DH);
  k_wsplit<<<dim3(2, 2, 8), dim3(256), 0, stream>>>(Wk, Wkt, DH, DH);
  k_wsplit<<<dim3(2, 2, 8), dim3(256), 0, stream>>>(Wv, Wvt, DH, DH);
  k_wsplit<<<dim3(16, 16, 1), dim3(256), 0, stream>>>(Wg, Wgt, HD, HD);
  k_wsplit<<<dim3(16, 16, 1), dim3(256), 0, stream>>>(Wo, Wot, HD, HD);
  k_qkv<<<dim3(32, 8, 2), dim3(256), 0, stream>>>(X, tabs, Wqt, Wkt, Wvt,
                                                  Q, K, VT, Xh);
  k_delta<<<dim3(16, 16), dim3(256), 0, stream>>>(K, VT, DSt);
  k_scan<<<dim3(8, 16), dim3(256), 0, stream>>>(DSt);
  k_ret<<<dim3(16, 16), dim3(512), 0, stream>>>(Q, K, VT, DSt, gw, gb, Yn);
  k_gemm<<<dim3(256), dim3(512), 0, stream>>>(Xh, Wgt, Yn, A2, nullptr, 1);
  k_gemm<<<dim3(256), dim3(512), 0, stream>>>(A2, Wot, nullptr, nullptr, out, 0);
}

// Round 9
// 108.044 us; speedup vs baseline: 7.7900x; 1.0772x over previous
//
#include <hip/hip_runtime.h>
#include <math.h>

#define NB 2
#define SEQ 2048
#define HD 1024
#define NH 8
#define DH 128
#define HALF 64

typedef __bf16 bf16_t;
typedef __attribute__((ext_vector_type(8))) __bf16 bf16x8;
typedef __attribute__((ext_vector_type(4))) __bf16 bf16x4;
typedef __attribute__((ext_vector_type(4))) float f32x4;

typedef __attribute__((address_space(1))) void gvoid;
typedef __attribute__((address_space(3))) void lvoid;

__device__ __forceinline__ void gld16(const bf16_t* g, bf16_t* l) {
  __builtin_amdgcn_global_load_lds((gvoid*)g, (lvoid*)l, 16, 0, 0);
}

__device__ __forceinline__ float head_l2g(int hh) {
  double ga = log(1.0/32.0), gbb = log(1.0/512.0);
  float gamma = (float)(1.0 - exp(ga + (double)hh * (gbb - ga) / 7.0));
  return log2f(gamma);
}

// ---------------- prep: xpos tables + all weight transposes (one launch) ---
__device__ void wsplit_body(const float* __restrict__ in, bf16_t* __restrict__ oh,
                            int M, int N, int bx, int by, int z,
                            float (*tile)[65]) {
  in += (size_t)z * M * N; oh += (size_t)z * M * N;
  int r0 = by * 64, c0 = bx * 64;
  int t = threadIdx.x;
  for (int idx = t; idx < 1024; idx += 256) {
    int r = idx >> 4, c4 = (idx & 15) * 4;
    float4 v = *(const float4*)(in + (size_t)(r0 + r) * N + c0 + c4);
    *(float4*)&tile[r][c4] = v;
  }
  __syncthreads();
  for (int idx = t; idx < 1024; idx += 256) {
    int c = idx >> 4, r4 = (idx & 15) * 4;
    bf16x4 h;
    #pragma unroll
    for (int j = 0; j < 4; ++j)
      h[j] = (bf16_t)tile[r4 + j][c];
    *(bf16x4*)(oh + (size_t)(c0 + c) * M + r0 + r4) = h;
  }
}

__global__ __launch_bounds__(256) void k_prep(
    const float* __restrict__ Wq, const float* __restrict__ Wk,
    const float* __restrict__ Wv, const float* __restrict__ Wg,
    const float* __restrict__ Wo,
    float* __restrict__ tabs, bf16_t* __restrict__ Wqt,
    bf16_t* __restrict__ Wkt, bf16_t* __restrict__ Wvt,
    bf16_t* __restrict__ Wgt, bf16_t* __restrict__ Wot) {
  __shared__ float tile[64][65];
  int b = blockIdx.x;
  if (b < 512) {
    int idx = b * 256 + threadIdx.x;
    int s = idx >> 6, i = idx & 63;
    float dd = (float)DH;
    float scale = (2.0f * (float)i + 0.4f * dd) / (1.4f * dd);
    float sc = expf(logf(scale) * ((float)s / 512.0f));
    float inv_freq = expf(-logf(10000.0f) * ((float)i / (float)HALF));
    float ang = (float)s * inv_freq;
    float sn, cs;
    sincosf(ang, &sn, &cs);
    float rsc = 1.0f / sc;
    tabs[idx]               = sn * sc;
    tabs[SEQ*HALF + idx]    = cs * sc;
    tabs[2*SEQ*HALF + idx]  = sn * rsc;
    tabs[3*SEQ*HALF + idx]  = cs * rsc;
  } else if (b < 608) {
    int i = b - 512;               // 96 blocks: 3 x (2x2x8)
    int which = i >> 5;
    int j = i & 31;
    const float* in = (which == 0) ? Wq : (which == 1) ? Wk : Wv;
    bf16_t* oh = (which == 0) ? Wqt : (which == 1) ? Wkt : Wvt;
    wsplit_body(in, oh, DH, DH, j & 1, (j >> 1) & 1, j >> 2, tile);
  } else {
    int i = b - 608;               // 512 blocks: 2 x (16x16)
    int which = i >> 8;
    int j = i & 255;
    wsplit_body(which ? Wo : Wg, which ? Wot : Wgt, HD, HD,
                j & 15, j >> 4, 0, tile);
  }
}

// ---------------- QKV projection (plain bf16 MFMA) + fused xpos ------------
__global__ __launch_bounds__(256, 2) void k_qkv(
    const float* __restrict__ X, const float* __restrict__ tabs,
    const bf16_t* __restrict__ Wqt, const bf16_t* __restrict__ Wkt,
    const bf16_t* __restrict__ Wvt,
    bf16_t* __restrict__ Qo, bf16_t* __restrict__ Ko,
    bf16_t* __restrict__ VTo, bf16_t* __restrict__ Xhg) {
  __shared__ bf16_t Wsh[128][128];
  int t = threadIdx.x;
  int lane = t & 63, w = t >> 6;
  int lr = lane & 15, lg = lane >> 4;
  int s0 = blockIdx.x * 64;
  int hh = blockIdx.y;
  int b  = blockIdx.z;
  size_t bh = (size_t)(b*NH + hh);

  bf16x8 xh[4];
  {
    const float* xp = X + ((size_t)(b*SEQ + s0 + 16*w + lr)) * HD + hh*DH + 8*lg;
    #pragma unroll
    for (int ks = 0; ks < 4; ++ks) {
      float4 u = *(const float4*)(xp + 32*ks);
      float4 v = *(const float4*)(xp + 32*ks + 4);
      float fv[8] = {u.x,u.y,u.z,u.w,v.x,v.y,v.z,v.w};
      #pragma unroll
      for (int j = 0; j < 8; ++j) xh[ks][j] = (bf16_t)fv[j];
    }
  }
  {
    bf16_t* xo = Xhg + ((size_t)(b*SEQ + s0 + 16*w + lr)) * HD + hh*DH + 8*lg;
    #pragma unroll
    for (int ks = 0; ks < 4; ++ks)
      *(bf16x8*)(xo + 32*ks) = xh[ks];
  }

  const bf16_t* Wp[3] = {Wqt, Wkt, Wvt};

  for (int which = 0; which < 3; ++which) {
    const bf16_t* wp = Wp[which] + (size_t)hh * (DH*DH);
    __syncthreads();
    for (int idx = t; idx < 2048; idx += 256) {
      int e = idx >> 4, kb = idx & 15;
      int kbs = kb ^ (e & 7);
      *(bf16x8*)&Wsh[e][kbs*8] = *(const bf16x8*)(wp + (size_t)e*DH + kb*8);
    }
    __syncthreads();
    f32x4 yacc[8];
    #pragma unroll
    for (int i = 0; i < 8; ++i) yacc[i] = (f32x4){0.f,0.f,0.f,0.f};
    #pragma unroll
    for (int sub = 0; sub < 8; ++sub) {
      int e = 16*sub + lr;
      #pragma unroll
      for (int ks = 0; ks < 4; ++ks) {
        int ch = (lg + 4*ks) ^ (lr & 7);
        bf16x8 bhv = *(const bf16x8*)&Wsh[e][ch*8];
        yacc[sub] = __builtin_amdgcn_mfma_f32_16x16x32_bf16(xh[ks], bhv, yacc[sub], 0, 0, 0);
      }
    }
    if (which < 2) {
      const float* st = tabs + (which ? 2*SEQ*HALF : 0);
      const float* ct = st + SEQ*HALF;
      bf16_t* Op = which ? Ko : Qo;
      #pragma unroll
      for (int sub = 0; sub < 8; ++sub) {
        int e = 16*sub + lr;
        int i = e >> 1;
        #pragma unroll
        for (int reg = 0; reg < 4; ++reg) {
          float v = yacc[sub][reg];
          float p = __shfl_xor(v, 1);
          int srow = s0 + 16*w + 4*lg + reg;
          float sv = st[srow*HALF + i], cv = ct[srow*HALF + i];
          float o = v * cv + ((e & 1) ? p : -p) * sv;
          Op[(bh*SEQ + srow) * DH + e] = (bf16_t)o;
        }
      }
    } else {
      #pragma unroll
      for (int sub = 0; sub < 8; ++sub) {
        int e = 16*sub + lr;
        bf16x4 hv;
        #pragma unroll
        for (int reg = 0; reg < 4; ++reg)
          hv[reg] = (bf16_t)yacc[sub][reg];
        *(bf16x4*)(VTo + bh * (size_t)(DH*SEQ) + (size_t)e*SEQ + (s0 + 16*w + 4*lg)) = hv;
      }
    }
  }
}

// ---------------- delta: Dt[dv][dk] = sum_tau g^(127-tau) V[tau][dv] K[tau][dk]
__global__ __launch_bounds__(256, 1) void k_delta(
    const bf16_t* __restrict__ Kg, const bf16_t* __restrict__ VTg,
    bf16_t* __restrict__ DSt) {
  __shared__ bf16_t KT[128][128];   // [dk][tau], chunk-swz
  __shared__ bf16_t Vd[128][128];   // [dv][tau], chunk-swz
  int t = threadIdx.x;
  int lane = t & 63, w = t >> 6;
  int lr = lane & 15, lg = lane >> 4;
  int c = blockIdx.x, bh = blockIdx.y, hh = bh & 7;
  float l2g = head_l2g(hh);
  size_t kbase = (size_t)bh * SEQ * DH + (size_t)c * 128 * DH;
  size_t vtb   = (size_t)bh * DH * SEQ + (size_t)c * 128;

  for (int idx = t; idx < 2048; idx += 256) {
    int dc = idx >> 7, tau = idx & 127;
    bf16x8 h8 = *(const bf16x8*)(Kg + kbase + (size_t)tau*DH + dc*8);
    #pragma unroll
    for (int j = 0; j < 8; ++j) {
      int d = dc*8 + j;
      int col = (((tau>>3) ^ (d & 7)) << 3) | (tau & 7);
      KT[d][col] = h8[j];
    }
  }
  for (int idx = t; idx < 2048; idx += 256) {
    int dv = idx >> 4, tc = idx & 15;
    bf16x8 h8 = *(const bf16x8*)(VTg + vtb + (size_t)dv*SEQ + tc*8);
    bf16x8 oh;
    #pragma unroll
    for (int j = 0; j < 8; ++j) {
      int tau = tc*8 + j;
      oh[j] = (bf16_t)((float)h8[j] * exp2f(l2g * (float)(127 - tau)));
    }
    int cs = tc ^ (dv & 7);
    *(bf16x8*)&Vd[dv][cs*8] = oh;
  }
  __syncthreads();

  f32x4 acc[2][8];
  #pragma unroll
  for (int i = 0; i < 2; ++i)
    #pragma unroll
    for (int s = 0; s < 8; ++s) acc[i][s] = (f32x4){0.f,0.f,0.f,0.f};

  #pragma unroll
  for (int i = 0; i < 2; ++i) {
    int dv = 32*w + 16*i + lr;
    #pragma unroll
    for (int ks = 0; ks < 4; ++ks) {
      int ca = (lg + 4*ks) ^ (dv & 7);
      bf16x8 avh = *(const bf16x8*)&Vd[dv][ca*8];
      #pragma unroll
      for (int sub = 0; sub < 8; ++sub) {
        int dk = 16*sub + lr;
        int cb = (lg + 4*ks) ^ (dk & 7);
        bf16x8 bkh = *(const bf16x8*)&KT[dk][cb*8];
        acc[i][sub] = __builtin_amdgcn_mfma_f32_16x16x32_bf16(avh, bkh, acc[i][sub], 0, 0, 0);
      }
    }
  }
  size_t obase = ((size_t)bh * 16 + c) * 16384;
  #pragma unroll
  for (int i = 0; i < 2; ++i)
    #pragma unroll
    for (int sub = 0; sub < 8; ++sub)
      #pragma unroll
      for (int reg = 0; reg < 4; ++reg) {
        int dv = 32*w + 16*i + 4*lg + reg;
        int dk = 16*sub + lr;
        DSt[obase + (size_t)dv*128 + dk] = (bf16_t)acc[i][sub][reg];
      }
}

// ---------------- in-place prefix scan over chunks: DSt[c] Δ -> S_c --------
__global__ __launch_bounds__(256) void k_scan(bf16_t* __restrict__ DSt) {
  int t = threadIdx.x;
  int bh = blockIdx.y, hh = bh & 7;
  float l2g = head_l2g(hh);
  float g128 = exp2f(l2g * 128.0f);
  int dv = blockIdx.x * 16 + (t >> 4);
  int dk0 = (t & 15) * 8;
  size_t base = ((size_t)bh * 16) * 16384 + (size_t)dv*128 + dk0;
  float S[8] = {};
  for (int c = 0; c < 16; ++c) {
    size_t off = base + (size_t)c * 16384;
    bf16x8 dh = *(const bf16x8*)(DSt + off);
    bf16x8 sh;
    #pragma unroll
    for (int j = 0; j < 8; ++j) sh[j] = (bf16_t)S[j];
    *(bf16x8*)(DSt + off) = sh;
    #pragma unroll
    for (int j = 0; j < 8; ++j)
      S[j] = g128*S[j] + (float)dh[j];
  }
}

// ---------------- retention: cross (Q·S^T) + intra + FUSED groupnorm -------
// writes Yn as bf16 in (b,s,H) layout.
__global__ __launch_bounds__(512, 1) void k_ret(
    const bf16_t* __restrict__ Qg, const bf16_t* __restrict__ Kg,
    const bf16_t* __restrict__ VTg, const bf16_t* __restrict__ DSt,
    const float* __restrict__ gw, const float* __restrict__ gb,
    bf16_t* __restrict__ Yn) {
  __shared__ bf16_t Ksh[64][128];
  __shared__ bf16_t Vsh[128][64];
  __shared__ bf16_t Ph[128][64];
  int t = threadIdx.x;
  int lane = t & 63, w = t >> 6;          // 8 waves
  int lr = lane & 15, lg = lane >> 4;
  int c = blockIdx.x, bh = blockIdx.y, hh = bh & 7;
  int s0 = c * 128;
  size_t base  = (size_t)bh * SEQ * DH;
  size_t vbase = (size_t)bh * DH * SEQ;
  float l2g = head_l2g(hh);
  float colf = exp2f(-l2g * (float)lr);
  float g16v[4];
  #pragma unroll
  for (int ts = 0; ts < 4; ++ts) g16v[ts] = exp2f(-l2g * (float)(16*ts));

  bf16x8 qh[4];
  {
    const bf16_t* qp = Qg + base + (size_t)(s0 + 16*w + lr) * DH + lg * 8;
    #pragma unroll
    for (int ks = 0; ks < 4; ++ks)
      qh[ks] = *(const bf16x8*)(qp + 32*ks);
  }
  f32x4 yacc[8];
  #pragma unroll
  for (int i = 0; i < 8; ++i) yacc[i] = (f32x4){0.f,0.f,0.f,0.f};

  for (int idx = t; idx < 1024; idx += 512) {
    int r = idx >> 4, kb = idx & 15;
    int kbs = kb ^ (r & 7);
    *(bf16x8*)&Ksh[r][kbs*8] = *(const bf16x8*)(Kg + base + (size_t)(s0 + r)*DH + kb*8);
  }
  for (int idx = t; idx < 1024; idx += 512) {
    int d = idx >> 3, cb = idx & 7;
    int cbs = cb ^ (d & 7);
    *(bf16x8*)&Vsh[d][cbs*8] = *(const bf16x8*)(VTg + vbase + (size_t)d*SEQ + s0 + cb*8);
  }

  // ---- cross: yacc = Q · S^T (B-frags from global, L2-hot) ----
  {
    const bf16_t* sth = DSt + ((size_t)bh * 16 + c) * 16384;
    #pragma unroll
    for (int sub = 0; sub < 8; ++sub) {
      size_t ro = (size_t)(16*sub + lr) * 128 + 8*lg;
      #pragma unroll
      for (int ks = 0; ks < 4; ++ks) {
        bf16x8 bh_ = *(const bf16x8*)(sth + ro + 32*ks);
        yacc[sub] = __builtin_amdgcn_mfma_f32_16x16x32_bf16(qh[ks], bh_, yacc[sub], 0, 0, 0);
      }
    }
    float rowc[4];
    #pragma unroll
    for (int reg = 0; reg < 4; ++reg)
      rowc[reg] = exp2f(l2g * (float)(16*w + 4*lg + reg + 1));
    #pragma unroll
    for (int sub = 0; sub < 8; ++sub)
      #pragma unroll
      for (int reg = 0; reg < 4; ++reg)
        yacc[sub][reg] *= rowc[reg];
  }
  __syncthreads();

  for (int kt = 0; kt < 2; ++kt) {
    int t0 = kt * 64;
    if (kt == 1) {
      __syncthreads();
      for (int idx = t; idx < 1024; idx += 512) {
        int r = idx >> 4, kb = idx & 15;
        int kbs = kb ^ (r & 7);
        *(bf16x8*)&Ksh[r][kbs*8] = *(const bf16x8*)(Kg + base + (size_t)(s0 + 64 + r)*DH + kb*8);
      }
      for (int idx = t; idx < 1024; idx += 512) {
        int d = idx >> 3, cb = idx & 7;
        int cbs = cb ^ (d & 7);
        *(bf16x8*)&Vsh[d][cbs*8] = *(const bf16x8*)(VTg + vbase + (size_t)d*SEQ + s0 + 64 + cb*8);
      }
    }
    __syncthreads();
    if (!(kt == 1 && w < 4)) {
      float rowf[4];
      #pragma unroll
      for (int reg = 0; reg < 4; ++reg)
        rowf[reg] = exp2f(l2g * (float)(16*w + 4*lg + reg - t0));

      #pragma unroll
      for (int ts = 0; ts < 4; ++ts) {
        f32x4 sacc = (f32x4){0.f,0.f,0.f,0.f};
        int trow = 16*ts + lr;
        #pragma unroll
        for (int ks = 0; ks < 4; ++ks) {
          int kbs = (4*ks + lg) ^ (trow & 7);
          bf16x8 kh8 = *(const bf16x8*)&Ksh[trow][kbs*8];
          sacc = __builtin_amdgcn_mfma_f32_16x16x32_bf16(qh[ks], kh8, sacc, 0, 0, 0);
        }
        float cf = colf * g16v[ts];
        #pragma unroll
        for (int reg = 0; reg < 4; ++reg) {
          int qloc = 4*lg + reg;
          int diff = (16*w + qloc) - (t0 + trow);
          float p = (diff >= 0) ? sacc[reg] * (rowf[reg] * cf) : 0.0f;
          int cb = (trow >> 3) ^ (qloc & 7);
          Ph[16*w + qloc][cb*8 + (trow & 7)] = (bf16_t)p;
        }
      }
      #pragma unroll
      for (int ks = 0; ks < 2; ++ks) {
        int prow = 16*w + lr;
        int pcb = (4*ks + lg) ^ (lr & 7);
        bf16x8 pah = *(const bf16x8*)&Ph[prow][pcb*8];
        #pragma unroll
        for (int sub = 0; sub < 8; ++sub) {
          int drow = 16*sub + lr;
          int vcb = (4*ks + lg) ^ (drow & 7);
          bf16x8 vh8 = *(const bf16x8*)&Vsh[drow][vcb*8];
          yacc[sub] = __builtin_amdgcn_mfma_f32_16x16x32_bf16(pah, vh8, yacc[sub], 0, 0, 0);
        }
      }
    }
  }

  // ---- fused groupnorm (bf16 out) ----
  float s1v[4] = {0.f,0.f,0.f,0.f}, s2v[4] = {0.f,0.f,0.f,0.f};
  #pragma unroll
  for (int sub = 0; sub < 8; ++sub)
    #pragma unroll
    for (int reg = 0; reg < 4; ++reg) {
      float v = yacc[sub][reg];
      s1v[reg] += v;
      s2v[reg] += v * v;
    }
  #pragma unroll
  for (int off = 8; off; off >>= 1)
    #pragma unroll
    for (int reg = 0; reg < 4; ++reg) {
      s1v[reg] += __shfl_xor(s1v[reg], off);
      s2v[reg] += __shfl_xor(s2v[reg], off);
    }
  float gwv[8], gbv[8];
  #pragma unroll
  for (int sub = 0; sub < 8; ++sub) {
    gwv[sub] = gw[hh*DH + 16*sub + lr];
    gbv[sub] = gb[hh*DH + 16*sub + lr];
  }
  int b = bh >> 3;
  #pragma unroll
  for (int reg = 0; reg < 4; ++reg) {
    float mean = s1v[reg] * (1.0f/128.0f);
    float var = s2v[reg] * (1.0f/128.0f) - mean*mean;
    float inv = rsqrtf(var + 1e-5f);
    int srow = s0 + 16*w + 4*lg + reg;
    bf16_t* op = Yn + (size_t)(b*SEQ + srow) * HD + hh*DH;
    #pragma unroll
    for (int sub = 0; sub < 8; ++sub)
      op[16*sub + lr] = (bf16_t)((yacc[sub][reg] - mean) * inv * gwv[sub] + gbv[sub]);
  }
}

// ---------------- plain-bf16 MFMA GEMM, 64x128 tile, 2 blocks/CU -----------
// A: bf16 [M][K]. B: bf16 [N][K] (W^T). E: bf16 (mode 1).
__global__ __launch_bounds__(256, 2) void k_gemm(
    const bf16_t* __restrict__ Ag, const bf16_t* __restrict__ Bg,
    const bf16_t* __restrict__ E,
    bf16_t* __restrict__ Oh, float* __restrict__ Of, int mode) {
  __shared__ bf16_t SA[2][64][64];
  __shared__ bf16_t SBB[2][128][64];
  int t = threadIdx.x;
  int lane = t & 63, w = t >> 6;          // 4 waves
  int lr = lane & 15, lg = lane >> 4;
  int wr = w >> 1, wc = w & 1;            // wave tile: 32(m) x 64(n)
  int bid = blockIdx.x;                   // 512 blocks
  int xcd = bid & 7, local = bid >> 3;
  int mp = xcd * 8 + (local >> 3);        // 64 m-panels, 8 contiguous per XCD
  int np = local & 7;                     // 8 n-panels
  int m0 = mp * 64, n0 = np * 128;

  const bf16_t* As = Ag + (size_t)m0 * HD;
  const bf16_t* Bs = Bg + (size_t)n0 * HD;

  f32x4 acc[2][4];
  #pragma unroll
  for (int i = 0; i < 2; ++i)
    #pragma unroll
    for (int j = 0; j < 4; ++j) acc[i][j] = (f32x4){0.f,0.f,0.f,0.f};

  int srow = lane >> 3, sch = lane & 7;

  // prologue: stage K-step 0 into buf 0
  {
    #pragma unroll
    for (int i = 0; i < 2; ++i) {
      int row = w*16 + i*8 + srow;
      int kc = (sch ^ (row & 7)) * 8;
      gld16(As + (size_t)row*HD + kc, &SA[0][w*16 + i*8][0]);
    }
    #pragma unroll
    for (int i = 0; i < 4; ++i) {
      int row = w*32 + i*8 + srow;
      int kc = (sch ^ (row & 7)) * 8;
      gld16(Bs + (size_t)row*HD + kc, &SBB[0][w*32 + i*8][0]);
    }
  }
  __syncthreads();

  int buf = 0;
  for (int kt = 0; kt < 16; ++kt) {
    if (kt + 1 < 16) {
      int k0 = (kt + 1) * 64;
      #pragma unroll
      for (int i = 0; i < 2; ++i) {
        int row = w*16 + i*8 + srow;
        int kc = (sch ^ (row & 7)) * 8;
        gld16(As + (size_t)row*HD + k0 + kc, &SA[buf^1][w*16 + i*8][0]);
      }
      #pragma unroll
      for (int i = 0; i < 4; ++i) {
        int row = w*32 + i*8 + srow;
        int kc = (sch ^ (row & 7)) * 8;
        gld16(Bs + (size_t)row*HD + k0 + kc, &SBB[buf^1][w*32 + i*8][0]);
      }
    }
    #pragma unroll
    for (int ks = 0; ks < 2; ++ks) {
      bf16x8 a_[2], b_[4];
      #pragma unroll
      for (int mf = 0; mf < 2; ++mf) {
        int row = wr*32 + mf*16 + lr;
        int ch = (lg + 4*ks) ^ (row & 7);
        a_[mf] = *(const bf16x8*)&SA[buf][row][ch*8];
      }
      #pragma unroll
      for (int nf = 0; nf < 4; ++nf) {
        int row = wc*64 + nf*16 + lr;
        int ch = (lg + 4*ks) ^ (row & 7);
        b_[nf] = *(const bf16x8*)&SBB[buf][row][ch*8];
      }
      #pragma unroll
      for (int mf = 0; mf < 2; ++mf)
        #pragma unroll
        for (int nf = 0; nf < 4; ++nf)
          acc[mf][nf] = __builtin_amdgcn_mfma_f32_16x16x32_bf16(a_[mf], b_[nf], acc[mf][nf], 0, 0, 0);
    }
    __syncthreads();
    buf ^= 1;
  }
  #pragma unroll
  for (int mf = 0; mf < 2; ++mf) {
    #pragma unroll
    for (int nf = 0; nf < 4; ++nf) {
      #pragma unroll
      for (int reg = 0; reg < 4; ++reg) {
        int m = m0 + wr*32 + mf*16 + 4*lg + reg;
        int n = n0 + wc*64 + nf*16 + lr;
        float g = acc[mf][nf][reg];
        size_t off = (size_t)m * HD + n;
        if (mode == 1) {
          float sg = 1.0f / (1.0f + expf(-g));
          Oh[off] = (bf16_t)(g * sg * (float)E[off]);
        } else {
          Of[off] = g;
        }
      }
    }
  }
}

extern "C" void kernel_launch(void* const* d_in, const int* in_sizes, int n_in,
                              void* d_out, int out_size, void* d_ws, size_t ws_size,
                              hipStream_t stream) {
  const float* X  = (const float*)d_in[0];
  const float* Wq = (const float*)d_in[1];
  const float* Wk = (const float*)d_in[2];
  const float* Wv = (const float*)d_in[3];
  const float* Wg = (const float*)d_in[4];
  const float* Wo = (const float*)d_in[5];
  const float* gw = (const float*)d_in[6];
  const float* gb = (const float*)d_in[7];
  float* out = (float*)d_out;
  float* ws = (float*)d_ws;

  // ws: tabs 2.1MB | Q K VT 3x8.4 | Yn 8.4 | DSt 8.4 | W ~4.8 | Xh 8.4 (~57MB)
  float* tabs = ws;
  bf16_t* Q   = (bf16_t*)(ws + 524288);
  bf16_t* K   = Q + 4194304;
  bf16_t* VT  = K + 4194304;
  bf16_t* Yn  = VT + 4194304;      // bf16 now
  bf16_t* DSt = Yn + 4194304;
  bf16_t* Wqt = DSt + 4194304;
  bf16_t* Wkt = Wqt + 131072;
  bf16_t* Wvt = Wkt + 131072;
  bf16_t* Wgt = Wvt + 131072;
  bf16_t* Wot = Wgt + 1048576;
  bf16_t* Xh  = Wot + 1048576;
  bf16_t* A2  = Q;                 // Q dead after k_ret

  k_prep<<<dim3(1120), dim3(256), 0, stream>>>(Wq, Wk, Wv, Wg, Wo, tabs,
                                               Wqt, Wkt, Wvt, Wgt, Wot);
  k_qkv<<<dim3(32, 8, 2), dim3(256), 0, stream>>>(X, tabs, Wqt, Wkt, Wvt,
                                                  Q, K, VT, Xh);
  k_delta<<<dim3(16, 16), dim3(256), 0, stream>>>(K, VT, DSt);
  k_scan<<<dim3(8, 16), dim3(256), 0, stream>>>(DSt);
  k_ret<<<dim3(16, 16), dim3(512), 0, stream>>>(Q, K, VT, DSt, gw, gb, Yn);
  k_gemm<<<dim3(512), dim3(256), 0, stream>>>(Xh, Wgt, Yn, A2, nullptr, 1);
  k_gemm<<<dim3(512), dim3(256), 0, stream>>>(A2, Wot, nullptr, nullptr, out, 0);
}

// Round 10
// 98.101 us; speedup vs baseline: 8.5795x; 1.1013x over previous
//
#include <hip/hip_runtime.h>
#include <math.h>

#define NB 2
#define SEQ 2048
#define HD 1024
#define NH 8
#define DH 128
#define HALF 64

typedef __bf16 bf16_t;
typedef __attribute__((ext_vector_type(8))) __bf16 bf16x8;
typedef __attribute__((ext_vector_type(4))) __bf16 bf16x4;
typedef __attribute__((ext_vector_type(4))) float f32x4;

typedef __attribute__((address_space(1))) void gvoid;
typedef __attribute__((address_space(3))) void lvoid;

__device__ __forceinline__ void gld16(const bf16_t* g, bf16_t* l) {
  __builtin_amdgcn_global_load_lds((gvoid*)g, (lvoid*)l, 16, 0, 0);
}

__device__ __forceinline__ float head_l2g(int hh) {
  double ga = log(1.0/32.0), gbb = log(1.0/512.0);
  float gamma = (float)(1.0 - exp(ga + (double)hh * (gbb - ga) / 7.0));
  return log2f(gamma);
}

// ---------------- prep: xpos tables + all weight transposes (one launch) ---
__device__ void wsplit_body(const float* __restrict__ in, bf16_t* __restrict__ oh,
                            int M, int N, int bx, int by, int z,
                            float (*tile)[65]) {
  in += (size_t)z * M * N; oh += (size_t)z * M * N;
  int r0 = by * 64, c0 = bx * 64;
  int t = threadIdx.x;
  for (int idx = t; idx < 1024; idx += 256) {
    int r = idx >> 4, c4 = (idx & 15) * 4;
    float4 v = *(const float4*)(in + (size_t)(r0 + r) * N + c0 + c4);
    *(float4*)&tile[r][c4] = v;
  }
  __syncthreads();
  for (int idx = t; idx < 1024; idx += 256) {
    int c = idx >> 4, r4 = (idx & 15) * 4;
    bf16x4 h;
    #pragma unroll
    for (int j = 0; j < 4; ++j)
      h[j] = (bf16_t)tile[r4 + j][c];
    *(bf16x4*)(oh + (size_t)(c0 + c) * M + r0 + r4) = h;
  }
}

__global__ __launch_bounds__(256) void k_prep(
    const float* __restrict__ Wq, const float* __restrict__ Wk,
    const float* __restrict__ Wv, const float* __restrict__ Wg,
    const float* __restrict__ Wo,
    float* __restrict__ tabs, bf16_t* __restrict__ Wqt,
    bf16_t* __restrict__ Wkt, bf16_t* __restrict__ Wvt,
    bf16_t* __restrict__ Wgt, bf16_t* __restrict__ Wot) {
  __shared__ float tile[64][65];
  int b = blockIdx.x;
  if (b < 512) {
    int idx = b * 256 + threadIdx.x;
    int s = idx >> 6, i = idx & 63;
    float dd = (float)DH;
    float scale = (2.0f * (float)i + 0.4f * dd) / (1.4f * dd);
    float sc = expf(logf(scale) * ((float)s / 512.0f));
    float inv_freq = expf(-logf(10000.0f) * ((float)i / (float)HALF));
    float ang = (float)s * inv_freq;
    float sn, cs;
    sincosf(ang, &sn, &cs);
    float rsc = 1.0f / sc;
    tabs[idx]               = sn * sc;
    tabs[SEQ*HALF + idx]    = cs * sc;
    tabs[2*SEQ*HALF + idx]  = sn * rsc;
    tabs[3*SEQ*HALF + idx]  = cs * rsc;
  } else if (b < 608) {
    int i = b - 512;               // 96 blocks: 3 x (2x2x8)
    int which = i >> 5;
    int j = i & 31;
    const float* in = (which == 0) ? Wq : (which == 1) ? Wk : Wv;
    bf16_t* oh = (which == 0) ? Wqt : (which == 1) ? Wkt : Wvt;
    wsplit_body(in, oh, DH, DH, j & 1, (j >> 1) & 1, j >> 2, tile);
  } else {
    int i = b - 608;               // 512 blocks: 2 x (16x16)
    int which = i >> 8;
    int j = i & 255;
    wsplit_body(which ? Wo : Wg, which ? Wot : Wgt, HD, HD,
                j & 15, j >> 4, 0, tile);
  }
}

// ---------------- fused QKV projection + xpos + per-chunk delta ------------
// grid (16 chunks, 8 heads, 2 batch), 512 thr (8 waves x 16 rows), 96KB LDS.
// Writes Q, K row-major; VT transposed; Xh bf16; DSt[bh][c] = Δ_c.
__global__ __launch_bounds__(512, 1) void k_qkvd(
    const float* __restrict__ X, const float* __restrict__ tabs,
    const bf16_t* __restrict__ Wqt, const bf16_t* __restrict__ Wkt,
    const bf16_t* __restrict__ Wvt,
    bf16_t* __restrict__ Qo, bf16_t* __restrict__ Ko,
    bf16_t* __restrict__ VTo, bf16_t* __restrict__ Xhg,
    bf16_t* __restrict__ DSt) {
  __shared__ bf16_t Wsh[128][128];     // W^T tile (per weight, reused)
  __shared__ bf16_t KT[128][128];      // [dk][tau], chunk-swz (post-xpos K)
  __shared__ bf16_t Vd[128][128];      // [dv][tau], chunk-swz (decayed V)
  int t = threadIdx.x;
  int lane = t & 63, w = t >> 6;       // 8 waves
  int lr = lane & 15, lg = lane >> 4;
  int c = blockIdx.x, hh = blockIdx.y, b = blockIdx.z;
  int s0 = c * 128;
  size_t bh = (size_t)(b*NH + hh);
  float l2g = head_l2g(hh);

  // X fragments: row s0+16w+lr, k-chunks 8*lg + 32*ks
  bf16x8 xh[4];
  {
    const float* xp = X + ((size_t)(b*SEQ + s0 + 16*w + lr)) * HD + hh*DH + 8*lg;
    #pragma unroll
    for (int ks = 0; ks < 4; ++ks) {
      float4 u = *(const float4*)(xp + 32*ks);
      float4 v = *(const float4*)(xp + 32*ks + 4);
      float fv[8] = {u.x,u.y,u.z,u.w,v.x,v.y,v.z,v.w};
      #pragma unroll
      for (int j = 0; j < 8; ++j) xh[ks][j] = (bf16_t)fv[j];
    }
  }
  {
    bf16_t* xo = Xhg + ((size_t)(b*SEQ + s0 + 16*w + lr)) * HD + hh*DH + 8*lg;
    #pragma unroll
    for (int ks = 0; ks < 4; ++ks)
      *(bf16x8*)(xo + 32*ks) = xh[ks];
  }

  const bf16_t* Wp[3] = {Wqt, Wkt, Wvt};

  for (int which = 0; which < 3; ++which) {
    const bf16_t* wp = Wp[which] + (size_t)hh * (DH*DH);
    __syncthreads();                    // Wsh free (prev pass done)
    for (int idx = t; idx < 2048; idx += 512) {
      int e = idx >> 4, kb = idx & 15;
      int kbs = kb ^ (e & 7);
      *(bf16x8*)&Wsh[e][kbs*8] = *(const bf16x8*)(wp + (size_t)e*DH + kb*8);
    }
    __syncthreads();
    f32x4 yacc[8];
    #pragma unroll
    for (int i = 0; i < 8; ++i) yacc[i] = (f32x4){0.f,0.f,0.f,0.f};
    #pragma unroll
    for (int sub = 0; sub < 8; ++sub) {
      int e = 16*sub + lr;
      #pragma unroll
      for (int ks = 0; ks < 4; ++ks) {
        int ch = (lg + 4*ks) ^ (lr & 7);
        bf16x8 bhv = *(const bf16x8*)&Wsh[e][ch*8];
        yacc[sub] = __builtin_amdgcn_mfma_f32_16x16x32_bf16(xh[ks], bhv, yacc[sub], 0, 0, 0);
      }
    }
    // epilogue: C row (tau-local) = 16w+4lg+reg, col e = 16sub+lr
    if (which < 2) {
      const float* st = tabs + (which ? 2*SEQ*HALF : 0);
      const float* ct = st + SEQ*HALF;
      bf16_t* Op = which ? Ko : Qo;
      #pragma unroll
      for (int sub = 0; sub < 8; ++sub) {
        int e = 16*sub + lr;
        int i = e >> 1;
        #pragma unroll
        for (int reg = 0; reg < 4; ++reg) {
          float v = yacc[sub][reg];
          float p = __shfl_xor(v, 1);
          int tau = 16*w + 4*lg + reg;
          int srow = s0 + tau;
          float sv = st[srow*HALF + i], cv = ct[srow*HALF + i];
          float o = v * cv + ((e & 1) ? p : -p) * sv;
          bf16_t ob = (bf16_t)o;
          Op[(bh*SEQ + srow) * DH + e] = ob;
          if (which == 1) {             // stash K^T for delta
            int col = (((tau>>3) ^ (e & 7)) << 3) | (tau & 7);
            KT[e][col] = ob;
          }
        }
      }
    } else {
      float decay[4];
      #pragma unroll
      for (int reg = 0; reg < 4; ++reg)
        decay[reg] = exp2f(l2g * (float)(127 - (16*w + 4*lg + reg)));
      #pragma unroll
      for (int sub = 0; sub < 8; ++sub) {
        int e = 16*sub + lr;
        bf16x4 hv;
        #pragma unroll
        for (int reg = 0; reg < 4; ++reg) {
          int tau = 16*w + 4*lg + reg;
          float f = yacc[sub][reg];
          hv[reg] = (bf16_t)f;
          int col = (((tau>>3) ^ (e & 7)) << 3) | (tau & 7);
          Vd[e][col] = (bf16_t)(f * decay[reg]);   // decayed V^T for delta
        }
        *(bf16x4*)(VTo + bh * (size_t)(DH*SEQ) + (size_t)e*SEQ + (s0 + 16*w + 4*lg)) = hv;
      }
    }
  }
  __syncthreads();                      // KT / Vd complete

  // ---- delta: Dt[dv][dk] = sum_tau Vd[dv][tau] * KT[dk][tau] ----
  f32x4 acc[8];
  #pragma unroll
  for (int s = 0; s < 8; ++s) acc[s] = (f32x4){0.f,0.f,0.f,0.f};
  {
    int dv = 16*w + lr;
    #pragma unroll
    for (int ks = 0; ks < 4; ++ks) {
      int ca = (lg + 4*ks) ^ (dv & 7);
      bf16x8 avh = *(const bf16x8*)&Vd[dv][ca*8];
      #pragma unroll
      for (int sub = 0; sub < 8; ++sub) {
        int dk = 16*sub + lr;
        int cb = (lg + 4*ks) ^ (dk & 7);
        bf16x8 bkh = *(const bf16x8*)&KT[dk][cb*8];
        acc[sub] = __builtin_amdgcn_mfma_f32_16x16x32_bf16(avh, bkh, acc[sub], 0, 0, 0);
      }
    }
  }
  size_t obase = (bh * 16 + c) * 16384;
  #pragma unroll
  for (int sub = 0; sub < 8; ++sub)
    #pragma unroll
    for (int reg = 0; reg < 4; ++reg) {
      int dv = 16*w + 4*lg + reg;
      int dk = 16*sub + lr;
      DSt[obase + (size_t)dv*128 + dk] = (bf16_t)acc[sub][reg];
    }
}

// ---------------- in-place prefix scan over chunks: DSt[c] Δ -> S_c --------
__global__ __launch_bounds__(256) void k_scan(bf16_t* __restrict__ DSt) {
  int t = threadIdx.x;
  int bh = blockIdx.y, hh = bh & 7;
  float l2g = head_l2g(hh);
  float g128 = exp2f(l2g * 128.0f);
  int dv = blockIdx.x * 16 + (t >> 4);
  int dk0 = (t & 15) * 8;
  size_t base = ((size_t)bh * 16) * 16384 + (size_t)dv*128 + dk0;
  float S[8] = {};
  for (int c = 0; c < 16; ++c) {
    size_t off = base + (size_t)c * 16384;
    bf16x8 dh = *(const bf16x8*)(DSt + off);
    bf16x8 sh;
    #pragma unroll
    for (int j = 0; j < 8; ++j) sh[j] = (bf16_t)S[j];
    *(bf16x8*)(DSt + off) = sh;
    #pragma unroll
    for (int j = 0; j < 8; ++j)
      S[j] = g128*S[j] + (float)dh[j];
  }
}

// ---------------- retention: cross (Q·S^T) + intra + FUSED groupnorm -------
// writes Yn as bf16 in (b,s,H) layout.
__global__ __launch_bounds__(512, 1) void k_ret(
    const bf16_t* __restrict__ Qg, const bf16_t* __restrict__ Kg,
    const bf16_t* __restrict__ VTg, const bf16_t* __restrict__ DSt,
    const float* __restrict__ gw, const float* __restrict__ gb,
    bf16_t* __restrict__ Yn) {
  __shared__ bf16_t Ksh[64][128];
  __shared__ bf16_t Vsh[128][64];
  __shared__ bf16_t Ph[128][64];
  int t = threadIdx.x;
  int lane = t & 63, w = t >> 6;          // 8 waves
  int lr = lane & 15, lg = lane >> 4;
  int c = blockIdx.x, bh = blockIdx.y, hh = bh & 7;
  int s0 = c * 128;
  size_t base  = (size_t)bh * SEQ * DH;
  size_t vbase = (size_t)bh * DH * SEQ;
  float l2g = head_l2g(hh);
  float colf = exp2f(-l2g * (float)lr);
  float g16v[4];
  #pragma unroll
  for (int ts = 0; ts < 4; ++ts) g16v[ts] = exp2f(-l2g * (float)(16*ts));

  bf16x8 qh[4];
  {
    const bf16_t* qp = Qg + base + (size_t)(s0 + 16*w + lr) * DH + lg * 8;
    #pragma unroll
    for (int ks = 0; ks < 4; ++ks)
      qh[ks] = *(const bf16x8*)(qp + 32*ks);
  }
  f32x4 yacc[8];
  #pragma unroll
  for (int i = 0; i < 8; ++i) yacc[i] = (f32x4){0.f,0.f,0.f,0.f};

  for (int idx = t; idx < 1024; idx += 512) {
    int r = idx >> 4, kb = idx & 15;
    int kbs = kb ^ (r & 7);
    *(bf16x8*)&Ksh[r][kbs*8] = *(const bf16x8*)(Kg + base + (size_t)(s0 + r)*DH + kb*8);
  }
  for (int idx = t; idx < 1024; idx += 512) {
    int d = idx >> 3, cb = idx & 7;
    int cbs = cb ^ (d & 7);
    *(bf16x8*)&Vsh[d][cbs*8] = *(const bf16x8*)(VTg + vbase + (size_t)d*SEQ + s0 + cb*8);
  }

  // ---- cross: yacc = Q · S^T (B-frags from global, L2-hot) ----
  {
    const bf16_t* sth = DSt + ((size_t)bh * 16 + c) * 16384;
    #pragma unroll
    for (int sub = 0; sub < 8; ++sub) {
      size_t ro = (size_t)(16*sub + lr) * 128 + 8*lg;
      #pragma unroll
      for (int ks = 0; ks < 4; ++ks) {
        bf16x8 bh_ = *(const bf16x8*)(sth + ro + 32*ks);
        yacc[sub] = __builtin_amdgcn_mfma_f32_16x16x32_bf16(qh[ks], bh_, yacc[sub], 0, 0, 0);
      }
    }
    float rowc[4];
    #pragma unroll
    for (int reg = 0; reg < 4; ++reg)
      rowc[reg] = exp2f(l2g * (float)(16*w + 4*lg + reg + 1));
    #pragma unroll
    for (int sub = 0; sub < 8; ++sub)
      #pragma unroll
      for (int reg = 0; reg < 4; ++reg)
        yacc[sub][reg] *= rowc[reg];
  }
  __syncthreads();

  for (int kt = 0; kt < 2; ++kt) {
    int t0 = kt * 64;
    if (kt == 1) {
      __syncthreads();
      for (int idx = t; idx < 1024; idx += 512) {
        int r = idx >> 4, kb = idx & 15;
        int kbs = kb ^ (r & 7);
        *(bf16x8*)&Ksh[r][kbs*8] = *(const bf16x8*)(Kg + base + (size_t)(s0 + 64 + r)*DH + kb*8);
      }
      for (int idx = t; idx < 1024; idx += 512) {
        int d = idx >> 3, cb = idx & 7;
        int cbs = cb ^ (d & 7);
        *(bf16x8*)&Vsh[d][cbs*8] = *(const bf16x8*)(VTg + vbase + (size_t)d*SEQ + s0 + 64 + cb*8);
      }
    }
    __syncthreads();
    if (!(kt == 1 && w < 4)) {
      float rowf[4];
      #pragma unroll
      for (int reg = 0; reg < 4; ++reg)
        rowf[reg] = exp2f(l2g * (float)(16*w + 4*lg + reg - t0));

      #pragma unroll
      for (int ts = 0; ts < 4; ++ts) {
        f32x4 sacc = (f32x4){0.f,0.f,0.f,0.f};
        int trow = 16*ts + lr;
        #pragma unroll
        for (int ks = 0; ks < 4; ++ks) {
          int kbs = (4*ks + lg) ^ (trow & 7);
          bf16x8 kh8 = *(const bf16x8*)&Ksh[trow][kbs*8];
          sacc = __builtin_amdgcn_mfma_f32_16x16x32_bf16(qh[ks], kh8, sacc, 0, 0, 0);
        }
        float cf = colf * g16v[ts];
        #pragma unroll
        for (int reg = 0; reg < 4; ++reg) {
          int qloc = 4*lg + reg;
          int diff = (16*w + qloc) - (t0 + trow);
          float p = (diff >= 0) ? sacc[reg] * (rowf[reg] * cf) : 0.0f;
          int cb = (trow >> 3) ^ (qloc & 7);
          Ph[16*w + qloc][cb*8 + (trow & 7)] = (bf16_t)p;
        }
      }
      #pragma unroll
      for (int ks = 0; ks < 2; ++ks) {
        int prow = 16*w + lr;
        int pcb = (4*ks + lg) ^ (lr & 7);
        bf16x8 pah = *(const bf16x8*)&Ph[prow][pcb*8];
        #pragma unroll
        for (int sub = 0; sub < 8; ++sub) {
          int drow = 16*sub + lr;
          int vcb = (4*ks + lg) ^ (drow & 7);
          bf16x8 vh8 = *(const bf16x8*)&Vsh[drow][vcb*8];
          yacc[sub] = __builtin_amdgcn_mfma_f32_16x16x32_bf16(pah, vh8, yacc[sub], 0, 0, 0);
        }
      }
    }
  }

  // ---- fused groupnorm (bf16 out) ----
  float s1v[4] = {0.f,0.f,0.f,0.f}, s2v[4] = {0.f,0.f,0.f,0.f};
  #pragma unroll
  for (int sub = 0; sub < 8; ++sub)
    #pragma unroll
    for (int reg = 0; reg < 4; ++reg) {
      float v = yacc[sub][reg];
      s1v[reg] += v;
      s2v[reg] += v * v;
    }
  #pragma unroll
  for (int off = 8; off; off >>= 1)
    #pragma unroll
    for (int reg = 0; reg < 4; ++reg) {
      s1v[reg] += __shfl_xor(s1v[reg], off);
      s2v[reg] += __shfl_xor(s2v[reg], off);
    }
  float gwv[8], gbv[8];
  #pragma unroll
  for (int sub = 0; sub < 8; ++sub) {
    gwv[sub] = gw[hh*DH + 16*sub + lr];
    gbv[sub] = gb[hh*DH + 16*sub + lr];
  }
  int b = bh >> 3;
  #pragma unroll
  for (int reg = 0; reg < 4; ++reg) {
    float mean = s1v[reg] * (1.0f/128.0f);
    float var = s2v[reg] * (1.0f/128.0f) - mean*mean;
    float inv = rsqrtf(var + 1e-5f);
    int srow = s0 + 16*w + 4*lg + reg;
    bf16_t* op = Yn + (size_t)(b*SEQ + srow) * HD + hh*DH;
    #pragma unroll
    for (int sub = 0; sub < 8; ++sub)
      op[16*sub + lr] = (bf16_t)((yacc[sub][reg] - mean) * inv * gwv[sub] + gbv[sub]);
  }
}

// ---------------- plain-bf16 MFMA GEMM, 64x128 tile, 2 blocks/CU -----------
__global__ __launch_bounds__(256, 2) void k_gemm(
    const bf16_t* __restrict__ Ag, const bf16_t* __restrict__ Bg,
    const bf16_t* __restrict__ E,
    bf16_t* __restrict__ Oh, float* __restrict__ Of, int mode) {
  __shared__ bf16_t SA[2][64][64];
  __shared__ bf16_t SBB[2][128][64];
  int t = threadIdx.x;
  int lane = t & 63, w = t >> 6;          // 4 waves
  int lr = lane & 15, lg = lane >> 4;
  int wr = w >> 1, wc = w & 1;            // wave tile: 32(m) x 64(n)
  int bid = blockIdx.x;                   // 512 blocks
  int xcd = bid & 7, local = bid >> 3;
  int mp = xcd * 8 + (local >> 3);        // 64 m-panels, 8 contiguous per XCD
  int np = local & 7;                     // 8 n-panels
  int m0 = mp * 64, n0 = np * 128;

  const bf16_t* As = Ag + (size_t)m0 * HD;
  const bf16_t* Bs = Bg + (size_t)n0 * HD;

  f32x4 acc[2][4];
  #pragma unroll
  for (int i = 0; i < 2; ++i)
    #pragma unroll
    for (int j = 0; j < 4; ++j) acc[i][j] = (f32x4){0.f,0.f,0.f,0.f};

  int srow = lane >> 3, sch = lane & 7;

  {
    #pragma unroll
    for (int i = 0; i < 2; ++i) {
      int row = w*16 + i*8 + srow;
      int kc = (sch ^ (row & 7)) * 8;
      gld16(As + (size_t)row*HD + kc, &SA[0][w*16 + i*8][0]);
    }
    #pragma unroll
    for (int i = 0; i < 4; ++i) {
      int row = w*32 + i*8 + srow;
      int kc = (sch ^ (row & 7)) * 8;
      gld16(Bs + (size_t)row*HD + kc, &SBB[0][w*32 + i*8][0]);
    }
  }
  __syncthreads();

  int buf = 0;
  for (int kt = 0; kt < 16; ++kt) {
    if (kt + 1 < 16) {
      int k0 = (kt + 1) * 64;
      #pragma unroll
      for (int i = 0; i < 2; ++i) {
        int row = w*16 + i*8 + srow;
        int kc = (sch ^ (row & 7)) * 8;
        gld16(As + (size_t)row*HD + k0 + kc, &SA[buf^1][w*16 + i*8][0]);
      }
      #pragma unroll
      for (int i = 0; i < 4; ++i) {
        int row = w*32 + i*8 + srow;
        int kc = (sch ^ (row & 7)) * 8;
        gld16(Bs + (size_t)row*HD + k0 + kc, &SBB[buf^1][w*32 + i*8][0]);
      }
    }
    #pragma unroll
    for (int ks = 0; ks < 2; ++ks) {
      bf16x8 a_[2], b_[4];
      #pragma unroll
      for (int mf = 0; mf < 2; ++mf) {
        int row = wr*32 + mf*16 + lr;
        int ch = (lg + 4*ks) ^ (row & 7);
        a_[mf] = *(const bf16x8*)&SA[buf][row][ch*8];
      }
      #pragma unroll
      for (int nf = 0; nf < 4; ++nf) {
        int row = wc*64 + nf*16 + lr;
        int ch = (lg + 4*ks) ^ (row & 7);
        b_[nf] = *(const bf16x8*)&SBB[buf][row][ch*8];
      }
      #pragma unroll
      for (int mf = 0; mf < 2; ++mf)
        #pragma unroll
        for (int nf = 0; nf < 4; ++nf)
          acc[mf][nf] = __builtin_amdgcn_mfma_f32_16x16x32_bf16(a_[mf], b_[nf], acc[mf][nf], 0, 0, 0);
    }
    __syncthreads();
    buf ^= 1;
  }
  #pragma unroll
  for (int mf = 0; mf < 2; ++mf) {
    #pragma unroll
    for (int nf = 0; nf < 4; ++nf) {
      #pragma unroll
      for (int reg = 0; reg < 4; ++reg) {
        int m = m0 + wr*32 + mf*16 + 4*lg + reg;
        int n = n0 + wc*64 + nf*16 + lr;
        float g = acc[mf][nf][reg];
        size_t off = (size_t)m * HD + n;
        if (mode == 1) {
          float sg = 1.0f / (1.0f + expf(-g));
          Oh[off] = (bf16_t)(g * sg * (float)E[off]);
        } else {
          Of[off] = g;
        }
      }
    }
  }
}

extern "C" void kernel_launch(void* const* d_in, const int* in_sizes, int n_in,
                              void* d_out, int out_size, void* d_ws, size_t ws_size,
                              hipStream_t stream) {
  const float* X  = (const float*)d_in[0];
  const float* Wq = (const float*)d_in[1];
  const float* Wk = (const float*)d_in[2];
  const float* Wv = (const float*)d_in[3];
  const float* Wg = (const float*)d_in[4];
  const float* Wo = (const float*)d_in[5];
  const float* gw = (const float*)d_in[6];
  const float* gb = (const float*)d_in[7];
  float* out = (float*)d_out;
  float* ws = (float*)d_ws;

  // ws: tabs 2.1MB | Q K VT 3x8.4 | Yn 8.4 | DSt 8.4 | W ~4.8 | Xh 8.4 (~57MB)
  float* tabs = ws;
  bf16_t* Q   = (bf16_t*)(ws + 524288);
  bf16_t* K   = Q + 4194304;
  bf16_t* VT  = K + 4194304;
  bf16_t* Yn  = VT + 4194304;
  bf16_t* DSt = Yn + 4194304;
  bf16_t* Wqt = DSt + 4194304;
  bf16_t* Wkt = Wqt + 131072;
  bf16_t* Wvt = Wkt + 131072;
  bf16_t* Wgt = Wvt + 131072;
  bf16_t* Wot = Wgt + 1048576;
  bf16_t* Xh  = Wot + 1048576;
  bf16_t* A2  = Q;                 // Q dead after k_ret

  k_prep<<<dim3(1120), dim3(256), 0, stream>>>(Wq, Wk, Wv, Wg, Wo, tabs,
                                               Wqt, Wkt, Wvt, Wgt, Wot);
  k_qkvd<<<dim3(16, 8, 2), dim3(512), 0, stream>>>(X, tabs, Wqt, Wkt, Wvt,
                                                   Q, K, VT, Xh, DSt);
  k_scan<<<dim3(8, 16), dim3(256), 0, stream>>>(DSt);
  k_ret<<<dim3(16, 16), dim3(512), 0, stream>>>(Q, K, VT, DSt, gw, gb, Yn);
  k_gemm<<<dim3(512), dim3(256), 0, stream>>>(Xh, Wgt, Yn, A2, nullptr, 1);
  k_gemm<<<dim3(512), dim3(256), 0, stream>>>(A2, Wot, nullptr, nullptr, out, 0);
}

// Round 11
// 95.494 us; speedup vs baseline: 8.8137x; 1.0273x over previous
//
#include <hip/hip_runtime.h>
#include <math.h>

#define NB 2
#define SEQ 2048
#define HD 1024
#define NH 8
#define DH 128
#define HALF 64

typedef __bf16 bf16_t;
typedef __attribute__((ext_vector_type(8))) __bf16 bf16x8;
typedef __attribute__((ext_vector_type(4))) __bf16 bf16x4;
typedef __attribute__((ext_vector_type(4))) float f32x4;

typedef __attribute__((address_space(1))) void gvoid;
typedef __attribute__((address_space(3))) void lvoid;

__device__ __forceinline__ void gld16(const bf16_t* g, bf16_t* l) {
  __builtin_amdgcn_global_load_lds((gvoid*)g, (lvoid*)l, 16, 0, 0);
}

__device__ __forceinline__ float head_l2g(int hh) {
  double ga = log(1.0/32.0), gbb = log(1.0/512.0);
  float gamma = (float)(1.0 - exp(ga + (double)hh * (gbb - ga) / 7.0));
  return log2f(gamma);
}

// shared transpose+cast body (stride-parameterized)
__device__ __forceinline__ void wsplit_body(
    const float* in, bf16_t* oh, int M, int N,
    int bx, int by, int z, float (*tile)[65], int nthr, int t) {
  in += (size_t)z * M * N; oh += (size_t)z * M * N;
  int r0 = by * 64, c0 = bx * 64;
  for (int idx = t; idx < 1024; idx += nthr) {
    int r = idx >> 4, c4 = (idx & 15) * 4;
    float4 v = *(const float4*)(in + (size_t)(r0 + r) * N + c0 + c4);
    *(float4*)&tile[r][c4] = v;
  }
  __syncthreads();
  for (int idx = t; idx < 1024; idx += nthr) {
    int c = idx >> 4, r4 = (idx & 15) * 4;
    bf16x4 h;
    #pragma unroll
    for (int j = 0; j < 4; ++j)
      h[j] = (bf16_t)tile[r4 + j][c];
    *(bf16x4*)(oh + (size_t)(c0 + c) * M + r0 + r4) = h;
  }
}

// ---------------- prep: xpos tables + QKV weight transposes ----------------
__global__ __launch_bounds__(256) void k_prep(
    const float* __restrict__ Wq, const float* __restrict__ Wk,
    const float* __restrict__ Wv,
    float* __restrict__ tabs, bf16_t* __restrict__ Wqt,
    bf16_t* __restrict__ Wkt, bf16_t* __restrict__ Wvt) {
  __shared__ float tile[64][65];
  int b = blockIdx.x;
  if (b < 512) {
    int idx = b * 256 + threadIdx.x;
    int s = idx >> 6, i = idx & 63;
    float dd = (float)DH;
    float scale = (2.0f * (float)i + 0.4f * dd) / (1.4f * dd);
    float sc = expf(logf(scale) * ((float)s / 512.0f));
    float inv_freq = expf(-logf(10000.0f) * ((float)i / (float)HALF));
    float ang = (float)s * inv_freq;
    float sn, cs;
    sincosf(ang, &sn, &cs);
    float rsc = 1.0f / sc;
    tabs[idx]               = sn * sc;
    tabs[SEQ*HALF + idx]    = cs * sc;
    tabs[2*SEQ*HALF + idx]  = sn * rsc;
    tabs[3*SEQ*HALF + idx]  = cs * rsc;
  } else {
    int i = b - 512;               // 96 blocks: 3 x (2x2x8)
    int which = i >> 5;
    int j = i & 31;
    const float* in = (which == 0) ? Wq : (which == 1) ? Wk : Wv;
    bf16_t* oh = (which == 0) ? Wqt : (which == 1) ? Wkt : Wvt;
    wsplit_body(in, oh, DH, DH, j & 1, (j >> 1) & 1, j >> 2, tile,
                256, threadIdx.x);
  }
}

// ---------------- fused QKV projection + xpos + per-chunk delta ------------
// grid (16 chunks, 8 heads, 2 batch), 512 thr, 96KB LDS.
__global__ __launch_bounds__(512, 1) void k_qkvd(
    const float* __restrict__ X, const float* __restrict__ tabs,
    const bf16_t* __restrict__ Wqt, const bf16_t* __restrict__ Wkt,
    const bf16_t* __restrict__ Wvt,
    bf16_t* __restrict__ Qo, bf16_t* __restrict__ Ko,
    bf16_t* __restrict__ VTo, bf16_t* __restrict__ Xhg,
    bf16_t* __restrict__ DSt) {
  __shared__ bf16_t Wsh[128][128];     // W^T tile (per weight, reused)
  __shared__ bf16_t KT[128][128];      // [dk][tau], chunk-swz (post-xpos K)
  __shared__ bf16_t Vd[128][128];      // [dv][tau], chunk-swz (decayed V)
  int t = threadIdx.x;
  int lane = t & 63, w = t >> 6;       // 8 waves
  int lr = lane & 15, lg = lane >> 4;
  int c = blockIdx.x, hh = blockIdx.y, b = blockIdx.z;
  int s0 = c * 128;
  size_t bh = (size_t)(b*NH + hh);
  float l2g = head_l2g(hh);

  bf16x8 xh[4];
  {
    const float* xp = X + ((size_t)(b*SEQ + s0 + 16*w + lr)) * HD + hh*DH + 8*lg;
    #pragma unroll
    for (int ks = 0; ks < 4; ++ks) {
      float4 u = *(const float4*)(xp + 32*ks);
      float4 v = *(const float4*)(xp + 32*ks + 4);
      float fv[8] = {u.x,u.y,u.z,u.w,v.x,v.y,v.z,v.w};
      #pragma unroll
      for (int j = 0; j < 8; ++j) xh[ks][j] = (bf16_t)fv[j];
    }
  }
  {
    bf16_t* xo = Xhg + ((size_t)(b*SEQ + s0 + 16*w + lr)) * HD + hh*DH + 8*lg;
    #pragma unroll
    for (int ks = 0; ks < 4; ++ks)
      *(bf16x8*)(xo + 32*ks) = xh[ks];
  }

  const bf16_t* Wp[3] = {Wqt, Wkt, Wvt};

  for (int which = 0; which < 3; ++which) {
    const bf16_t* wp = Wp[which] + (size_t)hh * (DH*DH);
    __syncthreads();                    // Wsh free (prev pass done)
    // async stage W^T: wave w rows [w*16, w*16+16), pre-swizzled source
    #pragma unroll
    for (int i = 0; i < 4; ++i) {
      int e = w*16 + i*4 + (lane >> 4);
      int kb = (lane & 15) ^ (e & 7);
      gld16(wp + (size_t)e*DH + kb*8, &Wsh[w*16 + i*4][0]);
    }
    __syncthreads();
    f32x4 yacc[8];
    #pragma unroll
    for (int i = 0; i < 8; ++i) yacc[i] = (f32x4){0.f,0.f,0.f,0.f};
    #pragma unroll
    for (int sub = 0; sub < 8; ++sub) {
      int e = 16*sub + lr;
      #pragma unroll
      for (int ks = 0; ks < 4; ++ks) {
        int ch = (lg + 4*ks) ^ (lr & 7);
        bf16x8 bhv = *(const bf16x8*)&Wsh[e][ch*8];
        yacc[sub] = __builtin_amdgcn_mfma_f32_16x16x32_bf16(xh[ks], bhv, yacc[sub], 0, 0, 0);
      }
    }
    if (which < 2) {
      const float* st = tabs + (which ? 2*SEQ*HALF : 0);
      const float* ct = st + SEQ*HALF;
      bf16_t* Op = which ? Ko : Qo;
      #pragma unroll
      for (int sub = 0; sub < 8; ++sub) {
        int e = 16*sub + lr;
        int i = e >> 1;
        #pragma unroll
        for (int reg = 0; reg < 4; ++reg) {
          float v = yacc[sub][reg];
          float p = __shfl_xor(v, 1);
          int tau = 16*w + 4*lg + reg;
          int srow = s0 + tau;
          float sv = st[srow*HALF + i], cv = ct[srow*HALF + i];
          float o = v * cv + ((e & 1) ? p : -p) * sv;
          bf16_t ob = (bf16_t)o;
          Op[(bh*SEQ + srow) * DH + e] = ob;
          if (which == 1) {             // stash K^T for delta
            int col = (((tau>>3) ^ (e & 7)) << 3) | (tau & 7);
            KT[e][col] = ob;
          }
        }
      }
    } else {
      float decay[4];
      #pragma unroll
      for (int reg = 0; reg < 4; ++reg)
        decay[reg] = exp2f(l2g * (float)(127 - (16*w + 4*lg + reg)));
      #pragma unroll
      for (int sub = 0; sub < 8; ++sub) {
        int e = 16*sub + lr;
        bf16x4 hv;
        #pragma unroll
        for (int reg = 0; reg < 4; ++reg) {
          int tau = 16*w + 4*lg + reg;
          float f = yacc[sub][reg];
          hv[reg] = (bf16_t)f;
          int col = (((tau>>3) ^ (e & 7)) << 3) | (tau & 7);
          Vd[e][col] = (bf16_t)(f * decay[reg]);
        }
        *(bf16x4*)(VTo + bh * (size_t)(DH*SEQ) + (size_t)e*SEQ + (s0 + 16*w + 4*lg)) = hv;
      }
    }
  }
  __syncthreads();                      // KT / Vd complete

  // ---- delta: Dt[dv][dk] = sum_tau Vd[dv][tau] * KT[dk][tau] ----
  f32x4 acc[8];
  #pragma unroll
  for (int s = 0; s < 8; ++s) acc[s] = (f32x4){0.f,0.f,0.f,0.f};
  {
    int dv = 16*w + lr;
    #pragma unroll
    for (int ks = 0; ks < 4; ++ks) {
      int ca = (lg + 4*ks) ^ (dv & 7);
      bf16x8 avh = *(const bf16x8*)&Vd[dv][ca*8];
      #pragma unroll
      for (int sub = 0; sub < 8; ++sub) {
        int dk = 16*sub + lr;
        int cb = (lg + 4*ks) ^ (dk & 7);
        bf16x8 bkh = *(const bf16x8*)&KT[dk][cb*8];
        acc[sub] = __builtin_amdgcn_mfma_f32_16x16x32_bf16(avh, bkh, acc[sub], 0, 0, 0);
      }
    }
  }
  size_t obase = (bh * 16 + c) * 16384;
  #pragma unroll
  for (int sub = 0; sub < 8; ++sub)
    #pragma unroll
    for (int reg = 0; reg < 4; ++reg) {
      int dv = 16*w + 4*lg + reg;
      int dk = 16*sub + lr;
      DSt[obase + (size_t)dv*128 + dk] = (bf16_t)acc[sub][reg];
    }
}

// ---------------- retention: in-block scan + cross + intra + groupnorm -----
// flat grid: blocks 0..255 = retention (c=bid&15, bh=bid>>4);
// blocks 256..767 = Wg/Wo transposes (hidden under ret). 512 thr.
__global__ __launch_bounds__(512, 1) void k_ret(
    const bf16_t* __restrict__ Qg, const bf16_t* __restrict__ Kg,
    const bf16_t* __restrict__ VTg, const bf16_t* __restrict__ DSt,
    const float* __restrict__ gw, const float* __restrict__ gb,
    bf16_t* __restrict__ Yn,
    const float* __restrict__ Wg, const float* __restrict__ Wo,
    bf16_t* __restrict__ Wgt, bf16_t* __restrict__ Wot) {
  __shared__ bf16_t Ksh[64][128];
  __shared__ bf16_t Vsh[128][64];
  __shared__ bf16_t Ph[128][64];
  __shared__ bf16_t Slds[128][128];
  __shared__ float tile[64][65];
  int t = threadIdx.x;
  int bid = blockIdx.x;
  if (bid >= 256) {
    int i = bid - 256;               // 512 blocks: 2 x (16x16)
    int which = i >> 8;
    int j = i & 255;
    wsplit_body(which ? Wo : Wg, which ? Wot : Wgt, HD, HD,
                j & 15, j >> 4, 0, tile, 512, t);
    return;
  }
  int lane = t & 63, w = t >> 6;          // 8 waves
  int lr = lane & 15, lg = lane >> 4;
  int c = bid & 15, bh = bid >> 4, hh = bh & 7;
  int s0 = c * 128;
  size_t base  = (size_t)bh * SEQ * DH;
  size_t vbase = (size_t)bh * DH * SEQ;
  float l2g = head_l2g(hh);
  float colf = exp2f(-l2g * (float)lr);
  float g16v[4];
  #pragma unroll
  for (int ts = 0; ts < 4; ++ts) g16v[ts] = exp2f(-l2g * (float)(16*ts));

  // ---- issue async staging of intra tile 0 (K rows, V cols s0..s0+63) ----
  #pragma unroll
  for (int i = 0; i < 2; ++i) {
    int r = w*8 + i*4 + (lane >> 4);
    int kb = (lane & 15) ^ (r & 7);
    gld16(Kg + base + (size_t)(s0 + r)*DH + kb*8, &Ksh[w*8 + i*4][0]);
  }
  #pragma unroll
  for (int i = 0; i < 2; ++i) {
    int d = w*16 + i*8 + (lane >> 3);
    int cb = (lane & 7) ^ (d & 7);
    gld16(VTg + vbase + (size_t)d*SEQ + s0 + cb*8, &Vsh[w*16 + i*8][0]);
  }

  // ---- Q fragments ----
  bf16x8 qh[4];
  {
    const bf16_t* qp = Qg + base + (size_t)(s0 + 16*w + lr) * DH + lg * 8;
    #pragma unroll
    for (int ks = 0; ks < 4; ++ks)
      qh[ks] = *(const bf16x8*)(qp + 32*ks);
  }

  // ---- in-block scan: S_c = sum_{cp<c} g128^(c-1-cp) * Δ_cp  (fp32) ----
  {
    float g128 = exp2f(l2g * 128.0f);
    float S0[8] = {}, S1[8] = {}, S2[8] = {}, S3[8] = {};
    const bf16_t* dbase = DSt + ((size_t)bh * 16) * 16384
                        + (size_t)(t >> 2) * 128 + (t & 3) * 32;
    for (int cp = 0; cp < c; ++cp) {
      const bf16_t* dp = dbase + (size_t)cp * 16384;
      bf16x8 d0 = *(const bf16x8*)dp;
      bf16x8 d1 = *(const bf16x8*)(dp + 8);
      bf16x8 d2 = *(const bf16x8*)(dp + 16);
      bf16x8 d3 = *(const bf16x8*)(dp + 24);
      #pragma unroll
      for (int j = 0; j < 8; ++j) {
        S0[j] = g128*S0[j] + (float)d0[j];
        S1[j] = g128*S1[j] + (float)d1[j];
        S2[j] = g128*S2[j] + (float)d2[j];
        S3[j] = g128*S3[j] + (float)d3[j];
      }
    }
    int dv = t >> 2;
    #pragma unroll
    for (int q = 0; q < 4; ++q) {
      const float* Sq = (q == 0) ? S0 : (q == 1) ? S1 : (q == 2) ? S2 : S3;
      int ch = ((t & 3) * 4 + q) ^ (dv & 7);
      bf16x8 s8;
      #pragma unroll
      for (int j = 0; j < 8; ++j) s8[j] = (bf16_t)Sq[j];
      *(bf16x8*)&Slds[dv][ch*8] = s8;
    }
  }
  __syncthreads();   // tile0 gld16 + Slds writes complete

  // ---- cross: yacc = Q · S^T (B-frags from LDS) ----
  f32x4 yacc[8];
  #pragma unroll
  for (int i = 0; i < 8; ++i) yacc[i] = (f32x4){0.f,0.f,0.f,0.f};
  {
    #pragma unroll
    for (int sub = 0; sub < 8; ++sub) {
      int dv = 16*sub + lr;
      #pragma unroll
      for (int ks = 0; ks < 4; ++ks) {
        int ch = (lg + 4*ks) ^ (dv & 7);
        bf16x8 b8 = *(const bf16x8*)&Slds[dv][ch*8];
        yacc[sub] = __builtin_amdgcn_mfma_f32_16x16x32_bf16(qh[ks], b8, yacc[sub], 0, 0, 0);
      }
    }
    float rowc[4];
    #pragma unroll
    for (int reg = 0; reg < 4; ++reg)
      rowc[reg] = exp2f(l2g * (float)(16*w + 4*lg + reg + 1));
    #pragma unroll
    for (int sub = 0; sub < 8; ++sub)
      #pragma unroll
      for (int reg = 0; reg < 4; ++reg)
        yacc[sub][reg] *= rowc[reg];
  }

  // ---- intra tiles ----
  for (int kt = 0; kt < 2; ++kt) {
    int t0 = kt * 64;
    if (kt == 1) {
      __syncthreads();   // all waves done reading tile 0
      #pragma unroll
      for (int i = 0; i < 2; ++i) {
        int r = w*8 + i*4 + (lane >> 4);
        int kb = (lane & 15) ^ (r & 7);
        gld16(Kg + base + (size_t)(s0 + 64 + r)*DH + kb*8, &Ksh[w*8 + i*4][0]);
      }
      #pragma unroll
      for (int i = 0; i < 2; ++i) {
        int d = w*16 + i*8 + (lane >> 3);
        int cb = (lane & 7) ^ (d & 7);
        gld16(VTg + vbase + (size_t)d*SEQ + s0 + 64 + cb*8, &Vsh[w*16 + i*8][0]);
      }
      __syncthreads();   // tile 1 staged
    }
    if (!(kt == 1 && w < 4)) {
      float rowf[4];
      #pragma unroll
      for (int reg = 0; reg < 4; ++reg)
        rowf[reg] = exp2f(l2g * (float)(16*w + 4*lg + reg - t0));

      #pragma unroll
      for (int ts = 0; ts < 4; ++ts) {
        f32x4 sacc = (f32x4){0.f,0.f,0.f,0.f};
        int trow = 16*ts + lr;
        #pragma unroll
        for (int ks = 0; ks < 4; ++ks) {
          int kbs = (4*ks + lg) ^ (trow & 7);
          bf16x8 kh8 = *(const bf16x8*)&Ksh[trow][kbs*8];
          sacc = __builtin_amdgcn_mfma_f32_16x16x32_bf16(qh[ks], kh8, sacc, 0, 0, 0);
        }
        float cf = colf * g16v[ts];
        #pragma unroll
        for (int reg = 0; reg < 4; ++reg) {
          int qloc = 4*lg + reg;
          int diff = (16*w + qloc) - (t0 + trow);
          float p = (diff >= 0) ? sacc[reg] * (rowf[reg] * cf) : 0.0f;
          int cb = (trow >> 3) ^ (qloc & 7);
          Ph[16*w + qloc][cb*8 + (trow & 7)] = (bf16_t)p;
        }
      }
      #pragma unroll
      for (int ks = 0; ks < 2; ++ks) {
        int prow = 16*w + lr;
        int pcb = (4*ks + lg) ^ (lr & 7);
        bf16x8 pah = *(const bf16x8*)&Ph[prow][pcb*8];
        #pragma unroll
        for (int sub = 0; sub < 8; ++sub) {
          int drow = 16*sub + lr;
          int vcb = (4*ks + lg) ^ (drow & 7);
          bf16x8 vh8 = *(const bf16x8*)&Vsh[drow][vcb*8];
          yacc[sub] = __builtin_amdgcn_mfma_f32_16x16x32_bf16(pah, vh8, yacc[sub], 0, 0, 0);
        }
      }
    }
  }

  // ---- fused groupnorm (bf16 out) ----
  float s1v[4] = {0.f,0.f,0.f,0.f}, s2v[4] = {0.f,0.f,0.f,0.f};
  #pragma unroll
  for (int sub = 0; sub < 8; ++sub)
    #pragma unroll
    for (int reg = 0; reg < 4; ++reg) {
      float v = yacc[sub][reg];
      s1v[reg] += v;
      s2v[reg] += v * v;
    }
  #pragma unroll
  for (int off = 8; off; off >>= 1)
    #pragma unroll
    for (int reg = 0; reg < 4; ++reg) {
      s1v[reg] += __shfl_xor(s1v[reg], off);
      s2v[reg] += __shfl_xor(s2v[reg], off);
    }
  float gwv[8], gbv[8];
  #pragma unroll
  for (int sub = 0; sub < 8; ++sub) {
    gwv[sub] = gw[hh*DH + 16*sub + lr];
    gbv[sub] = gb[hh*DH + 16*sub + lr];
  }
  int b = bh >> 3;
  #pragma unroll
  for (int reg = 0; reg < 4; ++reg) {
    float mean = s1v[reg] * (1.0f/128.0f);
    float var = s2v[reg] * (1.0f/128.0f) - mean*mean;
    float inv = rsqrtf(var + 1e-5f);
    int srow = s0 + 16*w + 4*lg + reg;
    bf16_t* op = Yn + (size_t)(b*SEQ + srow) * HD + hh*DH;
    #pragma unroll
    for (int sub = 0; sub < 8; ++sub)
      op[16*sub + lr] = (bf16_t)((yacc[sub][reg] - mean) * inv * gwv[sub] + gbv[sub]);
  }
}

// ---------------- plain-bf16 MFMA GEMM, 64x128 tile, 2 blocks/CU -----------
__global__ __launch_bounds__(256, 2) void k_gemm(
    const bf16_t* __restrict__ Ag, const bf16_t* __restrict__ Bg,
    const bf16_t* __restrict__ E,
    bf16_t* __restrict__ Oh, float* __restrict__ Of, int mode) {
  __shared__ bf16_t SA[2][64][64];
  __shared__ bf16_t SBB[2][128][64];
  int t = threadIdx.x;
  int lane = t & 63, w = t >> 6;          // 4 waves
  int lr = lane & 15, lg = lane >> 4;
  int wr = w >> 1, wc = w & 1;            // wave tile: 32(m) x 64(n)
  int bid = blockIdx.x;                   // 512 blocks
  int xcd = bid & 7, local = bid >> 3;
  int mp = xcd * 8 + (local >> 3);        // 64 m-panels, 8 contiguous per XCD
  int np = local & 7;                     // 8 n-panels
  int m0 = mp * 64, n0 = np * 128;

  const bf16_t* As = Ag + (size_t)m0 * HD;
  const bf16_t* Bs = Bg + (size_t)n0 * HD;

  f32x4 acc[2][4];
  #pragma unroll
  for (int i = 0; i < 2; ++i)
    #pragma unroll
    for (int j = 0; j < 4; ++j) acc[i][j] = (f32x4){0.f,0.f,0.f,0.f};

  int srow = lane >> 3, sch = lane & 7;

  {
    #pragma unroll
    for (int i = 0; i < 2; ++i) {
      int row = w*16 + i*8 + srow;
      int kc = (sch ^ (row & 7)) * 8;
      gld16(As + (size_t)row*HD + kc, &SA[0][w*16 + i*8][0]);
    }
    #pragma unroll
    for (int i = 0; i < 4; ++i) {
      int row = w*32 + i*8 + srow;
      int kc = (sch ^ (row & 7)) * 8;
      gld16(Bs + (size_t)row*HD + kc, &SBB[0][w*32 + i*8][0]);
    }
  }
  __syncthreads();

  int buf = 0;
  for (int kt = 0; kt < 16; ++kt) {
    if (kt + 1 < 16) {
      int k0 = (kt + 1) * 64;
      #pragma unroll
      for (int i = 0; i < 2; ++i) {
        int row = w*16 + i*8 + srow;
        int kc = (sch ^ (row & 7)) * 8;
        gld16(As + (size_t)row*HD + k0 + kc, &SA[buf^1][w*16 + i*8][0]);
      }
      #pragma unroll
      for (int i = 0; i < 4; ++i) {
        int row = w*32 + i*8 + srow;
        int kc = (sch ^ (row & 7)) * 8;
        gld16(Bs + (size_t)row*HD + k0 + kc, &SBB[buf^1][w*32 + i*8][0]);
      }
    }
    #pragma unroll
    for (int ks = 0; ks < 2; ++ks) {
      bf16x8 a_[2], b_[4];
      #pragma unroll
      for (int mf = 0; mf < 2; ++mf) {
        int row = wr*32 + mf*16 + lr;
        int ch = (lg + 4*ks) ^ (row & 7);
        a_[mf] = *(const bf16x8*)&SA[buf][row][ch*8];
      }
      #pragma unroll
      for (int nf = 0; nf < 4; ++nf) {
        int row = wc*64 + nf*16 + lr;
        int ch = (lg + 4*ks) ^ (row & 7);
        b_[nf] = *(const bf16x8*)&SBB[buf][row][ch*8];
      }
      #pragma unroll
      for (int mf = 0; mf < 2; ++mf)
        #pragma unroll
        for (int nf = 0; nf < 4; ++nf)
          acc[mf][nf] = __builtin_amdgcn_mfma_f32_16x16x32_bf16(a_[mf], b_[nf], acc[mf][nf], 0, 0, 0);
    }
    __syncthreads();
    buf ^= 1;
  }
  #pragma unroll
  for (int mf = 0; mf < 2; ++mf) {
    #pragma unroll
    for (int nf = 0; nf < 4; ++nf) {
      #pragma unroll
      for (int reg = 0; reg < 4; ++reg) {
        int m = m0 + wr*32 + mf*16 + 4*lg + reg;
        int n = n0 + wc*64 + nf*16 + lr;
        float g = acc[mf][nf][reg];
        size_t off = (size_t)m * HD + n;
        if (mode == 1) {
          float sg = 1.0f / (1.0f + expf(-g));
          Oh[off] = (bf16_t)(g * sg * (float)E[off]);
        } else {
          Of[off] = g;
        }
      }
    }
  }
}

extern "C" void kernel_launch(void* const* d_in, const int* in_sizes, int n_in,
                              void* d_out, int out_size, void* d_ws, size_t ws_size,
                              hipStream_t stream) {
  const float* X  = (const float*)d_in[0];
  const float* Wq = (const float*)d_in[1];
  const float* Wk = (const float*)d_in[2];
  const float* Wv = (const float*)d_in[3];
  const float* Wg = (const float*)d_in[4];
  const float* Wo = (const float*)d_in[5];
  const float* gw = (const float*)d_in[6];
  const float* gb = (const float*)d_in[7];
  float* out = (float*)d_out;
  float* ws = (float*)d_ws;

  // ws: tabs 2.1MB | Q K VT 3x8.4 | Yn 8.4 | DSt 8.4 | W ~4.8 | Xh 8.4 (~57MB)
  float* tabs = ws;
  bf16_t* Q   = (bf16_t*)(ws + 524288);
  bf16_t* K   = Q + 4194304;
  bf16_t* VT  = K + 4194304;
  bf16_t* Yn  = VT + 4194304;
  bf16_t* DSt = Yn + 4194304;
  bf16_t* Wqt = DSt + 4194304;
  bf16_t* Wkt = Wqt + 131072;
  bf16_t* Wvt = Wkt + 131072;
  bf16_t* Wgt = Wvt + 131072;
  bf16_t* Wot = Wgt + 1048576;
  bf16_t* Xh  = Wot + 1048576;
  bf16_t* A2  = Q;                 // Q dead after k_ret

  k_prep<<<dim3(608), dim3(256), 0, stream>>>(Wq, Wk, Wv, tabs, Wqt, Wkt, Wvt);
  k_qkvd<<<dim3(16, 8, 2), dim3(512), 0, stream>>>(X, tabs, Wqt, Wkt, Wvt,
                                                   Q, K, VT, Xh, DSt);
  k_ret<<<dim3(768), dim3(512), 0, stream>>>(Q, K, VT, DSt, gw, gb, Yn,
                                             Wg, Wo, Wgt, Wot);
  k_gemm<<<dim3(512), dim3(256), 0, stream>>>(Xh, Wgt, Yn, A2, nullptr, 1);
  k_gemm<<<dim3(512), dim3(256), 0, stream>>>(A2, Wot, nullptr, nullptr, out, 0);
}